// Round 1
// baseline (319.071 us; speedup 1.0000x reference)
//
#include <hip/hip_runtime.h>

#define T_    1024
#define B_    2
#define D_    1024
#define E_    12
#define TOPK  4
#define ED_   256
#define HD_   64
#define H_    4
#define N_    (T_*B_)      // 2048 tokens
#define NROW  (N_*TOPK)    // 8192 (n,k) rows
#define PB_MAX 268         // max 32-row expert chunks: 8192/32 + 12
#define PB3_MAX 76         // max 128-row expert chunks: 8192/128 + 12
#define KR_   768          // split-precision K for reduce: [a_hi|a_lo|a_hi]

typedef __bf16 bf16x8 __attribute__((ext_vector_type(8)));
typedef float  f32x4  __attribute__((ext_vector_type(4)));

__device__ __forceinline__ float sc_() { return 0.35355339059327373f; } // 64^-0.25

__device__ __forceinline__ void async16(const void* g, void* l) {
    __builtin_amdgcn_global_load_lds((const __attribute__((address_space(1))) void*)g,
                                     (__attribute__((address_space(3))) void*)l, 16, 0, 0);
}

// ---------------- one-time: wgT[e][d] = wg[d][e] (f32, 48 KB) ----------------
__global__ void castwg_kernel(const float* __restrict__ wg, float* __restrict__ wgT) {
    int d = blockIdx.x * 256 + threadIdx.x;   // grid 4 x 256
#pragma unroll
    for (int e = 0; e < E_; ++e) wgT[e * D_ + d] = wg[d * E_ + e];
}

// ---------------- gating: wave per token, NO atomics -------------------------
__global__ void __launch_bounds__(256)
gate_kernel(const float* __restrict__ x, const float* __restrict__ wgT,
            float* __restrict__ gates, int* __restrict__ idx) {
    int w = threadIdx.x >> 6, L = threadIdx.x & 63;
    int n = blockIdx.x * 4 + w;
    const float* xr = x + (size_t)n * D_;
    float acc[E_];
#pragma unroll
    for (int e = 0; e < E_; ++e) acc[e] = 0.f;
#pragma unroll
    for (int it = 0; it < 4; ++it) {
        float4 xv = *(const float4*)(xr + it * 256 + L * 4);
#pragma unroll
        for (int e = 0; e < E_; ++e) {
            float4 wv = *(const float4*)(wgT + e * D_ + it * 256 + L * 4);
            acc[e] += xv.x * wv.x + xv.y * wv.y + xv.z * wv.z + xv.w * wv.w;
        }
    }
#pragma unroll
    for (int e = 0; e < E_; ++e) {
        float v = acc[e];
        for (int o = 32; o > 0; o >>= 1) v += __shfl_down(v, o);
        acc[e] = v;
    }
    if (L == 0) {
        float mx = acc[0];
        for (int e = 1; e < E_; ++e) mx = fmaxf(mx, acc[e]);
        float s = 0.f, pr[E_];
        for (int e = 0; e < E_; ++e) { pr[e] = expf(acc[e] - mx); s += pr[e]; }
        float inv = 1.f / s;
        for (int e = 0; e < E_; ++e) pr[e] *= inv;
        for (int k = 0; k < TOPK; ++k) {
            int be = 0; float bv = -1.f;
            for (int e = 0; e < E_; ++e) if (pr[e] > bv) { bv = pr[e]; be = e; }
            gates[n * TOPK + k] = bv;
            idx[n * TOPK + k] = be;
            pr[be] = -1.f;
        }
    }
}

// ---------------- hist: per-block expert counts via ballot (no atomics) ------
// grid 32, block 256: block b covers rows b*256..+255
__global__ void hist_kernel(const int* __restrict__ idx, int* __restrict__ bcnt) {
    int b = blockIdx.x, tid = threadIdx.x, w = tid >> 6, L = tid & 63;
    int e = idx[b * 256 + tid];
    __shared__ int wcnt[4][E_];
#pragma unroll
    for (int e0 = 0; e0 < E_; ++e0) {
        unsigned long long m = __ballot(e == e0);
        if (L == 0) wcnt[w][e0] = (int)__popcll(m);
    }
    __syncthreads();
    if (tid < E_) bcnt[b * E_ + tid] = wcnt[0][tid] + wcnt[1][tid] + wcnt[2][tid] + wcnt[3][tid];
}

// ---------------- scan: offsets + per-block bases + chunk maps (32 & 128) ----
__global__ void scan_kernel(const int* __restrict__ bcnt, int* __restrict__ offs,
                            int* __restrict__ base,
                            int* __restrict__ rbe2, int* __restrict__ rbs2,
                            int* __restrict__ rbc2,
                            int* __restrict__ rbe3, int* __restrict__ rbs3,
                            int* __restrict__ rbc3) {
    if (threadIdx.x == 0 && blockIdx.x == 0) {
        int counts[E_], offl[E_ + 1];
        for (int e = 0; e < E_; ++e) {
            int s = 0;
            for (int b = 0; b < 32; ++b) s += bcnt[b * E_ + e];
            counts[e] = s;
        }
        int o = 0;
        for (int e = 0; e < E_; ++e) { offl[e] = o; o += counts[e]; }
        offl[E_] = o;
        for (int e = 0; e <= E_; ++e) offs[e] = offl[e];
        for (int e = 0; e < E_; ++e) {
            int run = offl[e];
            for (int b = 0; b < 32; ++b) { base[b * E_ + e] = run; run += bcnt[b * E_ + e]; }
        }
        int nb2 = 0;
        for (int e = 0; e < E_; ++e) {
            int c = counts[e];
            for (int s = 0; s < c; s += 32) {
                rbe2[nb2] = e; rbs2[nb2] = offl[e] + s;
                rbc2[nb2] = (c - s < 32) ? (c - s) : 32; ++nb2;
            }
        }
        for (; nb2 < PB_MAX; ++nb2) { rbe2[nb2] = 0; rbs2[nb2] = 0; rbc2[nb2] = 0; }
        int nb3 = 0;
        for (int e = 0; e < E_; ++e) {
            int c = counts[e];
            for (int s = 0; s < c; s += 128) {
                rbe3[nb3] = e; rbs3[nb3] = offl[e] + s;
                rbc3[nb3] = (c - s < 128) ? (c - s) : 128; ++nb3;
            }
        }
        for (; nb3 < PB3_MAX; ++nb3) { rbe3[nb3] = 0; rbs3[nb3] = 0; rbc3[nb3] = 0; }
    }
}

// ---------------- scatter via ballot rank (no atomics) -----------------------
__global__ void scatter_kernel(const int* __restrict__ idx, const int* __restrict__ base,
                               int* __restrict__ perm) {
    int b = blockIdx.x, tid = threadIdx.x, w = tid >> 6, L = tid & 63;
    int r = b * 256 + tid;
    int e = idx[r];
    __shared__ int wcnt[4][E_];
    int rankw = 0;
#pragma unroll
    for (int e0 = 0; e0 < E_; ++e0) {
        unsigned long long m = __ballot(e == e0);
        if (e == e0) rankw = (int)__popcll(m & ((1ULL << L) - 1ULL));
        if (L == 0) wcnt[w][e0] = (int)__popcll(m);
    }
    __syncthreads();
    int pre = 0;
    for (int w2 = 0; w2 < w; ++w2) pre += wcnt[w2][e];
    perm[base[b * E_ + e] + pre + rankw] = r;
}

// ---------------- one-time casts ---------------------------------------------
__global__ void castx_kernel(const float* __restrict__ x, ushort* __restrict__ xb) {
    int t = blockIdx.x * 256 + threadIdx.x;
    float4 v = *(const float4*)(x + (size_t)t * 4);
    union { __bf16 h[4]; uint2 u; } pk;
    pk.h[0] = (__bf16)v.x; pk.h[1] = (__bf16)v.y;
    pk.h[2] = (__bf16)v.z; pk.h[3] = (__bf16)v.w;
    *(uint2*)(xb + (size_t)t * 4) = pk.u;
}

// grid (12,16,4): e, 64-d tile, 64-ed tile.  wmapT[e][ed][d] = bf16(w_map[e][d][ed])
__global__ void castw_kernel(const float* __restrict__ wmap, ushort* __restrict__ wmapT) {
    int e = blockIdx.x, dt = blockIdx.y, et = blockIdx.z;
    __shared__ float ls[64][65];
    int c = threadIdx.x & 63, rg = threadIdx.x >> 6;
    const float* src = wmap + (size_t)e * (D_ * ED_) + (size_t)(dt * 64) * ED_ + et * 64;
#pragma unroll
    for (int q = 0; q < 16; ++q) {
        int r = q * 4 + rg;
        ls[r][c] = src[(size_t)r * ED_ + c];
    }
    __syncthreads();
    ushort* dst = wmapT + ((size_t)e << 18) + (size_t)(et * 64) * 1024 + dt * 64;
#pragma unroll
    for (int q = 0; q < 16; ++q) {
        int r = q * 4 + rg;
        union { __bf16 h; ushort u; } cv; cv.h = (__bf16)ls[c][r];
        dst[(size_t)r * 1024 + c] = cv.u;
    }
}

// grid (2,16,4): which, 64-d tile, 64-ed tile. wT[ed][d] = bf16(w[d][ed])
__global__ void castwkv_kernel(const float* __restrict__ wk, const float* __restrict__ wv,
                               ushort* __restrict__ wkT, ushort* __restrict__ wvT) {
    int which = blockIdx.x, dt = blockIdx.y, et = blockIdx.z;
    const float* w = which ? wv : wk;
    ushort* wT = which ? wvT : wkT;
    __shared__ float ls[64][65];
    int c = threadIdx.x & 63, rg = threadIdx.x >> 6;
    const float* src = w + (size_t)(dt * 64) * ED_ + et * 64;
#pragma unroll
    for (int q = 0; q < 16; ++q) {
        int r = q * 4 + rg;
        ls[r][c] = src[(size_t)r * ED_ + c];
    }
    __syncthreads();
    ushort* dst = wT + (size_t)(et * 64) * 1024 + dt * 64;
#pragma unroll
    for (int q = 0; q < 16; ++q) {
        int r = q * 4 + rg;
        union { __bf16 h; ushort u; } cv; cv.h = (__bf16)ls[c][r];
        dst[(size_t)r * 1024 + c] = cv.u;
    }
}

// grid (12,4,16): e, 64-ed tile, 64-d tile.
// wredT3[e][d][k]: k in [0,256)=w_hi[ed], [256,512)=w_hi[ed], [512,768)=w_lo[ed]
__global__ void castwred_kernel(const float* __restrict__ wred, ushort* __restrict__ wredT3) {
    int e = blockIdx.x, et = blockIdx.y, dt = blockIdx.z;
    __shared__ float ls[64][65];
    int c = threadIdx.x & 63, rg = threadIdx.x >> 6;
    const float* src = wred + (size_t)e * (ED_ * D_) + (size_t)(et * 64) * D_ + dt * 64;
#pragma unroll
    for (int q = 0; q < 16; ++q) {
        int r = q * 4 + rg;           // ed-local
        ls[r][c] = src[(size_t)r * D_ + c];
    }
    __syncthreads();
    ushort* dst = wredT3 + (size_t)e * (D_ * KR_) + (size_t)(dt * 64) * KR_ + et * 64;
#pragma unroll
    for (int q = 0; q < 16; ++q) {
        int r = q * 4 + rg;           // d-local
        float v = ls[c][r];
        union { __bf16 h; ushort u; } hi; hi.h = (__bf16)v;
        float lo = v - (float)hi.h;
        union { __bf16 h; ushort u; } lov; lov.h = (__bf16)lo;
        dst[(size_t)r * KR_ + c] = hi.u;
        dst[(size_t)r * KR_ + 256 + c] = hi.u;
        dst[(size_t)r * KR_ + 512 + c] = lov.u;
    }
}

// ---------------- k/v projection as bf16 MFMA GEMM ---------------------------
__global__ void __launch_bounds__(256)
kv_mfma(const ushort* __restrict__ keyb, const ushort* __restrict__ valb,
        const ushort* __restrict__ wkT, const ushort* __restrict__ wvT,
        ushort* __restrict__ kpb, ushort* __restrict__ vpT) {
    int which = blockIdx.y;
    const ushort* xb = which ? valb : keyb;
    const ushort* wT = which ? wvT : wkT;
    int m0 = blockIdx.x * 32;
    int b = m0 >> 10, t0 = m0 & 1023;
    int tid = threadIdx.x, w = tid >> 6, L = tid & 63;
    __shared__ __align__(16) ushort As[2][32 * 64];
    __shared__ __align__(16) ushort Bs[2][4 * 64 * 64];

    int swz = ((L & 7) ^ ((L >> 3) & 7)) * 8;
    int an = (((t0 + w * 8 + (L >> 3)) << 1) | b);
    const ushort* asrc = xb + (size_t)an * 1024 + swz;
    const ushort* bsrc = wT + (size_t)(w * 64 + (L >> 3)) * 1024 + swz;

    f32x4 acc[2][4];
#pragma unroll
    for (int mt = 0; mt < 2; ++mt)
#pragma unroll
        for (int nt = 0; nt < 4; ++nt) acc[mt][nt] = (f32x4){0.f, 0.f, 0.f, 0.f};

    auto stage = [&](int kt, int bf) {
        async16(asrc + kt * 64, &As[bf][w * 512]);
#pragma unroll
        for (int q = 0; q < 8; ++q)
            async16(bsrc + (size_t)q * 8192 + kt * 64, &Bs[bf][(w * 64 + q * 8) * 64]);
    };
    auto compute = [&](int bf) {
        const ushort* AB = As[bf];
        const ushort* BB = Bs[bf] + w * 4096;
#pragma unroll
        for (int ks = 0; ks < 2; ++ks) {
            int phys = (((ks * 4 + (L >> 4)) ^ (L & 7))) * 8;
            bf16x8 a0 = *(const bf16x8*)(AB + (L & 15) * 64 + phys);
            bf16x8 a1 = *(const bf16x8*)(AB + (16 + (L & 15)) * 64 + phys);
#pragma unroll
            for (int nt = 0; nt < 4; ++nt) {
                bf16x8 bfr = *(const bf16x8*)(BB + (nt * 16 + (L & 15)) * 64 + phys);
                acc[0][nt] = __builtin_amdgcn_mfma_f32_16x16x32_bf16(a0, bfr, acc[0][nt], 0, 0, 0);
                acc[1][nt] = __builtin_amdgcn_mfma_f32_16x16x32_bf16(a1, bfr, acc[1][nt], 0, 0, 0);
            }
        }
    };

    stage(0, 0);
    for (int t = 0; t < 16; ++t) {
        __syncthreads();
        if (t < 15) stage(t + 1, (t + 1) & 1);
        compute(t & 1);
    }

#pragma unroll
    for (int mt = 0; mt < 2; ++mt)
#pragma unroll
        for (int nt = 0; nt < 4; ++nt) {
            int ed = w * 64 + nt * 16 + (L & 15);
            int tb = t0 + mt * 16 + (L >> 4) * 4;
            if (which == 0) {
#pragma unroll
                for (int r = 0; r < 4; ++r) {
                    union { __bf16 h; ushort u; } cv;
                    cv.h = (__bf16)(acc[mt][nt][r] * sc_());
                    kpb[((size_t)((b << 10) + tb + r)) * ED_ + ed] = cv.u;
                }
            } else {
                int h = ed >> 6, d = ed & 63;
                union { __bf16 h4[4]; uint2 u; } pk;
#pragma unroll
                for (int r = 0; r < 4; ++r) pk.h4[r] = (__bf16)acc[mt][nt][r];
                *(uint2*)&vpT[((size_t)((b * 4 + h) * 64 + d)) * 1024 + tb] = pk.u;
            }
        }
}

// ---------------- q projection as bf16 MFMA GEMM per 32-row expert chunk -----
__global__ void __launch_bounds__(256)
qproj_mfma(const ushort* __restrict__ xb, const ushort* __restrict__ wmapT,
           const int* __restrict__ perm,
           const int* __restrict__ rbe2, const int* __restrict__ rbs2,
           const int* __restrict__ rbc2,
           float* __restrict__ qp, ushort* __restrict__ qpb) {
    int blk = blockIdx.x;
    int nr = rbc2[blk];
    if (nr == 0) return;
    int e = rbe2[blk], rs = rbs2[blk];
    int tid = threadIdx.x, w = tid >> 6, L = tid & 63;
    __shared__ __align__(16) ushort As[2][32 * 64];
    __shared__ __align__(16) ushort Bs[2][4 * 64 * 64];
    __shared__ int rows2[32];
    if (tid < 32) rows2[tid] = (tid < nr) ? perm[rs + tid] : -1;
    __syncthreads();

    int swz = ((L & 7) ^ ((L >> 3) & 7)) * 8;
    int ar = rows2[w * 8 + (L >> 3)];
    const ushort* asrc = xb + (size_t)((ar < 0 ? 0 : ar) >> 2) * 1024 + swz;
    const ushort* bsrc = wmapT + ((size_t)e << 18) + (size_t)(w * 64 + (L >> 3)) * 1024 + swz;

    f32x4 acc[2][4];
#pragma unroll
    for (int mt = 0; mt < 2; ++mt)
#pragma unroll
        for (int nt = 0; nt < 4; ++nt) acc[mt][nt] = (f32x4){0.f, 0.f, 0.f, 0.f};

    auto stage = [&](int kt, int bf) {
        async16(asrc + kt * 64, &As[bf][w * 512]);
#pragma unroll
        for (int q = 0; q < 8; ++q)
            async16(bsrc + (size_t)q * 8192 + kt * 64, &Bs[bf][(w * 64 + q * 8) * 64]);
    };
    auto compute = [&](int bf) {
        const ushort* AB = As[bf];
        const ushort* BB = Bs[bf] + w * 4096;
#pragma unroll
        for (int ks = 0; ks < 2; ++ks) {
            int phys = (((ks * 4 + (L >> 4)) ^ (L & 7))) * 8;
            bf16x8 a0 = *(const bf16x8*)(AB + (L & 15) * 64 + phys);
            bf16x8 a1 = *(const bf16x8*)(AB + (16 + (L & 15)) * 64 + phys);
#pragma unroll
            for (int nt = 0; nt < 4; ++nt) {
                bf16x8 b = *(const bf16x8*)(BB + (nt * 16 + (L & 15)) * 64 + phys);
                acc[0][nt] = __builtin_amdgcn_mfma_f32_16x16x32_bf16(a0, b, acc[0][nt], 0, 0, 0);
                acc[1][nt] = __builtin_amdgcn_mfma_f32_16x16x32_bf16(a1, b, acc[1][nt], 0, 0, 0);
            }
        }
    };

    stage(0, 0);
    for (int t = 0; t < 16; ++t) {
        __syncthreads();
        if (t < 15) stage(t + 1, (t + 1) & 1);
        compute(t & 1);
    }

#pragma unroll
    for (int mt = 0; mt < 2; ++mt)
#pragma unroll
        for (int nt = 0; nt < 4; ++nt) {
            int n = w * 64 + nt * 16 + (L & 15);
#pragma unroll
            for (int r = 0; r < 4; ++r) {
                int m = mt * 16 + (L >> 4) * 4 + r;
                int rowg = rows2[m];
                if (rowg >= 0) {
                    float v = acc[mt][nt][r] * sc_();
                    qp[(size_t)rowg * ED_ + n] = v;
                    union { __bf16 h; ushort u; } cv; cv.h = (__bf16)v;
                    qpb[(size_t)rowg * ED_ + n] = cv.u;
                }
            }
        }
}

// ---------------- rel bias table: rel[bkh,i,p] = q_row . rpe[h,:,p] ----------
__global__ void rel_kernel(const float* __restrict__ qp, const float* __restrict__ rpe,
                           float* __restrict__ rel) {
    int Rr = blockIdx.x * 2 + (threadIdx.x >> 7);
    int p = threadIdx.x & 127;
    int i = Rr & 1023, h = (Rr >> 10) & 3, kk = (Rr >> 12) & 3, bb = Rr >> 14;
    int row = ((i * 2 + bb) << 2) | kk;
    int qbase = __builtin_amdgcn_readfirstlane(row * ED_ + h * HD_);
    int hbase = __builtin_amdgcn_readfirstlane(h * HD_);
    float acc = 0.f;
    for (int d = 0; d < HD_; ++d)
        acc += qp[qbase + d] * rpe[(hbase + d) * 129 + p];
    rel[Rr * 128 + p] = acc;
}

// ---------------- MFMA flash attention (bf16, no-max softmax) ----------------
// epilogue writes split-precision azd[row][768] = [a_hi | a_lo | a_hi] (bf16)
__global__ void __launch_bounds__(256)
attn_kernel(const ushort* __restrict__ qpb, const ushort* __restrict__ kpb,
            const ushort* __restrict__ vpT, const float* __restrict__ rel,
            const float* __restrict__ gates, ushort* __restrict__ azd) {
    __shared__ __align__(16) ushort Ks[2][64 * 64];
    __shared__ __align__(16) ushort Vs[2][64 * 64];
    __shared__ __align__(16) ushort Ps[4][16 * 64];

    const int tid = threadIdx.x;
    const int w = tid >> 6, L = tid & 63;
    const int bkh = blockIdx.x & 31, it = blockIdx.x >> 5;
    const int h = bkh & 3, kk = (bkh >> 2) & 3, bb = bkh >> 4;
    const int i0w = it * 64 + w * 16;
    const int iL = i0w + (L & 15);
    const int row = ((iL * 2 + bb) << 2) | kk;

    const ushort* qrow = qpb + row * ED_ + h * HD_;
    bf16x8 qf0 = *(const bf16x8*)(qrow + (L >> 4) * 8);
    bf16x8 qf1 = *(const bf16x8*)(qrow + 32 + (L >> 4) * 8);

    const float* relrow = rel + ((size_t)((bkh << 10) + iL)) * 128;
    float rel_lo = relrow[1], rel_hi = relrow[127];
    float gate = gates[row];

    f32x4 O[4];
#pragma unroll
    for (int mf = 0; mf < 4; ++mf) O[mf] = (f32x4){0.f, 0.f, 0.f, 0.f};
    float l_acc = 0.f;

    const ushort* ksrc = kpb + (size_t)(bb << 10) * ED_ + h * HD_;
    const ushort* vsrc = vpT + (size_t)((bb * 4 + h) * 64) * 1024;

    auto stage = [&](int t, int bf) {
        int j0 = t * 64;
#pragma unroll
        for (int q = 0; q < 2; ++q) {
            int r = L >> 3;
            int c = (L & 7) ^ r;
            const ushort* src = ksrc + (size_t)(j0 + w * 16 + q * 8 + r) * ED_ + c * 8;
            async16(src, &Ks[bf][(w * 16 + q * 8) * 64]);
        }
#pragma unroll
        for (int q = 0; q < 2; ++q) {
            int r = L >> 3;
            int d = w * 16 + q * 8 + r;
            int c = (L & 7) ^ (d & 7);
            const ushort* src = vsrc + (size_t)d * 1024 + j0 + c * 8;
            async16(src, &Vs[bf][(w * 16 + q * 8) * 64]);
        }
    };

    auto compute = [&](int bf, int j0) {
        const ushort* KB = Ks[bf];
        const ushort* VB = Vs[bf];
        ushort* PW = Ps[w];
#pragma unroll
        for (int jf = 0; jf < 4; ++jf) {
            int jrow = jf * 16 + (L & 15);
            bf16x8 a0 = *(const bf16x8*)(KB + jrow * 64 + (((L >> 4)) ^ (L & 7)) * 8);
            bf16x8 a1 = *(const bf16x8*)(KB + jrow * 64 + ((4 + (L >> 4)) ^ (L & 7)) * 8);
            f32x4 s = (f32x4){0.f, 0.f, 0.f, 0.f};
            s = __builtin_amdgcn_mfma_f32_16x16x32_bf16(a0, qf0, s, 0, 0, 0);
            s = __builtin_amdgcn_mfma_f32_16x16x32_bf16(a1, qf1, s, 0, 0, 0);
            int jlo = j0 + jf * 16;
            int jbase = jlo + (L >> 4) * 4;
            float pv[4];
            if (jlo >= i0w + 78) {
#pragma unroll
                for (int r = 0; r < 4; ++r) pv[r] = __expf(s[r] + rel_hi);
            } else if (jlo <= i0w - 78) {
#pragma unroll
                for (int r = 0; r < 4; ++r) pv[r] = __expf(s[r] + rel_lo);
            } else {
#pragma unroll
                for (int r = 0; r < 4; ++r) {
                    int dj = jbase + r - iL;
                    dj = dj < -63 ? -63 : (dj > 63 ? 63 : dj);
                    pv[r] = __expf(s[r] + relrow[dj + 64]);
                }
            }
            l_acc += (pv[0] + pv[1]) + (pv[2] + pv[3]);
            union { __bf16 h4[4]; uint2 u; } pk;
#pragma unroll
            for (int r = 0; r < 4; ++r) pk.h4[r] = (__bf16)pv[r];
            int iloc = L & 15;
            int chunk = jf * 2 + ((L >> 4) >> 1);
            int phys = chunk ^ (iloc & 7);
            *(uint2*)(PW + iloc * 64 + phys * 8 + ((L >> 4) & 1) * 4) = pk.u;
        }
#pragma unroll
        for (int ks = 0; ks < 2; ++ks) {
            int c = ks * 4 + (L >> 4);
            int phys = c ^ (L & 7);
            bf16x8 pf = *(const bf16x8*)(PW + (L & 15) * 64 + phys * 8);
#pragma unroll
            for (int mf = 0; mf < 4; ++mf) {
                bf16x8 vf = *(const bf16x8*)(VB + (mf * 16 + (L & 15)) * 64 + phys * 8);
                O[mf] = __builtin_amdgcn_mfma_f32_16x16x32_bf16(vf, pf, O[mf], 0, 0, 0);
            }
        }
    };

    stage(0, 0);
    for (int t = 0; t < 16; ++t) {
        __syncthreads();
        if (t < 15) stage(t + 1, (t + 1) & 1);
        compute(t & 1, t * 64);
    }

    l_acc += __shfl_xor(l_acc, 16);
    l_acc += __shfl_xor(l_acc, 32);
    float inv = gate / l_acc;
    ushort* azrow = azd + (size_t)row * KR_ + h * HD_;
#pragma unroll
    for (int mf = 0; mf < 4; ++mf) {
        union { __bf16 h4[4]; uint2 u; } hi, lo;
#pragma unroll
        for (int r = 0; r < 4; ++r) {
            float v = O[mf][r] * inv;
            hi.h4[r] = (__bf16)v;
            lo.h4[r] = (__bf16)(v - (float)hi.h4[r]);
        }
        int off = mf * 16 + (L >> 4) * 4;
        *(uint2*)(azrow + off) = hi.u;
        *(uint2*)(azrow + 256 + off) = lo.u;
        *(uint2*)(azrow + 512 + off) = hi.u;
    }
}

// ---------------- zero the output (reduce accumulates atomically) ------------
__global__ void zero_out(float* __restrict__ out) {
    int t = blockIdx.x * 256 + threadIdx.x;       // N_*D_/4 threads
    *(float4*)(out + (size_t)t * 4) = make_float4(0.f, 0.f, 0.f, 0.f);
}

// ---------------- expert reduce as bf16 MFMA (split precision, K=768) --------
// 128-row chunks x 128-col tiles, grid (PB3_MAX, 8). Epilogue: HW f32 atomics
// into out (fuses the former combine_out): out[row>>2][d] += acc.
__global__ void __launch_bounds__(256)
reduce_mfma(const ushort* __restrict__ azd, const ushort* __restrict__ wredT3,
            const int* __restrict__ perm,
            const int* __restrict__ rbe3, const int* __restrict__ rbs3,
            const int* __restrict__ rbc3, float* __restrict__ out) {
    int blk = blockIdx.x;
    int nr = rbc3[blk];
    if (nr == 0) return;
    int e = rbe3[blk], rs = rbs3[blk];
    int n0 = blockIdx.y * 128;
    int tid = threadIdx.x, w = tid >> 6, L = tid & 63;
    __shared__ __align__(16) ushort As[2][128 * 64];   // 32 KB
    __shared__ __align__(16) ushort Bs[2][128 * 64];   // 32 KB
    __shared__ int rows3[128];
    if (tid < 128) rows3[tid] = (tid < nr) ? perm[rs + tid] : -1;
    __syncthreads();

    int swz = ((L & 7) ^ ((L >> 3) & 7)) * 8;
    const ushort* asrc[4];
#pragma unroll
    for (int q = 0; q < 4; ++q) {
        int ar = rows3[q * 32 + w * 8 + (L >> 3)];
        asrc[q] = azd + (size_t)(ar < 0 ? 0 : ar) * KR_ + swz;
    }
    const ushort* bsrc = wredT3 + (size_t)e * (D_ * KR_)
                       + (size_t)(n0 + w * 8 + (L >> 3)) * KR_ + swz;

    f32x4 acc[2][8];
#pragma unroll
    for (int mt = 0; mt < 2; ++mt)
#pragma unroll
        for (int nt = 0; nt < 8; ++nt) acc[mt][nt] = (f32x4){0.f, 0.f, 0.f, 0.f};

    auto stage = [&](int kt, int bf) {
#pragma unroll
        for (int q = 0; q < 4; ++q)
            async16(asrc[q] + kt * 64, &As[bf][(q * 32 + w * 8) * 64]);
#pragma unroll
        for (int q = 0; q < 4; ++q)
            async16(bsrc + (size_t)(q * 32) * KR_ + kt * 64, &Bs[bf][(q * 32 + w * 8) * 64]);
    };
    auto compute = [&](int bf) {
        const ushort* AB = As[bf] + w * 32 * 64;     // wave owns rows w*32..+31
        const ushort* BB = Bs[bf];                   // all waves share 128 cols
#pragma unroll
        for (int ks = 0; ks < 2; ++ks) {
            int phys = (((ks * 4 + (L >> 4)) ^ (L & 7))) * 8;
            bf16x8 a0 = *(const bf16x8*)(AB + (L & 15) * 64 + phys);
            bf16x8 a1 = *(const bf16x8*)(AB + (16 + (L & 15)) * 64 + phys);
#pragma unroll
            for (int nt = 0; nt < 8; ++nt) {
                bf16x8 b = *(const bf16x8*)(BB + (nt * 16 + (L & 15)) * 64 + phys);
                acc[0][nt] = __builtin_amdgcn_mfma_f32_16x16x32_bf16(a0, b, acc[0][nt], 0, 0, 0);
                acc[1][nt] = __builtin_amdgcn_mfma_f32_16x16x32_bf16(a1, b, acc[1][nt], 0, 0, 0);
            }
        }
    };

    stage(0, 0);
    for (int t = 0; t < 12; ++t) {       // K = 768 -> 12 tiles of 64
        __syncthreads();
        if (t < 11) stage(t + 1, (t + 1) & 1);
        compute(t & 1);
    }

#pragma unroll
    for (int mt = 0; mt < 2; ++mt)
#pragma unroll
        for (int nt = 0; nt < 8; ++nt) {
            int n = n0 + nt * 16 + (L & 15);
#pragma unroll
            for (int r = 0; r < 4; ++r) {
                int m = w * 32 + mt * 16 + (L >> 4) * 4 + r;
                int rowg = rows3[m];
                if (rowg >= 0)
                    unsafeAtomicAdd(out + (size_t)(rowg >> 2) * D_ + n, acc[mt][nt][r]);
            }
        }
}

// ---------------- launcher ---------------------------------------------------
extern "C" void kernel_launch(void* const* d_in, const int* in_sizes, int n_in,
                              void* d_out, int out_size, void* d_ws, size_t ws_size,
                              hipStream_t stream) {
    const float* query = (const float*)d_in[0];
    const float* key   = (const float*)d_in[1];
    const float* value = (const float*)d_in[2];
    const float* wg    = (const float*)d_in[3];
    const float* wmap  = (const float*)d_in[4];
    const float* wred  = (const float*)d_in[5];
    const float* wk    = (const float*)d_in[6];
    const float* wv    = (const float*)d_in[7];
    const float* rpe   = (const float*)d_in[8];
    float* out = (float*)d_out;

    char* ws = (char*)d_ws;
    float*  gates = (float*)(ws + 0);                      // 32 KB
    int*    idx   = (int*)(ws + (32 << 10));               // 32 KB
    char*   misc  = ws + (64 << 10);
    int*    offs   = (int*)(misc + 128);                   // 13 ints
    int*    bcnt   = (int*)(misc + 1024);                  // 32*12 ints
    int*    base   = (int*)(misc + 3072);                  // 32*12 ints
    int*    rbe2   = (int*)(misc + 8192);
    int*    rbs2   = (int*)(misc + 9472);
    int*    rbc2   = (int*)(misc + 10752);
    int*    rbe3   = (int*)(misc + 12288);                 // 76 ints
    int*    rbs3   = (int*)(misc + 12800);                 // 76 ints
    int*    rbc3   = (int*)(misc + 13312);                 // 76 ints
    int*    perm  = (int*)(ws + (96 << 10));               // 32 KB
    char*   base_ = ws + (128 << 10);
    float*  qp    = (float*)(base_);                       // 8 MB f32 (rel input)
    ushort* qpb   = (ushort*)(base_ + (8u  << 20));        // 4 MB
    ushort* kpb   = (ushort*)(base_ + (12u << 20));        // 1 MB [b][t][ed]
    ushort* vpT   = (ushort*)(base_ + (13u << 20));        // 1 MB [b][h][d][t]
    ushort* xb    = (ushort*)(base_ + (14u << 20));        // 4 MB
    ushort* wmapT = (ushort*)(base_ + (18u << 20));        // 6 MB
    ushort* keyb  = (ushort*)(base_ + (24u << 20));        // 4 MB
    ushort* valb  = (ushort*)(base_ + (28u << 20));        // 4 MB
    ushort* wkT   = (ushort*)(base_ + (32u << 20));        // 0.5 MB
    ushort* wvT   = (ushort*)(base_ + (32u << 20) + (512u << 10)); // 0.5 MB
    ushort* azd   = (ushort*)(base_ + (48u << 20));        // 12.6 MB [row][768]
    ushort* wredT3= (ushort*)(base_ + (61u << 20));        // 18.9 MB [e][d][768]
    float*  rel   = (float*)(base_ + (80u << 20));         // 16 MB
    float*  wgT   = (float*)(base_ + (96u << 20));         // 48 KB f32 [e][d]

    zero_out<<<(N_ * D_) / 1024, 256, 0, stream>>>(out);
    castwg_kernel<<<D_ / 256, 256, 0, stream>>>(wg, wgT);
    castx_kernel<<<(N_ * D_) / 1024, 256, 0, stream>>>(query, xb);
    castx_kernel<<<(N_ * D_) / 1024, 256, 0, stream>>>(key, keyb);
    castx_kernel<<<(N_ * D_) / 1024, 256, 0, stream>>>(value, valb);
    castw_kernel<<<dim3(E_, 16, 4), 256, 0, stream>>>(wmap, wmapT);
    castwkv_kernel<<<dim3(2, 16, 4), 256, 0, stream>>>(wk, wv, wkT, wvT);
    castwred_kernel<<<dim3(E_, 4, 16), 256, 0, stream>>>(wred, wredT3);
    gate_kernel<<<N_ / 4, 256, 0, stream>>>(query, wgT, gates, idx);
    hist_kernel<<<NROW / 256, 256, 0, stream>>>(idx, bcnt);
    scan_kernel<<<1, 64, 0, stream>>>(bcnt, offs, base, rbe2, rbs2, rbc2, rbe3, rbs3, rbc3);
    scatter_kernel<<<NROW / 256, 256, 0, stream>>>(idx, base, perm);
    kv_mfma<<<dim3(64, 2), 256, 0, stream>>>(keyb, valb, wkT, wvT, kpb, vpT);
    qproj_mfma<<<PB_MAX, 256, 0, stream>>>(xb, wmapT, perm, rbe2, rbs2, rbc2, qp, qpb);
    rel_kernel<<<(32 * T_) / 2, 256, 0, stream>>>(qp, rpe, rel);
    attn_kernel<<<512, 256, 0, stream>>>(qpb, kpb, vpT, rel, gates, azd);
    reduce_mfma<<<dim3(PB3_MAX, 8), 256, 0, stream>>>(azd, wredT3, perm, rbe3, rbs3, rbc3, out);
}

// Round 2
// 297.703 us; speedup vs baseline: 1.0718x; 1.0718x over previous
//
#include <hip/hip_runtime.h>

#define T_    1024
#define B_    2
#define D_    1024
#define E_    12
#define TOPK  4
#define ED_   256
#define HD_   64
#define H_    4
#define N_    (T_*B_)      // 2048 tokens
#define NROW  (N_*TOPK)    // 8192 (n,k) rows
#define PB_MAX 268         // max 32-row expert chunks: 8192/32 + 12
#define PB3_MAX 76         // max 128-row expert chunks: 8192/128 + 12
#define KA_   256          // reduce K (f16 single-pass: ED_)

typedef __bf16 bf16x8 __attribute__((ext_vector_type(8)));
typedef _Float16 f16x8 __attribute__((ext_vector_type(8)));
typedef float  f32x4  __attribute__((ext_vector_type(4)));

__device__ __forceinline__ float sc_() { return 0.35355339059327373f; } // 64^-0.25

__device__ __forceinline__ void async16(const void* g, void* l) {
    __builtin_amdgcn_global_load_lds((const __attribute__((address_space(1))) void*)g,
                                     (__attribute__((address_space(3))) void*)l, 16, 0, 0);
}

// ---------------- one-time: wgT[e][d] = wg[d][e] (f32, 48 KB) ----------------
__global__ void castwg_kernel(const float* __restrict__ wg, float* __restrict__ wgT) {
    int d = blockIdx.x * 256 + threadIdx.x;   // grid 4 x 256
#pragma unroll
    for (int e = 0; e < E_; ++e) wgT[e * D_ + d] = wg[d * E_ + e];
}

// ---------------- gating: wave per token, NO atomics -------------------------
__global__ void __launch_bounds__(256)
gate_kernel(const float* __restrict__ x, const float* __restrict__ wgT,
            float* __restrict__ gates, int* __restrict__ idx) {
    int w = threadIdx.x >> 6, L = threadIdx.x & 63;
    int n = blockIdx.x * 4 + w;
    const float* xr = x + (size_t)n * D_;
    float acc[E_];
#pragma unroll
    for (int e = 0; e < E_; ++e) acc[e] = 0.f;
#pragma unroll
    for (int it = 0; it < 4; ++it) {
        float4 xv = *(const float4*)(xr + it * 256 + L * 4);
#pragma unroll
        for (int e = 0; e < E_; ++e) {
            float4 wv = *(const float4*)(wgT + e * D_ + it * 256 + L * 4);
            acc[e] += xv.x * wv.x + xv.y * wv.y + xv.z * wv.z + xv.w * wv.w;
        }
    }
#pragma unroll
    for (int e = 0; e < E_; ++e) {
        float v = acc[e];
        for (int o = 32; o > 0; o >>= 1) v += __shfl_down(v, o);
        acc[e] = v;
    }
    if (L == 0) {
        float mx = acc[0];
        for (int e = 1; e < E_; ++e) mx = fmaxf(mx, acc[e]);
        float s = 0.f, pr[E_];
        for (int e = 0; e < E_; ++e) { pr[e] = expf(acc[e] - mx); s += pr[e]; }
        float inv = 1.f / s;
        for (int e = 0; e < E_; ++e) pr[e] *= inv;
        for (int k = 0; k < TOPK; ++k) {
            int be = 0; float bv = -1.f;
            for (int e = 0; e < E_; ++e) if (pr[e] > bv) { bv = pr[e]; be = e; }
            gates[n * TOPK + k] = bv;
            idx[n * TOPK + k] = be;
            pr[be] = -1.f;
        }
    }
}

// ---------------- hist: per-block expert counts via ballot (no atomics) ------
// grid 32, block 256: block b covers rows b*256..+255
__global__ void hist_kernel(const int* __restrict__ idx, int* __restrict__ bcnt) {
    int b = blockIdx.x, tid = threadIdx.x, w = tid >> 6, L = tid & 63;
    int e = idx[b * 256 + tid];
    __shared__ int wcnt[4][E_];
#pragma unroll
    for (int e0 = 0; e0 < E_; ++e0) {
        unsigned long long m = __ballot(e == e0);
        if (L == 0) wcnt[w][e0] = (int)__popcll(m);
    }
    __syncthreads();
    if (tid < E_) bcnt[b * E_ + tid] = wcnt[0][tid] + wcnt[1][tid] + wcnt[2][tid] + wcnt[3][tid];
}

// ---------------- scan: offsets + per-block bases + chunk maps (32 & 128) ----
__global__ void scan_kernel(const int* __restrict__ bcnt, int* __restrict__ offs,
                            int* __restrict__ base,
                            int* __restrict__ rbe2, int* __restrict__ rbs2,
                            int* __restrict__ rbc2,
                            int* __restrict__ rbe3, int* __restrict__ rbs3,
                            int* __restrict__ rbc3) {
    if (threadIdx.x == 0 && blockIdx.x == 0) {
        int counts[E_], offl[E_ + 1];
        for (int e = 0; e < E_; ++e) {
            int s = 0;
            for (int b = 0; b < 32; ++b) s += bcnt[b * E_ + e];
            counts[e] = s;
        }
        int o = 0;
        for (int e = 0; e < E_; ++e) { offl[e] = o; o += counts[e]; }
        offl[E_] = o;
        for (int e = 0; e <= E_; ++e) offs[e] = offl[e];
        for (int e = 0; e < E_; ++e) {
            int run = offl[e];
            for (int b = 0; b < 32; ++b) { base[b * E_ + e] = run; run += bcnt[b * E_ + e]; }
        }
        int nb2 = 0;
        for (int e = 0; e < E_; ++e) {
            int c = counts[e];
            for (int s = 0; s < c; s += 32) {
                rbe2[nb2] = e; rbs2[nb2] = offl[e] + s;
                rbc2[nb2] = (c - s < 32) ? (c - s) : 32; ++nb2;
            }
        }
        for (; nb2 < PB_MAX; ++nb2) { rbe2[nb2] = 0; rbs2[nb2] = 0; rbc2[nb2] = 0; }
        int nb3 = 0;
        for (int e = 0; e < E_; ++e) {
            int c = counts[e];
            for (int s = 0; s < c; s += 128) {
                rbe3[nb3] = e; rbs3[nb3] = offl[e] + s;
                rbc3[nb3] = (c - s < 128) ? (c - s) : 128; ++nb3;
            }
        }
        for (; nb3 < PB3_MAX; ++nb3) { rbe3[nb3] = 0; rbs3[nb3] = 0; rbc3[nb3] = 0; }
    }
}

// ---------------- scatter via ballot rank (no atomics) -----------------------
__global__ void scatter_kernel(const int* __restrict__ idx, const int* __restrict__ base,
                               int* __restrict__ perm) {
    int b = blockIdx.x, tid = threadIdx.x, w = tid >> 6, L = tid & 63;
    int r = b * 256 + tid;
    int e = idx[r];
    __shared__ int wcnt[4][E_];
    int rankw = 0;
#pragma unroll
    for (int e0 = 0; e0 < E_; ++e0) {
        unsigned long long m = __ballot(e == e0);
        if (e == e0) rankw = (int)__popcll(m & ((1ULL << L) - 1ULL));
        if (L == 0) wcnt[w][e0] = (int)__popcll(m);
    }
    __syncthreads();
    int pre = 0;
    for (int w2 = 0; w2 < w; ++w2) pre += wcnt[w2][e];
    perm[base[b * E_ + e] + pre + rankw] = r;
}

// ---------------- one-time casts ---------------------------------------------
__global__ void castx_kernel(const float* __restrict__ x, ushort* __restrict__ xb) {
    int t = blockIdx.x * 256 + threadIdx.x;
    float4 v = *(const float4*)(x + (size_t)t * 4);
    union { __bf16 h[4]; uint2 u; } pk;
    pk.h[0] = (__bf16)v.x; pk.h[1] = (__bf16)v.y;
    pk.h[2] = (__bf16)v.z; pk.h[3] = (__bf16)v.w;
    *(uint2*)(xb + (size_t)t * 4) = pk.u;
}

// grid (12,16,4): e, 64-d tile, 64-ed tile.  wmapT[e][ed][d] = bf16(w_map[e][d][ed])
__global__ void castw_kernel(const float* __restrict__ wmap, ushort* __restrict__ wmapT) {
    int e = blockIdx.x, dt = blockIdx.y, et = blockIdx.z;
    __shared__ float ls[64][65];
    int c = threadIdx.x & 63, rg = threadIdx.x >> 6;
    const float* src = wmap + (size_t)e * (D_ * ED_) + (size_t)(dt * 64) * ED_ + et * 64;
#pragma unroll
    for (int q = 0; q < 16; ++q) {
        int r = q * 4 + rg;
        ls[r][c] = src[(size_t)r * ED_ + c];
    }
    __syncthreads();
    ushort* dst = wmapT + ((size_t)e << 18) + (size_t)(et * 64) * 1024 + dt * 64;
#pragma unroll
    for (int q = 0; q < 16; ++q) {
        int r = q * 4 + rg;
        union { __bf16 h; ushort u; } cv; cv.h = (__bf16)ls[c][r];
        dst[(size_t)r * 1024 + c] = cv.u;
    }
}

// grid (2,16,4): which, 64-d tile, 64-ed tile. wT[ed][d] = bf16(w[d][ed])
__global__ void castwkv_kernel(const float* __restrict__ wk, const float* __restrict__ wv,
                               ushort* __restrict__ wkT, ushort* __restrict__ wvT) {
    int which = blockIdx.x, dt = blockIdx.y, et = blockIdx.z;
    const float* w = which ? wv : wk;
    ushort* wT = which ? wvT : wkT;
    __shared__ float ls[64][65];
    int c = threadIdx.x & 63, rg = threadIdx.x >> 6;
    const float* src = w + (size_t)(dt * 64) * ED_ + et * 64;
#pragma unroll
    for (int q = 0; q < 16; ++q) {
        int r = q * 4 + rg;
        ls[r][c] = src[(size_t)r * ED_ + c];
    }
    __syncthreads();
    ushort* dst = wT + (size_t)(et * 64) * 1024 + dt * 64;
#pragma unroll
    for (int q = 0; q < 16; ++q) {
        int r = q * 4 + rg;
        union { __bf16 h; ushort u; } cv; cv.h = (__bf16)ls[c][r];
        dst[(size_t)r * 1024 + c] = cv.u;
    }
}

// grid (12,4,16): e, 64-ed tile, 64-d tile.
// wredf[e][d][ed] = f16(w_reduce[e][ed][d])  (transpose, single precision pass)
__global__ void castwred_kernel(const float* __restrict__ wred, ushort* __restrict__ wredf) {
    int e = blockIdx.x, et = blockIdx.y, dt = blockIdx.z;
    __shared__ float ls[64][65];
    int c = threadIdx.x & 63, rg = threadIdx.x >> 6;
    const float* src = wred + (size_t)e * (ED_ * D_) + (size_t)(et * 64) * D_ + dt * 64;
#pragma unroll
    for (int q = 0; q < 16; ++q) {
        int r = q * 4 + rg;           // ed-local
        ls[r][c] = src[(size_t)r * D_ + c];
    }
    __syncthreads();
    ushort* dst = wredf + (size_t)e * (D_ * KA_) + (size_t)(dt * 64) * KA_ + et * 64;
#pragma unroll
    for (int q = 0; q < 16; ++q) {
        int r = q * 4 + rg;           // d-local
        union { _Float16 h; ushort u; } cv; cv.h = (_Float16)ls[c][r];
        dst[(size_t)r * KA_ + c] = cv.u;
    }
}

// ---------------- k/v projection as bf16 MFMA GEMM ---------------------------
__global__ void __launch_bounds__(256)
kv_mfma(const ushort* __restrict__ keyb, const ushort* __restrict__ valb,
        const ushort* __restrict__ wkT, const ushort* __restrict__ wvT,
        ushort* __restrict__ kpb, ushort* __restrict__ vpT) {
    int which = blockIdx.y;
    const ushort* xb = which ? valb : keyb;
    const ushort* wT = which ? wvT : wkT;
    int m0 = blockIdx.x * 32;
    int b = m0 >> 10, t0 = m0 & 1023;
    int tid = threadIdx.x, w = tid >> 6, L = tid & 63;
    __shared__ __align__(16) ushort As[2][32 * 64];
    __shared__ __align__(16) ushort Bs[2][4 * 64 * 64];

    int swz = ((L & 7) ^ ((L >> 3) & 7)) * 8;
    int an = (((t0 + w * 8 + (L >> 3)) << 1) | b);
    const ushort* asrc = xb + (size_t)an * 1024 + swz;
    const ushort* bsrc = wT + (size_t)(w * 64 + (L >> 3)) * 1024 + swz;

    f32x4 acc[2][4];
#pragma unroll
    for (int mt = 0; mt < 2; ++mt)
#pragma unroll
        for (int nt = 0; nt < 4; ++nt) acc[mt][nt] = (f32x4){0.f, 0.f, 0.f, 0.f};

    auto stage = [&](int kt, int bf) {
        async16(asrc + kt * 64, &As[bf][w * 512]);
#pragma unroll
        for (int q = 0; q < 8; ++q)
            async16(bsrc + (size_t)q * 8192 + kt * 64, &Bs[bf][(w * 64 + q * 8) * 64]);
    };
    auto compute = [&](int bf) {
        const ushort* AB = As[bf];
        const ushort* BB = Bs[bf] + w * 4096;
#pragma unroll
        for (int ks = 0; ks < 2; ++ks) {
            int phys = (((ks * 4 + (L >> 4)) ^ (L & 7))) * 8;
            bf16x8 a0 = *(const bf16x8*)(AB + (L & 15) * 64 + phys);
            bf16x8 a1 = *(const bf16x8*)(AB + (16 + (L & 15)) * 64 + phys);
#pragma unroll
            for (int nt = 0; nt < 4; ++nt) {
                bf16x8 bfr = *(const bf16x8*)(BB + (nt * 16 + (L & 15)) * 64 + phys);
                acc[0][nt] = __builtin_amdgcn_mfma_f32_16x16x32_bf16(a0, bfr, acc[0][nt], 0, 0, 0);
                acc[1][nt] = __builtin_amdgcn_mfma_f32_16x16x32_bf16(a1, bfr, acc[1][nt], 0, 0, 0);
            }
        }
    };

    stage(0, 0);
    for (int t = 0; t < 16; ++t) {
        __syncthreads();
        if (t < 15) stage(t + 1, (t + 1) & 1);
        compute(t & 1);
    }

#pragma unroll
    for (int mt = 0; mt < 2; ++mt)
#pragma unroll
        for (int nt = 0; nt < 4; ++nt) {
            int ed = w * 64 + nt * 16 + (L & 15);
            int tb = t0 + mt * 16 + (L >> 4) * 4;
            if (which == 0) {
#pragma unroll
                for (int r = 0; r < 4; ++r) {
                    union { __bf16 h; ushort u; } cv;
                    cv.h = (__bf16)(acc[mt][nt][r] * sc_());
                    kpb[((size_t)((b << 10) + tb + r)) * ED_ + ed] = cv.u;
                }
            } else {
                int h = ed >> 6, d = ed & 63;
                union { __bf16 h4[4]; uint2 u; } pk;
#pragma unroll
                for (int r = 0; r < 4; ++r) pk.h4[r] = (__bf16)acc[mt][nt][r];
                *(uint2*)&vpT[((size_t)((b * 4 + h) * 64 + d)) * 1024 + tb] = pk.u;
            }
        }
}

// ---------------- q projection as bf16 MFMA GEMM per 32-row expert chunk -----
__global__ void __launch_bounds__(256)
qproj_mfma(const ushort* __restrict__ xb, const ushort* __restrict__ wmapT,
           const int* __restrict__ perm,
           const int* __restrict__ rbe2, const int* __restrict__ rbs2,
           const int* __restrict__ rbc2,
           float* __restrict__ qp, ushort* __restrict__ qpb) {
    int blk = blockIdx.x;
    int nr = rbc2[blk];
    if (nr == 0) return;
    int e = rbe2[blk], rs = rbs2[blk];
    int tid = threadIdx.x, w = tid >> 6, L = tid & 63;
    __shared__ __align__(16) ushort As[2][32 * 64];
    __shared__ __align__(16) ushort Bs[2][4 * 64 * 64];
    __shared__ int rows2[32];
    if (tid < 32) rows2[tid] = (tid < nr) ? perm[rs + tid] : -1;
    __syncthreads();

    int swz = ((L & 7) ^ ((L >> 3) & 7)) * 8;
    int ar = rows2[w * 8 + (L >> 3)];
    const ushort* asrc = xb + (size_t)((ar < 0 ? 0 : ar) >> 2) * 1024 + swz;
    const ushort* bsrc = wmapT + ((size_t)e << 18) + (size_t)(w * 64 + (L >> 3)) * 1024 + swz;

    f32x4 acc[2][4];
#pragma unroll
    for (int mt = 0; mt < 2; ++mt)
#pragma unroll
        for (int nt = 0; nt < 4; ++nt) acc[mt][nt] = (f32x4){0.f, 0.f, 0.f, 0.f};

    auto stage = [&](int kt, int bf) {
        async16(asrc + kt * 64, &As[bf][w * 512]);
#pragma unroll
        for (int q = 0; q < 8; ++q)
            async16(bsrc + (size_t)q * 8192 + kt * 64, &Bs[bf][(w * 64 + q * 8) * 64]);
    };
    auto compute = [&](int bf) {
        const ushort* AB = As[bf];
        const ushort* BB = Bs[bf] + w * 4096;
#pragma unroll
        for (int ks = 0; ks < 2; ++ks) {
            int phys = (((ks * 4 + (L >> 4)) ^ (L & 7))) * 8;
            bf16x8 a0 = *(const bf16x8*)(AB + (L & 15) * 64 + phys);
            bf16x8 a1 = *(const bf16x8*)(AB + (16 + (L & 15)) * 64 + phys);
#pragma unroll
            for (int nt = 0; nt < 4; ++nt) {
                bf16x8 b = *(const bf16x8*)(BB + (nt * 16 + (L & 15)) * 64 + phys);
                acc[0][nt] = __builtin_amdgcn_mfma_f32_16x16x32_bf16(a0, b, acc[0][nt], 0, 0, 0);
                acc[1][nt] = __builtin_amdgcn_mfma_f32_16x16x32_bf16(a1, b, acc[1][nt], 0, 0, 0);
            }
        }
    };

    stage(0, 0);
    for (int t = 0; t < 16; ++t) {
        __syncthreads();
        if (t < 15) stage(t + 1, (t + 1) & 1);
        compute(t & 1);
    }

#pragma unroll
    for (int mt = 0; mt < 2; ++mt)
#pragma unroll
        for (int nt = 0; nt < 4; ++nt) {
            int n = w * 64 + nt * 16 + (L & 15);
#pragma unroll
            for (int r = 0; r < 4; ++r) {
                int m = mt * 16 + (L >> 4) * 4 + r;
                int rowg = rows2[m];
                if (rowg >= 0) {
                    float v = acc[mt][nt][r] * sc_();
                    qp[(size_t)rowg * ED_ + n] = v;
                    union { __bf16 h; ushort u; } cv; cv.h = (__bf16)v;
                    qpb[(size_t)rowg * ED_ + n] = cv.u;
                }
            }
        }
}

// ---------------- rel bias table: rel[bkh,i,p] = q_row . rpe[h,:,p] ----------
__global__ void rel_kernel(const float* __restrict__ qp, const float* __restrict__ rpe,
                           float* __restrict__ rel) {
    int Rr = blockIdx.x * 2 + (threadIdx.x >> 7);
    int p = threadIdx.x & 127;
    int i = Rr & 1023, h = (Rr >> 10) & 3, kk = (Rr >> 12) & 3, bb = Rr >> 14;
    int row = ((i * 2 + bb) << 2) | kk;
    int qbase = __builtin_amdgcn_readfirstlane(row * ED_ + h * HD_);
    int hbase = __builtin_amdgcn_readfirstlane(h * HD_);
    float acc = 0.f;
    for (int d = 0; d < HD_; ++d)
        acc += qp[qbase + d] * rpe[(hbase + d) * 129 + p];
    rel[Rr * 128 + p] = acc;
}

// ---------------- MFMA flash attention (bf16, no-max softmax) ----------------
// epilogue writes az[row][256] = f16(attn*gate/l)
__global__ void __launch_bounds__(256)
attn_kernel(const ushort* __restrict__ qpb, const ushort* __restrict__ kpb,
            const ushort* __restrict__ vpT, const float* __restrict__ rel,
            const float* __restrict__ gates, ushort* __restrict__ az) {
    __shared__ __align__(16) ushort Ks[2][64 * 64];
    __shared__ __align__(16) ushort Vs[2][64 * 64];
    __shared__ __align__(16) ushort Ps[4][16 * 64];

    const int tid = threadIdx.x;
    const int w = tid >> 6, L = tid & 63;
    const int bkh = blockIdx.x & 31, it = blockIdx.x >> 5;
    const int h = bkh & 3, kk = (bkh >> 2) & 3, bb = bkh >> 4;
    const int i0w = it * 64 + w * 16;
    const int iL = i0w + (L & 15);
    const int row = ((iL * 2 + bb) << 2) | kk;

    const ushort* qrow = qpb + row * ED_ + h * HD_;
    bf16x8 qf0 = *(const bf16x8*)(qrow + (L >> 4) * 8);
    bf16x8 qf1 = *(const bf16x8*)(qrow + 32 + (L >> 4) * 8);

    const float* relrow = rel + ((size_t)((bkh << 10) + iL)) * 128;
    float rel_lo = relrow[1], rel_hi = relrow[127];
    float gate = gates[row];

    f32x4 O[4];
#pragma unroll
    for (int mf = 0; mf < 4; ++mf) O[mf] = (f32x4){0.f, 0.f, 0.f, 0.f};
    float l_acc = 0.f;

    const ushort* ksrc = kpb + (size_t)(bb << 10) * ED_ + h * HD_;
    const ushort* vsrc = vpT + (size_t)((bb * 4 + h) * 64) * 1024;

    auto stage = [&](int t, int bf) {
        int j0 = t * 64;
#pragma unroll
        for (int q = 0; q < 2; ++q) {
            int r = L >> 3;
            int c = (L & 7) ^ r;
            const ushort* src = ksrc + (size_t)(j0 + w * 16 + q * 8 + r) * ED_ + c * 8;
            async16(src, &Ks[bf][(w * 16 + q * 8) * 64]);
        }
#pragma unroll
        for (int q = 0; q < 2; ++q) {
            int r = L >> 3;
            int d = w * 16 + q * 8 + r;
            int c = (L & 7) ^ (d & 7);
            const ushort* src = vsrc + (size_t)d * 1024 + j0 + c * 8;
            async16(src, &Vs[bf][(w * 16 + q * 8) * 64]);
        }
    };

    auto compute = [&](int bf, int j0) {
        const ushort* KB = Ks[bf];
        const ushort* VB = Vs[bf];
        ushort* PW = Ps[w];
#pragma unroll
        for (int jf = 0; jf < 4; ++jf) {
            int jrow = jf * 16 + (L & 15);
            bf16x8 a0 = *(const bf16x8*)(KB + jrow * 64 + (((L >> 4)) ^ (L & 7)) * 8);
            bf16x8 a1 = *(const bf16x8*)(KB + jrow * 64 + ((4 + (L >> 4)) ^ (L & 7)) * 8);
            f32x4 s = (f32x4){0.f, 0.f, 0.f, 0.f};
            s = __builtin_amdgcn_mfma_f32_16x16x32_bf16(a0, qf0, s, 0, 0, 0);
            s = __builtin_amdgcn_mfma_f32_16x16x32_bf16(a1, qf1, s, 0, 0, 0);
            int jlo = j0 + jf * 16;
            int jbase = jlo + (L >> 4) * 4;
            float pv[4];
            if (jlo >= i0w + 78) {
#pragma unroll
                for (int r = 0; r < 4; ++r) pv[r] = __expf(s[r] + rel_hi);
            } else if (jlo <= i0w - 78) {
#pragma unroll
                for (int r = 0; r < 4; ++r) pv[r] = __expf(s[r] + rel_lo);
            } else {
#pragma unroll
                for (int r = 0; r < 4; ++r) {
                    int dj = jbase + r - iL;
                    dj = dj < -63 ? -63 : (dj > 63 ? 63 : dj);
                    pv[r] = __expf(s[r] + relrow[dj + 64]);
                }
            }
            l_acc += (pv[0] + pv[1]) + (pv[2] + pv[3]);
            union { __bf16 h4[4]; uint2 u; } pk;
#pragma unroll
            for (int r = 0; r < 4; ++r) pk.h4[r] = (__bf16)pv[r];
            int iloc = L & 15;
            int chunk = jf * 2 + ((L >> 4) >> 1);
            int phys = chunk ^ (iloc & 7);
            *(uint2*)(PW + iloc * 64 + phys * 8 + ((L >> 4) & 1) * 4) = pk.u;
        }
#pragma unroll
        for (int ks = 0; ks < 2; ++ks) {
            int c = ks * 4 + (L >> 4);
            int phys = c ^ (L & 7);
            bf16x8 pf = *(const bf16x8*)(PW + (L & 15) * 64 + phys * 8);
#pragma unroll
            for (int mf = 0; mf < 4; ++mf) {
                bf16x8 vf = *(const bf16x8*)(VB + (mf * 16 + (L & 15)) * 64 + phys * 8);
                O[mf] = __builtin_amdgcn_mfma_f32_16x16x32_bf16(vf, pf, O[mf], 0, 0, 0);
            }
        }
    };

    stage(0, 0);
    for (int t = 0; t < 16; ++t) {
        __syncthreads();
        if (t < 15) stage(t + 1, (t + 1) & 1);
        compute(t & 1, t * 64);
    }

    l_acc += __shfl_xor(l_acc, 16);
    l_acc += __shfl_xor(l_acc, 32);
    float inv = gate / l_acc;
    ushort* azrow = az + (size_t)row * KA_ + h * HD_;
#pragma unroll
    for (int mf = 0; mf < 4; ++mf) {
        union { _Float16 h4[4]; uint2 u; } pk;
#pragma unroll
        for (int r = 0; r < 4; ++r) pk.h4[r] = (_Float16)(O[mf][r] * inv);
        int off = mf * 16 + (L >> 4) * 4;
        *(uint2*)(azrow + off) = pk.u;
    }
}

// ---------------- zero the output (reduce accumulates atomically) ------------
__global__ void zero_out(float* __restrict__ out) {
    int t = blockIdx.x * 256 + threadIdx.x;       // N_*D_/4 threads
    *(float4*)(out + (size_t)t * 4) = make_float4(0.f, 0.f, 0.f, 0.f);
}

// ---------------- expert reduce as f16 MFMA (single pass, K=256) -------------
// 128-row chunks x 128-col tiles, grid (PB3_MAX, 8). Epilogue: HW f32 atomics
// into out (fused combine): out[row>>2][d] += acc.
__global__ void __launch_bounds__(256)
reduce_mfma(const ushort* __restrict__ az, const ushort* __restrict__ wredf,
            const int* __restrict__ perm,
            const int* __restrict__ rbe3, const int* __restrict__ rbs3,
            const int* __restrict__ rbc3, float* __restrict__ out) {
    int blk = blockIdx.x;
    int nr = rbc3[blk];
    if (nr == 0) return;
    int e = rbe3[blk], rs = rbs3[blk];
    int n0 = blockIdx.y * 128;
    int tid = threadIdx.x, w = tid >> 6, L = tid & 63;
    __shared__ __align__(16) ushort As[2][128 * 64];   // 32 KB
    __shared__ __align__(16) ushort Bs[2][128 * 64];   // 32 KB
    __shared__ int rows3[128];
    if (tid < 128) rows3[tid] = (tid < nr) ? perm[rs + tid] : -1;
    __syncthreads();

    int swz = ((L & 7) ^ ((L >> 3) & 7)) * 8;
    const ushort* asrc[4];
#pragma unroll
    for (int q = 0; q < 4; ++q) {
        int ar = rows3[q * 32 + w * 8 + (L >> 3)];
        asrc[q] = az + (size_t)(ar < 0 ? 0 : ar) * KA_ + swz;
    }
    const ushort* bsrc = wredf + (size_t)e * (D_ * KA_)
                       + (size_t)(n0 + w * 8 + (L >> 3)) * KA_ + swz;

    f32x4 acc[2][8];
#pragma unroll
    for (int mt = 0; mt < 2; ++mt)
#pragma unroll
        for (int nt = 0; nt < 8; ++nt) acc[mt][nt] = (f32x4){0.f, 0.f, 0.f, 0.f};

    auto stage = [&](int kt, int bf) {
#pragma unroll
        for (int q = 0; q < 4; ++q)
            async16(asrc[q] + kt * 64, &As[bf][(q * 32 + w * 8) * 64]);
#pragma unroll
        for (int q = 0; q < 4; ++q)
            async16(bsrc + (size_t)(q * 32) * KA_ + kt * 64, &Bs[bf][(q * 32 + w * 8) * 64]);
    };
    auto compute = [&](int bf) {
        const ushort* AB = As[bf] + w * 32 * 64;     // wave owns rows w*32..+31
        const ushort* BB = Bs[bf];                   // all waves share 128 cols
#pragma unroll
        for (int ks = 0; ks < 2; ++ks) {
            int phys = (((ks * 4 + (L >> 4)) ^ (L & 7))) * 8;
            f16x8 a0 = *(const f16x8*)(AB + (L & 15) * 64 + phys);
            f16x8 a1 = *(const f16x8*)(AB + (16 + (L & 15)) * 64 + phys);
#pragma unroll
            for (int nt = 0; nt < 8; ++nt) {
                f16x8 b = *(const f16x8*)(BB + (nt * 16 + (L & 15)) * 64 + phys);
                acc[0][nt] = __builtin_amdgcn_mfma_f32_16x16x32_f16(a0, b, acc[0][nt], 0, 0, 0);
                acc[1][nt] = __builtin_amdgcn_mfma_f32_16x16x32_f16(a1, b, acc[1][nt], 0, 0, 0);
            }
        }
    };

    stage(0, 0);
    for (int t = 0; t < 4; ++t) {        // K = 256 -> 4 tiles of 64
        __syncthreads();
        if (t < 3) stage(t + 1, (t + 1) & 1);
        compute(t & 1);
    }

#pragma unroll
    for (int mt = 0; mt < 2; ++mt)
#pragma unroll
        for (int nt = 0; nt < 8; ++nt) {
            int n = n0 + nt * 16 + (L & 15);
#pragma unroll
            for (int r = 0; r < 4; ++r) {
                int m = w * 32 + mt * 16 + (L >> 4) * 4 + r;
                int rowg = rows3[m];
                if (rowg >= 0)
                    unsafeAtomicAdd(out + (size_t)(rowg >> 2) * D_ + n, acc[mt][nt][r]);
            }
        }
}

// ---------------- launcher ---------------------------------------------------
extern "C" void kernel_launch(void* const* d_in, const int* in_sizes, int n_in,
                              void* d_out, int out_size, void* d_ws, size_t ws_size,
                              hipStream_t stream) {
    const float* query = (const float*)d_in[0];
    const float* key   = (const float*)d_in[1];
    const float* value = (const float*)d_in[2];
    const float* wg    = (const float*)d_in[3];
    const float* wmap  = (const float*)d_in[4];
    const float* wred  = (const float*)d_in[5];
    const float* wk    = (const float*)d_in[6];
    const float* wv    = (const float*)d_in[7];
    const float* rpe   = (const float*)d_in[8];
    float* out = (float*)d_out;

    char* ws = (char*)d_ws;
    float*  gates = (float*)(ws + 0);                      // 32 KB
    int*    idx   = (int*)(ws + (32 << 10));               // 32 KB
    char*   misc  = ws + (64 << 10);
    int*    offs   = (int*)(misc + 128);                   // 13 ints
    int*    bcnt   = (int*)(misc + 1024);                  // 32*12 ints
    int*    base   = (int*)(misc + 3072);                  // 32*12 ints
    int*    rbe2   = (int*)(misc + 8192);
    int*    rbs2   = (int*)(misc + 9472);
    int*    rbc2   = (int*)(misc + 10752);
    int*    rbe3   = (int*)(misc + 12288);                 // 76 ints
    int*    rbs3   = (int*)(misc + 12800);                 // 76 ints
    int*    rbc3   = (int*)(misc + 13312);                 // 76 ints
    int*    perm  = (int*)(ws + (96 << 10));               // 32 KB
    char*   base_ = ws + (128 << 10);
    float*  qp    = (float*)(base_);                       // 8 MB f32 (rel input)
    ushort* qpb   = (ushort*)(base_ + (8u  << 20));        // 4 MB
    ushort* kpb   = (ushort*)(base_ + (12u << 20));        // 1 MB [b][t][ed]
    ushort* vpT   = (ushort*)(base_ + (13u << 20));        // 1 MB [b][h][d][t]
    ushort* xb    = (ushort*)(base_ + (14u << 20));        // 4 MB
    ushort* wmapT = (ushort*)(base_ + (18u << 20));        // 6 MB
    ushort* keyb  = (ushort*)(base_ + (24u << 20));        // 4 MB
    ushort* valb  = (ushort*)(base_ + (28u << 20));        // 4 MB
    ushort* wkT   = (ushort*)(base_ + (32u << 20));        // 0.5 MB
    ushort* wvT   = (ushort*)(base_ + (32u << 20) + (512u << 10)); // 0.5 MB
    ushort* az    = (ushort*)(base_ + (48u << 20));        // 4.2 MB [row][256] f16
    ushort* wredf = (ushort*)(base_ + (61u << 20));        // 6.3 MB [e][d][256] f16
    float*  rel   = (float*)(base_ + (80u << 20));         // 16 MB
    float*  wgT   = (float*)(base_ + (96u << 20));         // 48 KB f32 [e][d]

    zero_out<<<(N_ * D_) / 1024, 256, 0, stream>>>(out);
    castwg_kernel<<<D_ / 256, 256, 0, stream>>>(wg, wgT);
    castx_kernel<<<(N_ * D_) / 1024, 256, 0, stream>>>(query, xb);
    castx_kernel<<<(N_ * D_) / 1024, 256, 0, stream>>>(key, keyb);
    castx_kernel<<<(N_ * D_) / 1024, 256, 0, stream>>>(value, valb);
    castw_kernel<<<dim3(E_, 16, 4), 256, 0, stream>>>(wmap, wmapT);
    castwkv_kernel<<<dim3(2, 16, 4), 256, 0, stream>>>(wk, wv, wkT, wvT);
    castwred_kernel<<<dim3(E_, 4, 16), 256, 0, stream>>>(wred, wredf);
    gate_kernel<<<N_ / 4, 256, 0, stream>>>(query, wgT, gates, idx);
    hist_kernel<<<NROW / 256, 256, 0, stream>>>(idx, bcnt);
    scan_kernel<<<1, 64, 0, stream>>>(bcnt, offs, base, rbe2, rbs2, rbc2, rbe3, rbs3, rbc3);
    scatter_kernel<<<NROW / 256, 256, 0, stream>>>(idx, base, perm);
    kv_mfma<<<dim3(64, 2), 256, 0, stream>>>(keyb, valb, wkT, wvT, kpb, vpT);
    qproj_mfma<<<PB_MAX, 256, 0, stream>>>(xb, wmapT, perm, rbe2, rbs2, rbc2, qp, qpb);
    rel_kernel<<<(32 * T_) / 2, 256, 0, stream>>>(qp, rpe, rel);
    attn_kernel<<<512, 256, 0, stream>>>(qpb, kpb, vpT, rel, gates, az);
    reduce_mfma<<<dim3(PB3_MAX, 8), 256, 0, stream>>>(az, wredf, perm, rbe3, rbs3, rbc3, out);
}

// Round 3
// 268.733 us; speedup vs baseline: 1.1873x; 1.1078x over previous
//
#include <hip/hip_runtime.h>

#define T_    1024
#define B_    2
#define D_    1024
#define E_    12
#define TOPK  4
#define ED_   256
#define HD_   64
#define H_    4
#define N_    (T_*B_)      // 2048 tokens
#define NROW  (N_*TOPK)    // 8192 (n,k) rows
#define PB_MAX 268         // max 32-row expert chunks: 8192/32 + 12
#define PB3_MAX 76         // max 128-row expert chunks: 8192/128 + 12
#define KA_   256          // reduce K (f16 single-pass: ED_)

typedef __bf16 bf16x8 __attribute__((ext_vector_type(8)));
typedef _Float16 f16x8 __attribute__((ext_vector_type(8)));
typedef float  f32x4  __attribute__((ext_vector_type(4)));

__device__ __forceinline__ float sc_() { return 0.35355339059327373f; } // 64^-0.25

__device__ __forceinline__ void async16(const void* g, void* l) {
    __builtin_amdgcn_global_load_lds((const __attribute__((address_space(1))) void*)g,
                                     (__attribute__((address_space(3))) void*)l, 16, 0, 0);
}

// ---------------- one-time: wgT[e][d] = wg[d][e] (f32, 48 KB) ----------------
__global__ void castwg_kernel(const float* __restrict__ wg, float* __restrict__ wgT) {
    int d = blockIdx.x * 256 + threadIdx.x;   // grid 4 x 256
#pragma unroll
    for (int e = 0; e < E_; ++e) wgT[e * D_ + d] = wg[d * E_ + e];
}

// ---------------- gating: wave per token, NO atomics -------------------------
__global__ void __launch_bounds__(256)
gate_kernel(const float* __restrict__ x, const float* __restrict__ wgT,
            float* __restrict__ gates, int* __restrict__ idx) {
    int w = threadIdx.x >> 6, L = threadIdx.x & 63;
    int n = blockIdx.x * 4 + w;
    const float* xr = x + (size_t)n * D_;
    float acc[E_];
#pragma unroll
    for (int e = 0; e < E_; ++e) acc[e] = 0.f;
#pragma unroll
    for (int it = 0; it < 4; ++it) {
        float4 xv = *(const float4*)(xr + it * 256 + L * 4);
#pragma unroll
        for (int e = 0; e < E_; ++e) {
            float4 wv = *(const float4*)(wgT + e * D_ + it * 256 + L * 4);
            acc[e] += xv.x * wv.x + xv.y * wv.y + xv.z * wv.z + xv.w * wv.w;
        }
    }
#pragma unroll
    for (int e = 0; e < E_; ++e) {
        float v = acc[e];
        for (int o = 32; o > 0; o >>= 1) v += __shfl_down(v, o);
        acc[e] = v;
    }
    if (L == 0) {
        float mx = acc[0];
        for (int e = 1; e < E_; ++e) mx = fmaxf(mx, acc[e]);
        float s = 0.f, pr[E_];
        for (int e = 0; e < E_; ++e) { pr[e] = expf(acc[e] - mx); s += pr[e]; }
        float inv = 1.f / s;
        for (int e = 0; e < E_; ++e) pr[e] *= inv;
        for (int k = 0; k < TOPK; ++k) {
            int be = 0; float bv = -1.f;
            for (int e = 0; e < E_; ++e) if (pr[e] > bv) { bv = pr[e]; be = e; }
            gates[n * TOPK + k] = bv;
            idx[n * TOPK + k] = be;
            pr[be] = -1.f;
        }
    }
}

// ---------------- hist: per-block expert counts via ballot (no atomics) ------
// grid 32, block 256: block b covers rows b*256..+255
__global__ void hist_kernel(const int* __restrict__ idx, int* __restrict__ bcnt) {
    int b = blockIdx.x, tid = threadIdx.x, w = tid >> 6, L = tid & 63;
    int e = idx[b * 256 + tid];
    __shared__ int wcnt[4][E_];
#pragma unroll
    for (int e0 = 0; e0 < E_; ++e0) {
        unsigned long long m = __ballot(e == e0);
        if (L == 0) wcnt[w][e0] = (int)__popcll(m);
    }
    __syncthreads();
    if (tid < E_) bcnt[b * E_ + tid] = wcnt[0][tid] + wcnt[1][tid] + wcnt[2][tid] + wcnt[3][tid];
}

// ---------------- scan: offsets + per-block bases + chunk maps (32 & 128) ----
__global__ void scan_kernel(const int* __restrict__ bcnt, int* __restrict__ offs,
                            int* __restrict__ base,
                            int* __restrict__ rbe2, int* __restrict__ rbs2,
                            int* __restrict__ rbc2,
                            int* __restrict__ rbe3, int* __restrict__ rbs3,
                            int* __restrict__ rbc3) {
    if (threadIdx.x == 0 && blockIdx.x == 0) {
        int counts[E_], offl[E_ + 1];
        for (int e = 0; e < E_; ++e) {
            int s = 0;
            for (int b = 0; b < 32; ++b) s += bcnt[b * E_ + e];
            counts[e] = s;
        }
        int o = 0;
        for (int e = 0; e < E_; ++e) { offl[e] = o; o += counts[e]; }
        offl[E_] = o;
        for (int e = 0; e <= E_; ++e) offs[e] = offl[e];
        for (int e = 0; e < E_; ++e) {
            int run = offl[e];
            for (int b = 0; b < 32; ++b) { base[b * E_ + e] = run; run += bcnt[b * E_ + e]; }
        }
        int nb2 = 0;
        for (int e = 0; e < E_; ++e) {
            int c = counts[e];
            for (int s = 0; s < c; s += 32) {
                rbe2[nb2] = e; rbs2[nb2] = offl[e] + s;
                rbc2[nb2] = (c - s < 32) ? (c - s) : 32; ++nb2;
            }
        }
        for (; nb2 < PB_MAX; ++nb2) { rbe2[nb2] = 0; rbs2[nb2] = 0; rbc2[nb2] = 0; }
        int nb3 = 0;
        for (int e = 0; e < E_; ++e) {
            int c = counts[e];
            for (int s = 0; s < c; s += 128) {
                rbe3[nb3] = e; rbs3[nb3] = offl[e] + s;
                rbc3[nb3] = (c - s < 128) ? (c - s) : 128; ++nb3;
            }
        }
        for (; nb3 < PB3_MAX; ++nb3) { rbe3[nb3] = 0; rbs3[nb3] = 0; rbc3[nb3] = 0; }
    }
}

// ---------------- scatter via ballot rank (no atomics) -----------------------
__global__ void scatter_kernel(const int* __restrict__ idx, const int* __restrict__ base,
                               int* __restrict__ perm) {
    int b = blockIdx.x, tid = threadIdx.x, w = tid >> 6, L = tid & 63;
    int r = b * 256 + tid;
    int e = idx[r];
    __shared__ int wcnt[4][E_];
    int rankw = 0;
#pragma unroll
    for (int e0 = 0; e0 < E_; ++e0) {
        unsigned long long m = __ballot(e == e0);
        if (e == e0) rankw = (int)__popcll(m & ((1ULL << L) - 1ULL));
        if (L == 0) wcnt[w][e0] = (int)__popcll(m);
    }
    __syncthreads();
    int pre = 0;
    for (int w2 = 0; w2 < w; ++w2) pre += wcnt[w2][e];
    perm[base[b * E_ + e] + pre + rankw] = r;
}

// ---------------- one-time casts ---------------------------------------------
__global__ void castx_kernel(const float* __restrict__ x, ushort* __restrict__ xb) {
    int t = blockIdx.x * 256 + threadIdx.x;
    float4 v = *(const float4*)(x + (size_t)t * 4);
    union { __bf16 h[4]; uint2 u; } pk;
    pk.h[0] = (__bf16)v.x; pk.h[1] = (__bf16)v.y;
    pk.h[2] = (__bf16)v.z; pk.h[3] = (__bf16)v.w;
    *(uint2*)(xb + (size_t)t * 4) = pk.u;
}

// grid (12,16,4): e, 64-d tile, 64-ed tile.  wmapT[e][ed][d] = bf16(w_map[e][d][ed])
__global__ void castw_kernel(const float* __restrict__ wmap, ushort* __restrict__ wmapT) {
    int e = blockIdx.x, dt = blockIdx.y, et = blockIdx.z;
    __shared__ float ls[64][65];
    int c = threadIdx.x & 63, rg = threadIdx.x >> 6;
    const float* src = wmap + (size_t)e * (D_ * ED_) + (size_t)(dt * 64) * ED_ + et * 64;
#pragma unroll
    for (int q = 0; q < 16; ++q) {
        int r = q * 4 + rg;
        ls[r][c] = src[(size_t)r * ED_ + c];
    }
    __syncthreads();
    ushort* dst = wmapT + ((size_t)e << 18) + (size_t)(et * 64) * 1024 + dt * 64;
#pragma unroll
    for (int q = 0; q < 16; ++q) {
        int r = q * 4 + rg;
        union { __bf16 h; ushort u; } cv; cv.h = (__bf16)ls[c][r];
        dst[(size_t)r * 1024 + c] = cv.u;
    }
}

// grid (2,16,4): which, 64-d tile, 64-ed tile. wT[ed][d] = bf16(w[d][ed])
__global__ void castwkv_kernel(const float* __restrict__ wk, const float* __restrict__ wv,
                               ushort* __restrict__ wkT, ushort* __restrict__ wvT) {
    int which = blockIdx.x, dt = blockIdx.y, et = blockIdx.z;
    const float* w = which ? wv : wk;
    ushort* wT = which ? wvT : wkT;
    __shared__ float ls[64][65];
    int c = threadIdx.x & 63, rg = threadIdx.x >> 6;
    const float* src = w + (size_t)(dt * 64) * ED_ + et * 64;
#pragma unroll
    for (int q = 0; q < 16; ++q) {
        int r = q * 4 + rg;
        ls[r][c] = src[(size_t)r * ED_ + c];
    }
    __syncthreads();
    ushort* dst = wT + (size_t)(et * 64) * 1024 + dt * 64;
#pragma unroll
    for (int q = 0; q < 16; ++q) {
        int r = q * 4 + rg;
        union { __bf16 h; ushort u; } cv; cv.h = (__bf16)ls[c][r];
        dst[(size_t)r * 1024 + c] = cv.u;
    }
}

// grid (12,4,16): e, 64-ed tile, 64-d tile.
// wredf[e][d][ed] = f16(w_reduce[e][ed][d])  (transpose, single precision pass)
__global__ void castwred_kernel(const float* __restrict__ wred, ushort* __restrict__ wredf) {
    int e = blockIdx.x, et = blockIdx.y, dt = blockIdx.z;
    __shared__ float ls[64][65];
    int c = threadIdx.x & 63, rg = threadIdx.x >> 6;
    const float* src = wred + (size_t)e * (ED_ * D_) + (size_t)(et * 64) * D_ + dt * 64;
#pragma unroll
    for (int q = 0; q < 16; ++q) {
        int r = q * 4 + rg;           // ed-local
        ls[r][c] = src[(size_t)r * D_ + c];
    }
    __syncthreads();
    ushort* dst = wredf + (size_t)e * (D_ * KA_) + (size_t)(dt * 64) * KA_ + et * 64;
#pragma unroll
    for (int q = 0; q < 16; ++q) {
        int r = q * 4 + rg;           // d-local
        union { _Float16 h; ushort u; } cv; cv.h = (_Float16)ls[c][r];
        dst[(size_t)r * KA_ + c] = cv.u;
    }
}

// ---------------- one-time: rpeT[h][p][d] = bf16(rpe[h][d][p]) (64 KB) -------
__global__ void castrpe_kernel(const float* __restrict__ rpe, ushort* __restrict__ rpeT) {
    int h = blockIdx.x;                 // 4
    int p = threadIdx.x & 127;          // 128 (p=0 unused by attn but harmless)
    int dq = threadIdx.x >> 7;          // 0/1
#pragma unroll
    for (int d0 = 0; d0 < 64; d0 += 2) {
        int d = d0 + dq;
        union { __bf16 b; ushort u; } cv;
        cv.b = (__bf16)rpe[(size_t)(h * 64 + d) * 129 + p];
        rpeT[(size_t)(h * 128 + p) * 64 + d] = cv.u;
    }
}

// ---------------- k/v projection as bf16 MFMA GEMM ---------------------------
__global__ void __launch_bounds__(256)
kv_mfma(const ushort* __restrict__ keyb, const ushort* __restrict__ valb,
        const ushort* __restrict__ wkT, const ushort* __restrict__ wvT,
        ushort* __restrict__ kpb, ushort* __restrict__ vpT) {
    int which = blockIdx.y;
    const ushort* xb = which ? valb : keyb;
    const ushort* wT = which ? wvT : wkT;
    int m0 = blockIdx.x * 32;
    int b = m0 >> 10, t0 = m0 & 1023;
    int tid = threadIdx.x, w = tid >> 6, L = tid & 63;
    __shared__ __align__(16) ushort As[2][32 * 64];
    __shared__ __align__(16) ushort Bs[2][4 * 64 * 64];

    int swz = ((L & 7) ^ ((L >> 3) & 7)) * 8;
    int an = (((t0 + w * 8 + (L >> 3)) << 1) | b);
    const ushort* asrc = xb + (size_t)an * 1024 + swz;
    const ushort* bsrc = wT + (size_t)(w * 64 + (L >> 3)) * 1024 + swz;

    f32x4 acc[2][4];
#pragma unroll
    for (int mt = 0; mt < 2; ++mt)
#pragma unroll
        for (int nt = 0; nt < 4; ++nt) acc[mt][nt] = (f32x4){0.f, 0.f, 0.f, 0.f};

    auto stage = [&](int kt, int bf) {
        async16(asrc + kt * 64, &As[bf][w * 512]);
#pragma unroll
        for (int q = 0; q < 8; ++q)
            async16(bsrc + (size_t)q * 8192 + kt * 64, &Bs[bf][(w * 64 + q * 8) * 64]);
    };
    auto compute = [&](int bf) {
        const ushort* AB = As[bf];
        const ushort* BB = Bs[bf] + w * 4096;
#pragma unroll
        for (int ks = 0; ks < 2; ++ks) {
            int phys = (((ks * 4 + (L >> 4)) ^ (L & 7))) * 8;
            bf16x8 a0 = *(const bf16x8*)(AB + (L & 15) * 64 + phys);
            bf16x8 a1 = *(const bf16x8*)(AB + (16 + (L & 15)) * 64 + phys);
#pragma unroll
            for (int nt = 0; nt < 4; ++nt) {
                bf16x8 bfr = *(const bf16x8*)(BB + (nt * 16 + (L & 15)) * 64 + phys);
                acc[0][nt] = __builtin_amdgcn_mfma_f32_16x16x32_bf16(a0, bfr, acc[0][nt], 0, 0, 0);
                acc[1][nt] = __builtin_amdgcn_mfma_f32_16x16x32_bf16(a1, bfr, acc[1][nt], 0, 0, 0);
            }
        }
    };

    stage(0, 0);
    for (int t = 0; t < 16; ++t) {
        __syncthreads();
        if (t < 15) stage(t + 1, (t + 1) & 1);
        compute(t & 1);
    }

#pragma unroll
    for (int mt = 0; mt < 2; ++mt)
#pragma unroll
        for (int nt = 0; nt < 4; ++nt) {
            int ed = w * 64 + nt * 16 + (L & 15);
            int tb = t0 + mt * 16 + (L >> 4) * 4;
            if (which == 0) {
#pragma unroll
                for (int r = 0; r < 4; ++r) {
                    union { __bf16 h; ushort u; } cv;
                    cv.h = (__bf16)(acc[mt][nt][r] * sc_());
                    kpb[((size_t)((b << 10) + tb + r)) * ED_ + ed] = cv.u;
                }
            } else {
                int h = ed >> 6, d = ed & 63;
                union { __bf16 h4[4]; uint2 u; } pk;
#pragma unroll
                for (int r = 0; r < 4; ++r) pk.h4[r] = (__bf16)acc[mt][nt][r];
                *(uint2*)&vpT[((size_t)((b * 4 + h) * 64 + d)) * 1024 + tb] = pk.u;
            }
        }
}

// ---------------- q projection as bf16 MFMA GEMM per 32-row expert chunk -----
__global__ void __launch_bounds__(256)
qproj_mfma(const ushort* __restrict__ xb, const ushort* __restrict__ wmapT,
           const int* __restrict__ perm,
           const int* __restrict__ rbe2, const int* __restrict__ rbs2,
           const int* __restrict__ rbc2,
           ushort* __restrict__ qpb) {
    int blk = blockIdx.x;
    int nr = rbc2[blk];
    if (nr == 0) return;
    int e = rbe2[blk], rs = rbs2[blk];
    int tid = threadIdx.x, w = tid >> 6, L = tid & 63;
    __shared__ __align__(16) ushort As[2][32 * 64];
    __shared__ __align__(16) ushort Bs[2][4 * 64 * 64];
    __shared__ int rows2[32];
    if (tid < 32) rows2[tid] = (tid < nr) ? perm[rs + tid] : -1;
    __syncthreads();

    int swz = ((L & 7) ^ ((L >> 3) & 7)) * 8;
    int ar = rows2[w * 8 + (L >> 3)];
    const ushort* asrc = xb + (size_t)((ar < 0 ? 0 : ar) >> 2) * 1024 + swz;
    const ushort* bsrc = wmapT + ((size_t)e << 18) + (size_t)(w * 64 + (L >> 3)) * 1024 + swz;

    f32x4 acc[2][4];
#pragma unroll
    for (int mt = 0; mt < 2; ++mt)
#pragma unroll
        for (int nt = 0; nt < 4; ++nt) acc[mt][nt] = (f32x4){0.f, 0.f, 0.f, 0.f};

    auto stage = [&](int kt, int bf) {
        async16(asrc + kt * 64, &As[bf][w * 512]);
#pragma unroll
        for (int q = 0; q < 8; ++q)
            async16(bsrc + (size_t)q * 8192 + kt * 64, &Bs[bf][(w * 64 + q * 8) * 64]);
    };
    auto compute = [&](int bf) {
        const ushort* AB = As[bf];
        const ushort* BB = Bs[bf] + w * 4096;
#pragma unroll
        for (int ks = 0; ks < 2; ++ks) {
            int phys = (((ks * 4 + (L >> 4)) ^ (L & 7))) * 8;
            bf16x8 a0 = *(const bf16x8*)(AB + (L & 15) * 64 + phys);
            bf16x8 a1 = *(const bf16x8*)(AB + (16 + (L & 15)) * 64 + phys);
#pragma unroll
            for (int nt = 0; nt < 4; ++nt) {
                bf16x8 b = *(const bf16x8*)(BB + (nt * 16 + (L & 15)) * 64 + phys);
                acc[0][nt] = __builtin_amdgcn_mfma_f32_16x16x32_bf16(a0, b, acc[0][nt], 0, 0, 0);
                acc[1][nt] = __builtin_amdgcn_mfma_f32_16x16x32_bf16(a1, b, acc[1][nt], 0, 0, 0);
            }
        }
    };

    stage(0, 0);
    for (int t = 0; t < 16; ++t) {
        __syncthreads();
        if (t < 15) stage(t + 1, (t + 1) & 1);
        compute(t & 1);
    }

#pragma unroll
    for (int mt = 0; mt < 2; ++mt)
#pragma unroll
        for (int nt = 0; nt < 4; ++nt) {
            int n = w * 64 + nt * 16 + (L & 15);
#pragma unroll
            for (int r = 0; r < 4; ++r) {
                int m = mt * 16 + (L >> 4) * 4 + r;
                int rowg = rows2[m];
                if (rowg >= 0) {
                    union { __bf16 h; ushort u; } cv;
                    cv.h = (__bf16)(acc[mt][nt][r] * sc_());
                    qpb[(size_t)rowg * ED_ + n] = cv.u;
                }
            }
        }
}

// ---------------- rel bias as bf16 MFMA GEMM: per head M=8192,K=64,N=128 -----
// rel2[(qrow*4 + h)*128 + p] = qpb[qrow][h*64..] . rpeT[h][p][..]
__global__ void __launch_bounds__(256)
rel_mfma(const ushort* __restrict__ qpb, const ushort* __restrict__ rpeT,
         float* __restrict__ rel) {
    int m0 = blockIdx.x * 128;
    int h  = blockIdx.y;
    int tid = threadIdx.x, w = tid >> 6, L = tid & 63;
    __shared__ __align__(16) ushort As[128 * 64];   // 16 KB
    __shared__ __align__(16) ushort Bs[128 * 64];   // 16 KB

    int swz = ((L & 7) ^ ((L >> 3) & 7)) * 8;
    const ushort* asrc = qpb + (size_t)(m0 + w * 8 + (L >> 3)) * ED_ + h * HD_ + swz;
    const ushort* bsrc = rpeT + (size_t)(h * 128 + w * 8 + (L >> 3)) * 64 + swz;
#pragma unroll
    for (int q = 0; q < 4; ++q) {
        async16(asrc + (size_t)(q * 32) * ED_, &As[(q * 32 + w * 8) * 64]);
        async16(bsrc + (size_t)(q * 32) * 64,  &Bs[(q * 32 + w * 8) * 64]);
    }
    __syncthreads();

    f32x4 acc[2][8];
#pragma unroll
    for (int mt = 0; mt < 2; ++mt)
#pragma unroll
        for (int nt = 0; nt < 8; ++nt) acc[mt][nt] = (f32x4){0.f, 0.f, 0.f, 0.f};

    const ushort* AB = As + w * 32 * 64;            // wave owns rows w*32..+31
#pragma unroll
    for (int ks = 0; ks < 2; ++ks) {
        int phys = (((ks * 4 + (L >> 4)) ^ (L & 7))) * 8;
        bf16x8 a0 = *(const bf16x8*)(AB + (L & 15) * 64 + phys);
        bf16x8 a1 = *(const bf16x8*)(AB + (16 + (L & 15)) * 64 + phys);
#pragma unroll
        for (int nt = 0; nt < 8; ++nt) {
            bf16x8 b = *(const bf16x8*)(Bs + (nt * 16 + (L & 15)) * 64 + phys);
            acc[0][nt] = __builtin_amdgcn_mfma_f32_16x16x32_bf16(a0, b, acc[0][nt], 0, 0, 0);
            acc[1][nt] = __builtin_amdgcn_mfma_f32_16x16x32_bf16(a1, b, acc[1][nt], 0, 0, 0);
        }
    }

#pragma unroll
    for (int mt = 0; mt < 2; ++mt)
#pragma unroll
        for (int nt = 0; nt < 8; ++nt) {
            int p = nt * 16 + (L & 15);
#pragma unroll
            for (int r = 0; r < 4; ++r) {
                int qrow = m0 + w * 32 + mt * 16 + (L >> 4) * 4 + r;
                rel[((size_t)qrow * 4 + h) * 128 + p] = acc[mt][nt][r];
            }
        }
}

// ---------------- MFMA flash attention (bf16, no-max softmax) ----------------
// epilogue writes az[row][256] = f16(attn*gate/l)
__global__ void __launch_bounds__(256)
attn_kernel(const ushort* __restrict__ qpb, const ushort* __restrict__ kpb,
            const ushort* __restrict__ vpT, const float* __restrict__ rel,
            const float* __restrict__ gates, ushort* __restrict__ az) {
    __shared__ __align__(16) ushort Ks[2][64 * 64];
    __shared__ __align__(16) ushort Vs[2][64 * 64];
    __shared__ __align__(16) ushort Ps[4][16 * 64];

    const int tid = threadIdx.x;
    const int w = tid >> 6, L = tid & 63;
    const int bkh = blockIdx.x & 31, it = blockIdx.x >> 5;
    const int h = bkh & 3, kk = (bkh >> 2) & 3, bb = bkh >> 4;
    const int i0w = it * 64 + w * 16;
    const int iL = i0w + (L & 15);
    const int row = ((iL * 2 + bb) << 2) | kk;

    const ushort* qrow = qpb + row * ED_ + h * HD_;
    bf16x8 qf0 = *(const bf16x8*)(qrow + (L >> 4) * 8);
    bf16x8 qf1 = *(const bf16x8*)(qrow + 32 + (L >> 4) * 8);

    const float* relrow = rel + ((size_t)row * 4 + h) * 128;
    float rel_lo = relrow[1], rel_hi = relrow[127];
    float gate = gates[row];

    f32x4 O[4];
#pragma unroll
    for (int mf = 0; mf < 4; ++mf) O[mf] = (f32x4){0.f, 0.f, 0.f, 0.f};
    float l_acc = 0.f;

    const ushort* ksrc = kpb + (size_t)(bb << 10) * ED_ + h * HD_;
    const ushort* vsrc = vpT + (size_t)((bb * 4 + h) * 64) * 1024;

    auto stage = [&](int t, int bf) {
        int j0 = t * 64;
#pragma unroll
        for (int q = 0; q < 2; ++q) {
            int r = L >> 3;
            int c = (L & 7) ^ r;
            const ushort* src = ksrc + (size_t)(j0 + w * 16 + q * 8 + r) * ED_ + c * 8;
            async16(src, &Ks[bf][(w * 16 + q * 8) * 64]);
        }
#pragma unroll
        for (int q = 0; q < 2; ++q) {
            int r = L >> 3;
            int d = w * 16 + q * 8 + r;
            int c = (L & 7) ^ (d & 7);
            const ushort* src = vsrc + (size_t)d * 1024 + j0 + c * 8;
            async16(src, &Vs[bf][(w * 16 + q * 8) * 64]);
        }
    };

    auto compute = [&](int bf, int j0) {
        const ushort* KB = Ks[bf];
        const ushort* VB = Vs[bf];
        ushort* PW = Ps[w];
#pragma unroll
        for (int jf = 0; jf < 4; ++jf) {
            int jrow = jf * 16 + (L & 15);
            bf16x8 a0 = *(const bf16x8*)(KB + jrow * 64 + (((L >> 4)) ^ (L & 7)) * 8);
            bf16x8 a1 = *(const bf16x8*)(KB + jrow * 64 + ((4 + (L >> 4)) ^ (L & 7)) * 8);
            f32x4 s = (f32x4){0.f, 0.f, 0.f, 0.f};
            s = __builtin_amdgcn_mfma_f32_16x16x32_bf16(a0, qf0, s, 0, 0, 0);
            s = __builtin_amdgcn_mfma_f32_16x16x32_bf16(a1, qf1, s, 0, 0, 0);
            int jlo = j0 + jf * 16;
            int jbase = jlo + (L >> 4) * 4;
            float pv[4];
            if (jlo >= i0w + 78) {
#pragma unroll
                for (int r = 0; r < 4; ++r) pv[r] = __expf(s[r] + rel_hi);
            } else if (jlo <= i0w - 78) {
#pragma unroll
                for (int r = 0; r < 4; ++r) pv[r] = __expf(s[r] + rel_lo);
            } else {
#pragma unroll
                for (int r = 0; r < 4; ++r) {
                    int dj = jbase + r - iL;
                    dj = dj < -63 ? -63 : (dj > 63 ? 63 : dj);
                    pv[r] = __expf(s[r] + relrow[dj + 64]);
                }
            }
            l_acc += (pv[0] + pv[1]) + (pv[2] + pv[3]);
            union { __bf16 h4[4]; uint2 u; } pk;
#pragma unroll
            for (int r = 0; r < 4; ++r) pk.h4[r] = (__bf16)pv[r];
            int iloc = L & 15;
            int chunk = jf * 2 + ((L >> 4) >> 1);
            int phys = chunk ^ (iloc & 7);
            *(uint2*)(PW + iloc * 64 + phys * 8 + ((L >> 4) & 1) * 4) = pk.u;
        }
#pragma unroll
        for (int ks = 0; ks < 2; ++ks) {
            int c = ks * 4 + (L >> 4);
            int phys = c ^ (L & 7);
            bf16x8 pf = *(const bf16x8*)(PW + (L & 15) * 64 + phys * 8);
#pragma unroll
            for (int mf = 0; mf < 4; ++mf) {
                bf16x8 vf = *(const bf16x8*)(VB + (mf * 16 + (L & 15)) * 64 + phys * 8);
                O[mf] = __builtin_amdgcn_mfma_f32_16x16x32_bf16(vf, pf, O[mf], 0, 0, 0);
            }
        }
    };

    stage(0, 0);
    for (int t = 0; t < 16; ++t) {
        __syncthreads();
        if (t < 15) stage(t + 1, (t + 1) & 1);
        compute(t & 1, t * 64);
    }

    l_acc += __shfl_xor(l_acc, 16);
    l_acc += __shfl_xor(l_acc, 32);
    float inv = gate / l_acc;
    ushort* azrow = az + (size_t)row * KA_ + h * HD_;
#pragma unroll
    for (int mf = 0; mf < 4; ++mf) {
        union { _Float16 h4[4]; uint2 u; } pk;
#pragma unroll
        for (int r = 0; r < 4; ++r) pk.h4[r] = (_Float16)(O[mf][r] * inv);
        int off = mf * 16 + (L >> 4) * 4;
        *(uint2*)(azrow + off) = pk.u;
    }
}

// ---------------- zero the output (reduce accumulates atomically) ------------
__global__ void zero_out(float* __restrict__ out) {
    int t = blockIdx.x * 256 + threadIdx.x;       // N_*D_/4 threads
    *(float4*)(out + (size_t)t * 4) = make_float4(0.f, 0.f, 0.f, 0.f);
}

// ---------------- expert reduce as f16 MFMA (single pass, K=256) -------------
// 128-row chunks x 128-col tiles, grid (PB3_MAX, 8). Epilogue: HW f32 atomics
// into out (fused combine): out[row>>2][d] += acc.
__global__ void __launch_bounds__(256)
reduce_mfma(const ushort* __restrict__ az, const ushort* __restrict__ wredf,
            const int* __restrict__ perm,
            const int* __restrict__ rbe3, const int* __restrict__ rbs3,
            const int* __restrict__ rbc3, float* __restrict__ out) {
    int blk = blockIdx.x;
    int nr = rbc3[blk];
    if (nr == 0) return;
    int e = rbe3[blk], rs = rbs3[blk];
    int n0 = blockIdx.y * 128;
    int tid = threadIdx.x, w = tid >> 6, L = tid & 63;
    __shared__ __align__(16) ushort As[2][128 * 64];   // 32 KB
    __shared__ __align__(16) ushort Bs[2][128 * 64];   // 32 KB
    __shared__ int rows3[128];
    if (tid < 128) rows3[tid] = (tid < nr) ? perm[rs + tid] : -1;
    __syncthreads();

    int swz = ((L & 7) ^ ((L >> 3) & 7)) * 8;
    const ushort* asrc[4];
#pragma unroll
    for (int q = 0; q < 4; ++q) {
        int ar = rows3[q * 32 + w * 8 + (L >> 3)];
        asrc[q] = az + (size_t)(ar < 0 ? 0 : ar) * KA_ + swz;
    }
    const ushort* bsrc = wredf + (size_t)e * (D_ * KA_)
                       + (size_t)(n0 + w * 8 + (L >> 3)) * KA_ + swz;

    f32x4 acc[2][8];
#pragma unroll
    for (int mt = 0; mt < 2; ++mt)
#pragma unroll
        for (int nt = 0; nt < 8; ++nt) acc[mt][nt] = (f32x4){0.f, 0.f, 0.f, 0.f};

    auto stage = [&](int kt, int bf) {
#pragma unroll
        for (int q = 0; q < 4; ++q)
            async16(asrc[q] + kt * 64, &As[bf][(q * 32 + w * 8) * 64]);
#pragma unroll
        for (int q = 0; q < 4; ++q)
            async16(bsrc + (size_t)(q * 32) * KA_ + kt * 64, &Bs[bf][(q * 32 + w * 8) * 64]);
    };
    auto compute = [&](int bf) {
        const ushort* AB = As[bf] + w * 32 * 64;     // wave owns rows w*32..+31
        const ushort* BB = Bs[bf];                   // all waves share 128 cols
#pragma unroll
        for (int ks = 0; ks < 2; ++ks) {
            int phys = (((ks * 4 + (L >> 4)) ^ (L & 7))) * 8;
            f16x8 a0 = *(const f16x8*)(AB + (L & 15) * 64 + phys);
            f16x8 a1 = *(const f16x8*)(AB + (16 + (L & 15)) * 64 + phys);
#pragma unroll
            for (int nt = 0; nt < 8; ++nt) {
                f16x8 b = *(const f16x8*)(BB + (nt * 16 + (L & 15)) * 64 + phys);
                acc[0][nt] = __builtin_amdgcn_mfma_f32_16x16x32_f16(a0, b, acc[0][nt], 0, 0, 0);
                acc[1][nt] = __builtin_amdgcn_mfma_f32_16x16x32_f16(a1, b, acc[1][nt], 0, 0, 0);
            }
        }
    };

    stage(0, 0);
    for (int t = 0; t < 4; ++t) {        // K = 256 -> 4 tiles of 64
        __syncthreads();
        if (t < 3) stage(t + 1, (t + 1) & 1);
        compute(t & 1);
    }

#pragma unroll
    for (int mt = 0; mt < 2; ++mt)
#pragma unroll
        for (int nt = 0; nt < 8; ++nt) {
            int n = n0 + nt * 16 + (L & 15);
#pragma unroll
            for (int r = 0; r < 4; ++r) {
                int m = w * 32 + mt * 16 + (L >> 4) * 4 + r;
                int rowg = rows3[m];
                if (rowg >= 0)
                    unsafeAtomicAdd(out + (size_t)(rowg >> 2) * D_ + n, acc[mt][nt][r]);
            }
        }
}

// ---------------- launcher ---------------------------------------------------
extern "C" void kernel_launch(void* const* d_in, const int* in_sizes, int n_in,
                              void* d_out, int out_size, void* d_ws, size_t ws_size,
                              hipStream_t stream) {
    const float* query = (const float*)d_in[0];
    const float* key   = (const float*)d_in[1];
    const float* value = (const float*)d_in[2];
    const float* wg    = (const float*)d_in[3];
    const float* wmap  = (const float*)d_in[4];
    const float* wred  = (const float*)d_in[5];
    const float* wk    = (const float*)d_in[6];
    const float* wv    = (const float*)d_in[7];
    const float* rpe   = (const float*)d_in[8];
    float* out = (float*)d_out;

    char* ws = (char*)d_ws;
    float*  gates = (float*)(ws + 0);                      // 32 KB
    int*    idx   = (int*)(ws + (32 << 10));               // 32 KB
    char*   misc  = ws + (64 << 10);
    int*    offs   = (int*)(misc + 128);                   // 13 ints
    int*    bcnt   = (int*)(misc + 1024);                  // 32*12 ints
    int*    base   = (int*)(misc + 3072);                  // 32*12 ints
    int*    rbe2   = (int*)(misc + 8192);
    int*    rbs2   = (int*)(misc + 9472);
    int*    rbc2   = (int*)(misc + 10752);
    int*    rbe3   = (int*)(misc + 12288);                 // 76 ints
    int*    rbs3   = (int*)(misc + 12800);                 // 76 ints
    int*    rbc3   = (int*)(misc + 13312);                 // 76 ints
    int*    perm  = (int*)(ws + (96 << 10));               // 32 KB
    char*   base_ = ws + (128 << 10);
    ushort* rpeT  = (ushort*)(base_);                      // 64 KB [h][p][d] bf16
    ushort* qpb   = (ushort*)(base_ + (8u  << 20));        // 4 MB
    ushort* kpb   = (ushort*)(base_ + (12u << 20));        // 1 MB [b][t][ed]
    ushort* vpT   = (ushort*)(base_ + (13u << 20));        // 1 MB [b][h][d][t]
    ushort* xb    = (ushort*)(base_ + (14u << 20));        // 4 MB
    ushort* wmapT = (ushort*)(base_ + (18u << 20));        // 6 MB
    ushort* keyb  = (ushort*)(base_ + (24u << 20));        // 4 MB
    ushort* valb  = (ushort*)(base_ + (28u << 20));        // 4 MB
    ushort* wkT   = (ushort*)(base_ + (32u << 20));        // 0.5 MB
    ushort* wvT   = (ushort*)(base_ + (32u << 20) + (512u << 10)); // 0.5 MB
    ushort* az    = (ushort*)(base_ + (48u << 20));        // 4.2 MB [row][256] f16
    ushort* wredf = (ushort*)(base_ + (61u << 20));        // 6.3 MB [e][d][256] f16
    float*  rel   = (float*)(base_ + (80u << 20));         // 16 MB [row][h][128]
    float*  wgT   = (float*)(base_ + (96u << 20));         // 48 KB f32 [e][d]

    zero_out<<<(N_ * D_) / 1024, 256, 0, stream>>>(out);
    castwg_kernel<<<D_ / 256, 256, 0, stream>>>(wg, wgT);
    castx_kernel<<<(N_ * D_) / 1024, 256, 0, stream>>>(query, xb);
    castx_kernel<<<(N_ * D_) / 1024, 256, 0, stream>>>(key, keyb);
    castx_kernel<<<(N_ * D_) / 1024, 256, 0, stream>>>(value, valb);
    castw_kernel<<<dim3(E_, 16, 4), 256, 0, stream>>>(wmap, wmapT);
    castwkv_kernel<<<dim3(2, 16, 4), 256, 0, stream>>>(wk, wv, wkT, wvT);
    castwred_kernel<<<dim3(E_, 4, 16), 256, 0, stream>>>(wred, wredf);
    castrpe_kernel<<<dim3(H_), 256, 0, stream>>>(rpe, rpeT);
    gate_kernel<<<N_ / 4, 256, 0, stream>>>(query, wgT, gates, idx);
    hist_kernel<<<NROW / 256, 256, 0, stream>>>(idx, bcnt);
    scan_kernel<<<1, 64, 0, stream>>>(bcnt, offs, base, rbe2, rbs2, rbc2, rbe3, rbs3, rbc3);
    scatter_kernel<<<NROW / 256, 256, 0, stream>>>(idx, base, perm);
    kv_mfma<<<dim3(64, 2), 256, 0, stream>>>(keyb, valb, wkT, wvT, kpb, vpT);
    qproj_mfma<<<PB_MAX, 256, 0, stream>>>(xb, wmapT, perm, rbe2, rbs2, rbc2, qpb);
    rel_mfma<<<dim3(64, 4), 256, 0, stream>>>(qpb, rpeT, rel);
    attn_kernel<<<512, 256, 0, stream>>>(qpb, kpb, vpT, rel, gates, az);
    reduce_mfma<<<dim3(PB3_MAX, 8), 256, 0, stream>>>(az, wredf, perm, rbe3, rbs3, rbc3, out);
}

// Round 4
// 257.001 us; speedup vs baseline: 1.2415x; 1.0457x over previous
//
#include <hip/hip_runtime.h>

#define T_    1024
#define B_    2
#define D_    1024
#define E_    12
#define TOPK  4
#define ED_   256
#define HD_   64
#define H_    4
#define N_    (T_*B_)      // 2048 tokens
#define NROW  (N_*TOPK)    // 8192 (n,k) rows
#define PB3_MAX 76         // max 128-row expert chunks: 8192/128 + 12
#define KA_   256          // reduce K (f16 single-pass: ED_)

typedef __bf16 bf16x8 __attribute__((ext_vector_type(8)));
typedef _Float16 f16x8 __attribute__((ext_vector_type(8)));
typedef float  f32x4  __attribute__((ext_vector_type(4)));

__device__ __forceinline__ float sc_() { return 0.35355339059327373f; } // 64^-0.25

__device__ __forceinline__ void async16(const void* g, void* l) {
    __builtin_amdgcn_global_load_lds((const __attribute__((address_space(1))) void*)g,
                                     (__attribute__((address_space(3))) void*)l, 16, 0, 0);
}

// ---------------- one-time: wgT[e][d] = wg[d][e] (f32, 48 KB) ----------------
__global__ void castwg_kernel(const float* __restrict__ wg, float* __restrict__ wgT) {
    int d = blockIdx.x * 256 + threadIdx.x;   // grid 4 x 256
#pragma unroll
    for (int e = 0; e < E_; ++e) wgT[e * D_ + d] = wg[d * E_ + e];
}

// ---------------- gating + query bf16 cast fused: wave per token -------------
__global__ void __launch_bounds__(256)
gatecast_kernel(const float* __restrict__ x, const float* __restrict__ wgT,
                float* __restrict__ gates, int* __restrict__ idx,
                ushort* __restrict__ xb) {
    int w = threadIdx.x >> 6, L = threadIdx.x & 63;
    int n = blockIdx.x * 4 + w;
    const float* xr = x + (size_t)n * D_;
    float acc[E_];
#pragma unroll
    for (int e = 0; e < E_; ++e) acc[e] = 0.f;
#pragma unroll
    for (int it = 0; it < 4; ++it) {
        float4 xv = *(const float4*)(xr + it * 256 + L * 4);
        union { __bf16 h[4]; uint2 u; } pk;
        pk.h[0] = (__bf16)xv.x; pk.h[1] = (__bf16)xv.y;
        pk.h[2] = (__bf16)xv.z; pk.h[3] = (__bf16)xv.w;
        *(uint2*)(xb + (size_t)n * D_ + it * 256 + L * 4) = pk.u;
#pragma unroll
        for (int e = 0; e < E_; ++e) {
            float4 wv = *(const float4*)(wgT + e * D_ + it * 256 + L * 4);
            acc[e] += xv.x * wv.x + xv.y * wv.y + xv.z * wv.z + xv.w * wv.w;
        }
    }
#pragma unroll
    for (int e = 0; e < E_; ++e) {
        float v = acc[e];
        for (int o = 32; o > 0; o >>= 1) v += __shfl_down(v, o);
        acc[e] = v;
    }
    if (L == 0) {
        float mx = acc[0];
        for (int e = 1; e < E_; ++e) mx = fmaxf(mx, acc[e]);
        float s = 0.f, pr[E_];
        for (int e = 0; e < E_; ++e) { pr[e] = expf(acc[e] - mx); s += pr[e]; }
        float inv = 1.f / s;
        for (int e = 0; e < E_; ++e) pr[e] *= inv;
        for (int k = 0; k < TOPK; ++k) {
            int be = 0; float bv = -1.f;
            for (int e = 0; e < E_; ++e) if (pr[e] > bv) { bv = pr[e]; be = e; }
            gates[n * TOPK + k] = bv;
            idx[n * TOPK + k] = be;
            pr[be] = -1.f;
        }
    }
}

// ---------------- hist: per-block expert counts via ballot (no atomics) ------
// grid 32, block 256: block b covers rows b*256..+255
__global__ void hist_kernel(const int* __restrict__ idx, int* __restrict__ bcnt) {
    int b = blockIdx.x, tid = threadIdx.x, w = tid >> 6, L = tid & 63;
    int e = idx[b * 256 + tid];
    __shared__ int wcnt[4][E_];
#pragma unroll
    for (int e0 = 0; e0 < E_; ++e0) {
        unsigned long long m = __ballot(e == e0);
        if (L == 0) wcnt[w][e0] = (int)__popcll(m);
    }
    __syncthreads();
    if (tid < E_) bcnt[b * E_ + tid] = wcnt[0][tid] + wcnt[1][tid] + wcnt[2][tid] + wcnt[3][tid];
}

// ---------------- scan (64-lane parallel): offsets + bases + 128-chunk map ---
__global__ void scan_kernel(const int* __restrict__ bcnt, int* __restrict__ offs,
                            int* __restrict__ base,
                            int* __restrict__ rbe3, int* __restrict__ rbs3,
                            int* __restrict__ rbc3) {
    __shared__ int counts[E_], offl[E_ + 1];
    int tid = threadIdx.x;
    if (tid < E_) {
        int s = 0;
        for (int b = 0; b < 32; ++b) s += bcnt[b * E_ + tid];
        counts[tid] = s;
    }
    __syncthreads();
    if (tid == 0) {
        int o = 0;
        for (int e = 0; e < E_; ++e) { offl[e] = o; o += counts[e]; }
        offl[E_] = o;
    }
    __syncthreads();
    if (tid <= E_) offs[tid] = offl[tid];
    for (int i = tid; i < 32 * E_; i += 64) {
        int b = i / E_, e = i % E_;
        int run = offl[e];
        for (int bb = 0; bb < b; ++bb) run += bcnt[bb * E_ + e];
        base[i] = run;
    }
    if (tid < E_) {
        int pos = 0;
        for (int e = 0; e < tid; ++e) pos += (counts[e] + 127) >> 7;
        int c = counts[tid];
        for (int s = 0, k = 0; s < c; s += 128, ++k) {
            rbe3[pos + k] = tid; rbs3[pos + k] = offl[tid] + s;
            int rem = c - s; rbc3[pos + k] = rem < 128 ? rem : 128;
        }
    }
    int tot = 0;
    for (int e = 0; e < E_; ++e) tot += (counts[e] + 127) >> 7;
    for (int i = tot + tid; i < PB3_MAX; i += 64) {
        rbe3[i] = 0; rbs3[i] = 0; rbc3[i] = 0;
    }
}

// ---------------- scatter via ballot rank (no atomics) -----------------------
__global__ void scatter_kernel(const int* __restrict__ idx, const int* __restrict__ base,
                               int* __restrict__ perm) {
    int b = blockIdx.x, tid = threadIdx.x, w = tid >> 6, L = tid & 63;
    int r = b * 256 + tid;
    int e = idx[r];
    __shared__ int wcnt[4][E_];
    int rankw = 0;
#pragma unroll
    for (int e0 = 0; e0 < E_; ++e0) {
        unsigned long long m = __ballot(e == e0);
        if (e == e0) rankw = (int)__popcll(m & ((1ULL << L) - 1ULL));
        if (L == 0) wcnt[w][e0] = (int)__popcll(m);
    }
    __syncthreads();
    int pre = 0;
    for (int w2 = 0; w2 < w; ++w2) pre += wcnt[w2][e];
    perm[base[b * E_ + e] + pre + rankw] = r;
}

// ---------------- key+value bf16 cast (merged) -------------------------------
__global__ void castkv2_kernel(const float* __restrict__ key, const float* __restrict__ value,
                               ushort* __restrict__ keyb, ushort* __restrict__ valb) {
    int g = blockIdx.x * 256 + threadIdx.x;          // 2 * 2^19 quads
    int which = g >> 19, t = g & ((1 << 19) - 1);
    const float* src = which ? value : key;
    ushort* dst = which ? valb : keyb;
    float4 v = *(const float4*)(src + (size_t)t * 4);
    union { __bf16 h[4]; uint2 u; } pk;
    pk.h[0] = (__bf16)v.x; pk.h[1] = (__bf16)v.y;
    pk.h[2] = (__bf16)v.z; pk.h[3] = (__bf16)v.w;
    *(uint2*)(dst + (size_t)t * 4) = pk.u;
}

// grid (12,16,4): e, 64-d tile, 64-ed tile.  wmapT[e][ed][d] = bf16(w_map[e][d][ed])
__global__ void castw_kernel(const float* __restrict__ wmap, ushort* __restrict__ wmapT) {
    int e = blockIdx.x, dt = blockIdx.y, et = blockIdx.z;
    __shared__ float ls[64][65];
    int c = threadIdx.x & 63, rg = threadIdx.x >> 6;
    const float* src = wmap + (size_t)e * (D_ * ED_) + (size_t)(dt * 64) * ED_ + et * 64;
#pragma unroll
    for (int q = 0; q < 16; ++q) {
        int r = q * 4 + rg;
        ls[r][c] = src[(size_t)r * ED_ + c];
    }
    __syncthreads();
    ushort* dst = wmapT + ((size_t)e << 18) + (size_t)(et * 64) * 1024 + dt * 64;
#pragma unroll
    for (int q = 0; q < 16; ++q) {
        int r = q * 4 + rg;
        union { __bf16 h; ushort u; } cv; cv.h = (__bf16)ls[c][r];
        dst[(size_t)r * 1024 + c] = cv.u;
    }
}

// grid (2,16,4): which, 64-d tile, 64-ed tile. wT[ed][d] = bf16(w[d][ed])
__global__ void castwkv_kernel(const float* __restrict__ wk, const float* __restrict__ wv,
                               ushort* __restrict__ wkT, ushort* __restrict__ wvT) {
    int which = blockIdx.x, dt = blockIdx.y, et = blockIdx.z;
    const float* w = which ? wv : wk;
    ushort* wT = which ? wvT : wkT;
    __shared__ float ls[64][65];
    int c = threadIdx.x & 63, rg = threadIdx.x >> 6;
    const float* src = w + (size_t)(dt * 64) * ED_ + et * 64;
#pragma unroll
    for (int q = 0; q < 16; ++q) {
        int r = q * 4 + rg;
        ls[r][c] = src[(size_t)r * ED_ + c];
    }
    __syncthreads();
    ushort* dst = wT + (size_t)(et * 64) * 1024 + dt * 64;
#pragma unroll
    for (int q = 0; q < 16; ++q) {
        int r = q * 4 + rg;
        union { __bf16 h; ushort u; } cv; cv.h = (__bf16)ls[c][r];
        dst[(size_t)r * 1024 + c] = cv.u;
    }
}

// grid (12,4,16): e, 64-ed tile, 64-d tile.
// wredf[e][d][ed] = f16(w_reduce[e][ed][d])  (transpose, single precision pass)
__global__ void castwred_kernel(const float* __restrict__ wred, ushort* __restrict__ wredf) {
    int e = blockIdx.x, et = blockIdx.y, dt = blockIdx.z;
    __shared__ float ls[64][65];
    int c = threadIdx.x & 63, rg = threadIdx.x >> 6;
    const float* src = wred + (size_t)e * (ED_ * D_) + (size_t)(et * 64) * D_ + dt * 64;
#pragma unroll
    for (int q = 0; q < 16; ++q) {
        int r = q * 4 + rg;           // ed-local
        ls[r][c] = src[(size_t)r * D_ + c];
    }
    __syncthreads();
    ushort* dst = wredf + (size_t)e * (D_ * KA_) + (size_t)(dt * 64) * KA_ + et * 64;
#pragma unroll
    for (int q = 0; q < 16; ++q) {
        int r = q * 4 + rg;           // d-local
        union { _Float16 h; ushort u; } cv; cv.h = (_Float16)ls[c][r];
        dst[(size_t)r * KA_ + c] = cv.u;
    }
}

// ---------------- one-time: rpeT[h][p][d] = bf16(rpe[h][d][p]) (64 KB) -------
__global__ void castrpe_kernel(const float* __restrict__ rpe, ushort* __restrict__ rpeT) {
    int h = blockIdx.x;                 // 4
    int p = threadIdx.x & 127;          // 128
    int dq = threadIdx.x >> 7;          // 0/1
#pragma unroll
    for (int d0 = 0; d0 < 64; d0 += 2) {
        int d = d0 + dq;
        union { __bf16 b; ushort u; } cv;
        cv.b = (__bf16)rpe[(size_t)(h * 64 + d) * 129 + p];
        rpeT[(size_t)(h * 128 + p) * 64 + d] = cv.u;
    }
}

// ---------------- k/v projection, 128x128 tiles, K=1024 ----------------------
// grid (16, 2, 2): m-chunk (b,t0), 128-col ed tile, which
__global__ void __launch_bounds__(256)
kv_mfma(const ushort* __restrict__ keyb, const ushort* __restrict__ valb,
        const ushort* __restrict__ wkT, const ushort* __restrict__ wvT,
        ushort* __restrict__ kpb, ushort* __restrict__ vpT) {
    int which = blockIdx.z;
    const ushort* xb = which ? valb : keyb;
    const ushort* wT = which ? wvT : wkT;
    int b = blockIdx.x >> 3, t0 = (blockIdx.x & 7) * 128;
    int n0 = blockIdx.y * 128;
    int tid = threadIdx.x, w = tid >> 6, L = tid & 63;
    __shared__ __align__(16) ushort As[2][128 * 64];   // 32 KB
    __shared__ __align__(16) ushort Bs[2][128 * 64];   // 32 KB

    int swz = ((L & 7) ^ ((L >> 3) & 7)) * 8;
    const ushort* asrc[4];
#pragma unroll
    for (int q = 0; q < 4; ++q) {
        int rl = q * 32 + w * 8 + (L >> 3);
        int an = (((t0 + rl) << 1) | b);
        asrc[q] = xb + (size_t)an * 1024 + swz;
    }
    const ushort* bsrc = wT + (size_t)(n0 + w * 8 + (L >> 3)) * 1024 + swz;

    f32x4 acc[2][8];
#pragma unroll
    for (int mt = 0; mt < 2; ++mt)
#pragma unroll
        for (int nt = 0; nt < 8; ++nt) acc[mt][nt] = (f32x4){0.f, 0.f, 0.f, 0.f};

    auto stage = [&](int kt, int bf) {
#pragma unroll
        for (int q = 0; q < 4; ++q)
            async16(asrc[q] + kt * 64, &As[bf][(q * 32 + w * 8) * 64]);
#pragma unroll
        for (int q = 0; q < 4; ++q)
            async16(bsrc + (size_t)(q * 32) * 1024 + kt * 64, &Bs[bf][(q * 32 + w * 8) * 64]);
    };
    auto compute = [&](int bf) {
        const ushort* AB = As[bf] + w * 32 * 64;
        const ushort* BB = Bs[bf];
#pragma unroll
        for (int ks = 0; ks < 2; ++ks) {
            int phys = (((ks * 4 + (L >> 4)) ^ (L & 7))) * 8;
            bf16x8 a0 = *(const bf16x8*)(AB + (L & 15) * 64 + phys);
            bf16x8 a1 = *(const bf16x8*)(AB + (16 + (L & 15)) * 64 + phys);
#pragma unroll
            for (int nt = 0; nt < 8; ++nt) {
                bf16x8 bfr = *(const bf16x8*)(BB + (nt * 16 + (L & 15)) * 64 + phys);
                acc[0][nt] = __builtin_amdgcn_mfma_f32_16x16x32_bf16(a0, bfr, acc[0][nt], 0, 0, 0);
                acc[1][nt] = __builtin_amdgcn_mfma_f32_16x16x32_bf16(a1, bfr, acc[1][nt], 0, 0, 0);
            }
        }
    };

    stage(0, 0);
    for (int t = 0; t < 16; ++t) {
        __syncthreads();
        if (t < 15) stage(t + 1, (t + 1) & 1);
        compute(t & 1);
    }

#pragma unroll
    for (int mt = 0; mt < 2; ++mt)
#pragma unroll
        for (int nt = 0; nt < 8; ++nt) {
            int ed = n0 + nt * 16 + (L & 15);
            int tb = t0 + w * 32 + mt * 16 + (L >> 4) * 4;
            if (which == 0) {
#pragma unroll
                for (int r = 0; r < 4; ++r) {
                    union { __bf16 h; ushort u; } cv;
                    cv.h = (__bf16)(acc[mt][nt][r] * sc_());
                    kpb[((size_t)((b << 10) + tb + r)) * ED_ + ed] = cv.u;
                }
            } else {
                int h = ed >> 6, d = ed & 63;
                union { __bf16 h4[4]; uint2 u; } pk;
#pragma unroll
                for (int r = 0; r < 4; ++r) pk.h4[r] = (__bf16)acc[mt][nt][r];
                *(uint2*)&vpT[((size_t)((b * 4 + h) * 64 + d)) * 1024 + tb] = pk.u;
            }
        }
}

// ---------------- q projection, 128-row expert chunks x 128-col, K=1024 ------
// grid (PB3_MAX, 2)
__global__ void __launch_bounds__(256)
qproj_mfma(const ushort* __restrict__ xb, const ushort* __restrict__ wmapT,
           const int* __restrict__ perm,
           const int* __restrict__ rbe3, const int* __restrict__ rbs3,
           const int* __restrict__ rbc3,
           ushort* __restrict__ qpb) {
    int blk = blockIdx.x;
    int nr = rbc3[blk];
    if (nr == 0) return;
    int e = rbe3[blk], rs = rbs3[blk];
    int n0 = blockIdx.y * 128;
    int tid = threadIdx.x, w = tid >> 6, L = tid & 63;
    __shared__ __align__(16) ushort As[2][128 * 64];   // 32 KB
    __shared__ __align__(16) ushort Bs[2][128 * 64];   // 32 KB
    __shared__ int rows3[128];
    if (tid < 128) rows3[tid] = (tid < nr) ? perm[rs + tid] : -1;
    __syncthreads();

    int swz = ((L & 7) ^ ((L >> 3) & 7)) * 8;
    const ushort* asrc[4];
#pragma unroll
    for (int q = 0; q < 4; ++q) {
        int ar = rows3[q * 32 + w * 8 + (L >> 3)];
        asrc[q] = xb + (size_t)((ar < 0 ? 0 : ar) >> 2) * 1024 + swz;
    }
    const ushort* bsrc = wmapT + ((size_t)e << 18) + (size_t)(n0 + w * 8 + (L >> 3)) * 1024 + swz;

    f32x4 acc[2][8];
#pragma unroll
    for (int mt = 0; mt < 2; ++mt)
#pragma unroll
        for (int nt = 0; nt < 8; ++nt) acc[mt][nt] = (f32x4){0.f, 0.f, 0.f, 0.f};

    auto stage = [&](int kt, int bf) {
#pragma unroll
        for (int q = 0; q < 4; ++q)
            async16(asrc[q] + kt * 64, &As[bf][(q * 32 + w * 8) * 64]);
#pragma unroll
        for (int q = 0; q < 4; ++q)
            async16(bsrc + (size_t)(q * 32) * 1024 + kt * 64, &Bs[bf][(q * 32 + w * 8) * 64]);
    };
    auto compute = [&](int bf) {
        const ushort* AB = As[bf] + w * 32 * 64;
        const ushort* BB = Bs[bf];
#pragma unroll
        for (int ks = 0; ks < 2; ++ks) {
            int phys = (((ks * 4 + (L >> 4)) ^ (L & 7))) * 8;
            bf16x8 a0 = *(const bf16x8*)(AB + (L & 15) * 64 + phys);
            bf16x8 a1 = *(const bf16x8*)(AB + (16 + (L & 15)) * 64 + phys);
#pragma unroll
            for (int nt = 0; nt < 8; ++nt) {
                bf16x8 bfr = *(const bf16x8*)(BB + (nt * 16 + (L & 15)) * 64 + phys);
                acc[0][nt] = __builtin_amdgcn_mfma_f32_16x16x32_bf16(a0, bfr, acc[0][nt], 0, 0, 0);
                acc[1][nt] = __builtin_amdgcn_mfma_f32_16x16x32_bf16(a1, bfr, acc[1][nt], 0, 0, 0);
            }
        }
    };

    stage(0, 0);
    for (int t = 0; t < 16; ++t) {
        __syncthreads();
        if (t < 15) stage(t + 1, (t + 1) & 1);
        compute(t & 1);
    }

#pragma unroll
    for (int mt = 0; mt < 2; ++mt)
#pragma unroll
        for (int nt = 0; nt < 8; ++nt) {
            int n = n0 + nt * 16 + (L & 15);
#pragma unroll
            for (int r = 0; r < 4; ++r) {
                int m = w * 32 + mt * 16 + (L >> 4) * 4 + r;
                int rowg = rows3[m];
                if (rowg >= 0) {
                    union { __bf16 h; ushort u; } cv;
                    cv.h = (__bf16)(acc[mt][nt][r] * sc_());
                    qpb[(size_t)rowg * ED_ + n] = cv.u;
                }
            }
        }
}

// ---------------- rel bias as bf16 MFMA GEMM: per head M=8192,K=64,N=128 -----
// rel[(qrow*4 + h)*128 + p] = qpb[qrow][h*64..] . rpeT[h][p][..]
__global__ void __launch_bounds__(256)
rel_mfma(const ushort* __restrict__ qpb, const ushort* __restrict__ rpeT,
         float* __restrict__ rel) {
    int m0 = blockIdx.x * 128;
    int h  = blockIdx.y;
    int tid = threadIdx.x, w = tid >> 6, L = tid & 63;
    __shared__ __align__(16) ushort As[128 * 64];   // 16 KB
    __shared__ __align__(16) ushort Bs[128 * 64];   // 16 KB

    int swz = ((L & 7) ^ ((L >> 3) & 7)) * 8;
    const ushort* asrc = qpb + (size_t)(m0 + w * 8 + (L >> 3)) * ED_ + h * HD_ + swz;
    const ushort* bsrc = rpeT + (size_t)(h * 128 + w * 8 + (L >> 3)) * 64 + swz;
#pragma unroll
    for (int q = 0; q < 4; ++q) {
        async16(asrc + (size_t)(q * 32) * ED_, &As[(q * 32 + w * 8) * 64]);
        async16(bsrc + (size_t)(q * 32) * 64,  &Bs[(q * 32 + w * 8) * 64]);
    }
    __syncthreads();

    f32x4 acc[2][8];
#pragma unroll
    for (int mt = 0; mt < 2; ++mt)
#pragma unroll
        for (int nt = 0; nt < 8; ++nt) acc[mt][nt] = (f32x4){0.f, 0.f, 0.f, 0.f};

    const ushort* AB = As + w * 32 * 64;            // wave owns rows w*32..+31
#pragma unroll
    for (int ks = 0; ks < 2; ++ks) {
        int phys = (((ks * 4 + (L >> 4)) ^ (L & 7))) * 8;
        bf16x8 a0 = *(const bf16x8*)(AB + (L & 15) * 64 + phys);
        bf16x8 a1 = *(const bf16x8*)(AB + (16 + (L & 15)) * 64 + phys);
#pragma unroll
        for (int nt = 0; nt < 8; ++nt) {
            bf16x8 b = *(const bf16x8*)(Bs + (nt * 16 + (L & 15)) * 64 + phys);
            acc[0][nt] = __builtin_amdgcn_mfma_f32_16x16x32_bf16(a0, b, acc[0][nt], 0, 0, 0);
            acc[1][nt] = __builtin_amdgcn_mfma_f32_16x16x32_bf16(a1, b, acc[1][nt], 0, 0, 0);
        }
    }

#pragma unroll
    for (int mt = 0; mt < 2; ++mt)
#pragma unroll
        for (int nt = 0; nt < 8; ++nt) {
            int p = nt * 16 + (L & 15);
#pragma unroll
            for (int r = 0; r < 4; ++r) {
                int qrow = m0 + w * 32 + mt * 16 + (L >> 4) * 4 + r;
                rel[((size_t)qrow * 4 + h) * 128 + p] = acc[mt][nt][r];
            }
        }
}

// ---------------- MFMA flash attention (bf16, no-max softmax) ----------------
// epilogue writes az[row][256] = f16(attn*gate/l)
__global__ void __launch_bounds__(256)
attn_kernel(const ushort* __restrict__ qpb, const ushort* __restrict__ kpb,
            const ushort* __restrict__ vpT, const float* __restrict__ rel,
            const float* __restrict__ gates, ushort* __restrict__ az) {
    __shared__ __align__(16) ushort Ks[2][64 * 64];
    __shared__ __align__(16) ushort Vs[2][64 * 64];
    __shared__ __align__(16) ushort Ps[4][16 * 64];

    const int tid = threadIdx.x;
    const int w = tid >> 6, L = tid & 63;
    const int bkh = blockIdx.x & 31, it = blockIdx.x >> 5;
    const int h = bkh & 3, kk = (bkh >> 2) & 3, bb = bkh >> 4;
    const int i0w = it * 64 + w * 16;
    const int iL = i0w + (L & 15);
    const int row = ((iL * 2 + bb) << 2) | kk;

    const ushort* qrow = qpb + row * ED_ + h * HD_;
    bf16x8 qf0 = *(const bf16x8*)(qrow + (L >> 4) * 8);
    bf16x8 qf1 = *(const bf16x8*)(qrow + 32 + (L >> 4) * 8);

    const float* relrow = rel + ((size_t)row * 4 + h) * 128;
    float rel_lo = relrow[1], rel_hi = relrow[127];
    float gate = gates[row];

    f32x4 O[4];
#pragma unroll
    for (int mf = 0; mf < 4; ++mf) O[mf] = (f32x4){0.f, 0.f, 0.f, 0.f};
    float l_acc = 0.f;

    const ushort* ksrc = kpb + (size_t)(bb << 10) * ED_ + h * HD_;
    const ushort* vsrc = vpT + (size_t)((bb * 4 + h) * 64) * 1024;

    auto stage = [&](int t, int bf) {
        int j0 = t * 64;
#pragma unroll
        for (int q = 0; q < 2; ++q) {
            int r = L >> 3;
            int c = (L & 7) ^ r;
            const ushort* src = ksrc + (size_t)(j0 + w * 16 + q * 8 + r) * ED_ + c * 8;
            async16(src, &Ks[bf][(w * 16 + q * 8) * 64]);
        }
#pragma unroll
        for (int q = 0; q < 2; ++q) {
            int r = L >> 3;
            int d = w * 16 + q * 8 + r;
            int c = (L & 7) ^ (d & 7);
            const ushort* src = vsrc + (size_t)d * 1024 + j0 + c * 8;
            async16(src, &Vs[bf][(w * 16 + q * 8) * 64]);
        }
    };

    auto compute = [&](int bf, int j0) {
        const ushort* KB = Ks[bf];
        const ushort* VB = Vs[bf];
        ushort* PW = Ps[w];
#pragma unroll
        for (int jf = 0; jf < 4; ++jf) {
            int jrow = jf * 16 + (L & 15);
            bf16x8 a0 = *(const bf16x8*)(KB + jrow * 64 + (((L >> 4)) ^ (L & 7)) * 8);
            bf16x8 a1 = *(const bf16x8*)(KB + jrow * 64 + ((4 + (L >> 4)) ^ (L & 7)) * 8);
            f32x4 s = (f32x4){0.f, 0.f, 0.f, 0.f};
            s = __builtin_amdgcn_mfma_f32_16x16x32_bf16(a0, qf0, s, 0, 0, 0);
            s = __builtin_amdgcn_mfma_f32_16x16x32_bf16(a1, qf1, s, 0, 0, 0);
            int jlo = j0 + jf * 16;
            int jbase = jlo + (L >> 4) * 4;
            float pv[4];
            if (jlo >= i0w + 78) {
#pragma unroll
                for (int r = 0; r < 4; ++r) pv[r] = __expf(s[r] + rel_hi);
            } else if (jlo <= i0w - 78) {
#pragma unroll
                for (int r = 0; r < 4; ++r) pv[r] = __expf(s[r] + rel_lo);
            } else {
#pragma unroll
                for (int r = 0; r < 4; ++r) {
                    int dj = jbase + r - iL;
                    dj = dj < -63 ? -63 : (dj > 63 ? 63 : dj);
                    pv[r] = __expf(s[r] + relrow[dj + 64]);
                }
            }
            l_acc += (pv[0] + pv[1]) + (pv[2] + pv[3]);
            union { __bf16 h4[4]; uint2 u; } pk;
#pragma unroll
            for (int r = 0; r < 4; ++r) pk.h4[r] = (__bf16)pv[r];
            int iloc = L & 15;
            int chunk = jf * 2 + ((L >> 4) >> 1);
            int phys = chunk ^ (iloc & 7);
            *(uint2*)(PW + iloc * 64 + phys * 8 + ((L >> 4) & 1) * 4) = pk.u;
        }
#pragma unroll
        for (int ks = 0; ks < 2; ++ks) {
            int c = ks * 4 + (L >> 4);
            int phys = c ^ (L & 7);
            bf16x8 pf = *(const bf16x8*)(PW + (L & 15) * 64 + phys * 8);
#pragma unroll
            for (int mf = 0; mf < 4; ++mf) {
                bf16x8 vf = *(const bf16x8*)(VB + (mf * 16 + (L & 15)) * 64 + phys * 8);
                O[mf] = __builtin_amdgcn_mfma_f32_16x16x32_bf16(vf, pf, O[mf], 0, 0, 0);
            }
        }
    };

    stage(0, 0);
    for (int t = 0; t < 16; ++t) {
        __syncthreads();
        if (t < 15) stage(t + 1, (t + 1) & 1);
        compute(t & 1, t * 64);
    }

    l_acc += __shfl_xor(l_acc, 16);
    l_acc += __shfl_xor(l_acc, 32);
    float inv = gate / l_acc;
    ushort* azrow = az + (size_t)row * KA_ + h * HD_;
#pragma unroll
    for (int mf = 0; mf < 4; ++mf) {
        union { _Float16 h4[4]; uint2 u; } pk;
#pragma unroll
        for (int r = 0; r < 4; ++r) pk.h4[r] = (_Float16)(O[mf][r] * inv);
        int off = mf * 16 + (L >> 4) * 4;
        *(uint2*)(azrow + off) = pk.u;
    }
}

// ---------------- zero the output (reduce accumulates atomically) ------------
__global__ void zero_out(float* __restrict__ out) {
    int t = blockIdx.x * 256 + threadIdx.x;       // N_*D_/4 threads
    *(float4*)(out + (size_t)t * 4) = make_float4(0.f, 0.f, 0.f, 0.f);
}

// ---------------- expert reduce as f16 MFMA (single pass, K=256) -------------
// 128-row chunks x 128-col tiles, grid (PB3_MAX, 8). Epilogue: HW f32 atomics
// into out (fused combine): out[row>>2][d] += acc.
__global__ void __launch_bounds__(256)
reduce_mfma(const ushort* __restrict__ az, const ushort* __restrict__ wredf,
            const int* __restrict__ perm,
            const int* __restrict__ rbe3, const int* __restrict__ rbs3,
            const int* __restrict__ rbc3, float* __restrict__ out) {
    int blk = blockIdx.x;
    int nr = rbc3[blk];
    if (nr == 0) return;
    int e = rbe3[blk], rs = rbs3[blk];
    int n0 = blockIdx.y * 128;
    int tid = threadIdx.x, w = tid >> 6, L = tid & 63;
    __shared__ __align__(16) ushort As[2][128 * 64];   // 32 KB
    __shared__ __align__(16) ushort Bs[2][128 * 64];   // 32 KB
    __shared__ int rows3[128];
    if (tid < 128) rows3[tid] = (tid < nr) ? perm[rs + tid] : -1;
    __syncthreads();

    int swz = ((L & 7) ^ ((L >> 3) & 7)) * 8;
    const ushort* asrc[4];
#pragma unroll
    for (int q = 0; q < 4; ++q) {
        int ar = rows3[q * 32 + w * 8 + (L >> 3)];
        asrc[q] = az + (size_t)(ar < 0 ? 0 : ar) * KA_ + swz;
    }
    const ushort* bsrc = wredf + (size_t)e * (D_ * KA_)
                       + (size_t)(n0 + w * 8 + (L >> 3)) * KA_ + swz;

    f32x4 acc[2][8];
#pragma unroll
    for (int mt = 0; mt < 2; ++mt)
#pragma unroll
        for (int nt = 0; nt < 8; ++nt) acc[mt][nt] = (f32x4){0.f, 0.f, 0.f, 0.f};

    auto stage = [&](int kt, int bf) {
#pragma unroll
        for (int q = 0; q < 4; ++q)
            async16(asrc[q] + kt * 64, &As[bf][(q * 32 + w * 8) * 64]);
#pragma unroll
        for (int q = 0; q < 4; ++q)
            async16(bsrc + (size_t)(q * 32) * KA_ + kt * 64, &Bs[bf][(q * 32 + w * 8) * 64]);
    };
    auto compute = [&](int bf) {
        const ushort* AB = As[bf] + w * 32 * 64;     // wave owns rows w*32..+31
        const ushort* BB = Bs[bf];                   // all waves share 128 cols
#pragma unroll
        for (int ks = 0; ks < 2; ++ks) {
            int phys = (((ks * 4 + (L >> 4)) ^ (L & 7))) * 8;
            f16x8 a0 = *(const f16x8*)(AB + (L & 15) * 64 + phys);
            f16x8 a1 = *(const f16x8*)(AB + (16 + (L & 15)) * 64 + phys);
#pragma unroll
            for (int nt = 0; nt < 8; ++nt) {
                f16x8 b = *(const f16x8*)(BB + (nt * 16 + (L & 15)) * 64 + phys);
                acc[0][nt] = __builtin_amdgcn_mfma_f32_16x16x32_f16(a0, b, acc[0][nt], 0, 0, 0);
                acc[1][nt] = __builtin_amdgcn_mfma_f32_16x16x32_f16(a1, b, acc[1][nt], 0, 0, 0);
            }
        }
    };

    stage(0, 0);
    for (int t = 0; t < 4; ++t) {        // K = 256 -> 4 tiles of 64
        __syncthreads();
        if (t < 3) stage(t + 1, (t + 1) & 1);
        compute(t & 1);
    }

#pragma unroll
    for (int mt = 0; mt < 2; ++mt)
#pragma unroll
        for (int nt = 0; nt < 8; ++nt) {
            int n = n0 + nt * 16 + (L & 15);
#pragma unroll
            for (int r = 0; r < 4; ++r) {
                int m = w * 32 + mt * 16 + (L >> 4) * 4 + r;
                int rowg = rows3[m];
                if (rowg >= 0)
                    unsafeAtomicAdd(out + (size_t)(rowg >> 2) * D_ + n, acc[mt][nt][r]);
            }
        }
}

// ---------------- launcher ---------------------------------------------------
extern "C" void kernel_launch(void* const* d_in, const int* in_sizes, int n_in,
                              void* d_out, int out_size, void* d_ws, size_t ws_size,
                              hipStream_t stream) {
    const float* query = (const float*)d_in[0];
    const float* key   = (const float*)d_in[1];
    const float* value = (const float*)d_in[2];
    const float* wg    = (const float*)d_in[3];
    const float* wmap  = (const float*)d_in[4];
    const float* wred  = (const float*)d_in[5];
    const float* wk    = (const float*)d_in[6];
    const float* wv    = (const float*)d_in[7];
    const float* rpe   = (const float*)d_in[8];
    float* out = (float*)d_out;

    char* ws = (char*)d_ws;
    float*  gates = (float*)(ws + 0);                      // 32 KB
    int*    idx   = (int*)(ws + (32 << 10));               // 32 KB
    char*   misc  = ws + (64 << 10);
    int*    offs   = (int*)(misc + 128);                   // 13 ints
    int*    bcnt   = (int*)(misc + 1024);                  // 32*12 ints
    int*    base   = (int*)(misc + 3072);                  // 32*12 ints
    int*    rbe3   = (int*)(misc + 12288);                 // 76 ints
    int*    rbs3   = (int*)(misc + 12800);                 // 76 ints
    int*    rbc3   = (int*)(misc + 13312);                 // 76 ints
    int*    perm  = (int*)(ws + (96 << 10));               // 32 KB
    char*   base_ = ws + (128 << 10);
    ushort* rpeT  = (ushort*)(base_);                      // 64 KB [h][p][d] bf16
    ushort* qpb   = (ushort*)(base_ + (8u  << 20));        // 4 MB
    ushort* kpb   = (ushort*)(base_ + (12u << 20));        // 1 MB [b][t][ed]
    ushort* vpT   = (ushort*)(base_ + (13u << 20));        // 1 MB [b][h][d][t]
    ushort* xb    = (ushort*)(base_ + (14u << 20));        // 4 MB
    ushort* wmapT = (ushort*)(base_ + (18u << 20));        // 6 MB
    ushort* keyb  = (ushort*)(base_ + (24u << 20));        // 4 MB
    ushort* valb  = (ushort*)(base_ + (28u << 20));        // 4 MB
    ushort* wkT   = (ushort*)(base_ + (32u << 20));        // 0.5 MB
    ushort* wvT   = (ushort*)(base_ + (32u << 20) + (512u << 10)); // 0.5 MB
    ushort* az    = (ushort*)(base_ + (48u << 20));        // 4.2 MB [row][256] f16
    ushort* wredf = (ushort*)(base_ + (61u << 20));        // 6.3 MB [e][d][256] f16
    float*  rel   = (float*)(base_ + (80u << 20));         // 16 MB [row][h][128]
    float*  wgT   = (float*)(base_ + (96u << 20));         // 48 KB f32 [e][d]

    zero_out<<<(N_ * D_) / 1024, 256, 0, stream>>>(out);
    castwg_kernel<<<D_ / 256, 256, 0, stream>>>(wg, wgT);
    castkv2_kernel<<<(2 * N_ * D_) / 1024, 256, 0, stream>>>(key, value, keyb, valb);
    castw_kernel<<<dim3(E_, 16, 4), 256, 0, stream>>>(wmap, wmapT);
    castwkv_kernel<<<dim3(2, 16, 4), 256, 0, stream>>>(wk, wv, wkT, wvT);
    castwred_kernel<<<dim3(E_, 4, 16), 256, 0, stream>>>(wred, wredf);
    castrpe_kernel<<<dim3(H_), 256, 0, stream>>>(rpe, rpeT);
    gatecast_kernel<<<N_ / 4, 256, 0, stream>>>(query, wgT, gates, idx, xb);
    hist_kernel<<<NROW / 256, 256, 0, stream>>>(idx, bcnt);
    scan_kernel<<<1, 64, 0, stream>>>(bcnt, offs, base, rbe3, rbs3, rbc3);
    scatter_kernel<<<NROW / 256, 256, 0, stream>>>(idx, base, perm);
    kv_mfma<<<dim3(16, 2, 2), 256, 0, stream>>>(keyb, valb, wkT, wvT, kpb, vpT);
    qproj_mfma<<<dim3(PB3_MAX, 2), 256, 0, stream>>>(xb, wmapT, perm, rbe3, rbs3, rbc3, qpb);
    rel_mfma<<<dim3(64, 4), 256, 0, stream>>>(qpb, rpeT, rel);
    attn_kernel<<<512, 256, 0, stream>>>(qpb, kpb, vpT, rel, gates, az);
    reduce_mfma<<<dim3(PB3_MAX, 8), 256, 0, stream>>>(az, wredf, perm, rbe3, rbs3, rbc3, out);
}

// Round 5
// 220.638 us; speedup vs baseline: 1.4461x; 1.1648x over previous
//
#include <hip/hip_runtime.h>

#define T_    1024
#define B_    2
#define D_    1024
#define E_    12
#define TOPK  4
#define ED_   256
#define HD_   64
#define H_    4
#define N_    (T_*B_)      // 2048 tokens
#define NROW  (N_*TOPK)    // 8192 (n,k) rows
#define PB3_MAX 76         // max 128-row expert chunks: 8192/128 + 12
#define KA_   256          // reduce K (f16 single-pass: ED_)

typedef __bf16 bf16x8 __attribute__((ext_vector_type(8)));
typedef _Float16 f16x8 __attribute__((ext_vector_type(8)));
typedef float  f32x4  __attribute__((ext_vector_type(4)));

__device__ __forceinline__ float sc_() { return 0.35355339059327373f; } // 64^-0.25

__device__ __forceinline__ void async16(const void* g, void* l) {
    __builtin_amdgcn_global_load_lds((const __attribute__((address_space(1))) void*)g,
                                     (__attribute__((address_space(3))) void*)l, 16, 0, 0);
}

// ================= prep: ALL independent pre-work in ONE launch ==============
// roles by blockIdx.x:
//   [0,512)      gate + query bf16 cast (wg loaded to LDS, transposed)
//   [512,1280)   castwred  (wredf[e][d][ed] = f16(wred[e][ed][d]))
//   [1280,5376)  castkv2   (key/value -> bf16)
//   [5376,6144)  castw     (wmapT[e][ed][d] = bf16(wmap[e][d][ed]))
//   [6144,8192)  zero out
//   [8192,8320)  castwkv   (wkT/wvT[ed][d] = bf16(w[d][ed]))
//   [8320,8324)  castrpe   (rpeT[h][p][d] = bf16(rpe[h][d][p]))
#define PREP_GRID 8324
__global__ void __launch_bounds__(256)
prep_kernel(const float* __restrict__ query, const float* __restrict__ key,
            const float* __restrict__ value, const float* __restrict__ wg,
            const float* __restrict__ wmap, const float* __restrict__ wred,
            const float* __restrict__ wk, const float* __restrict__ wv,
            const float* __restrict__ rpe,
            float* __restrict__ gates, int* __restrict__ idx, ushort* __restrict__ xb,
            ushort* __restrict__ keyb, ushort* __restrict__ valb,
            ushort* __restrict__ wmapT, ushort* __restrict__ wredf,
            ushort* __restrict__ wkT, ushort* __restrict__ wvT,
            ushort* __restrict__ rpeT, float* __restrict__ out) {
    __shared__ __align__(16) float lsbuf[12288];   // 48 KB, aliased per role
    int bid = blockIdx.x, tid = threadIdx.x;

    if (bid < 512) {
        // ---- gate + query cast ----
        float (*lsw)[1024] = (float(*)[1024])lsbuf;     // [e][d]
        for (int i = tid; i < 12288; i += 256) {
            int d = i / 12, e = i - d * 12;
            lsw[e][d] = wg[i];
        }
        __syncthreads();
        int w = tid >> 6, L = tid & 63;
        int n = bid * 4 + w;
        const float* xr = query + (size_t)n * D_;
        float acc[E_];
#pragma unroll
        for (int e = 0; e < E_; ++e) acc[e] = 0.f;
#pragma unroll
        for (int it = 0; it < 4; ++it) {
            float4 xv = *(const float4*)(xr + it * 256 + L * 4);
            union { __bf16 h[4]; uint2 u; } pk;
            pk.h[0] = (__bf16)xv.x; pk.h[1] = (__bf16)xv.y;
            pk.h[2] = (__bf16)xv.z; pk.h[3] = (__bf16)xv.w;
            *(uint2*)(xb + (size_t)n * D_ + it * 256 + L * 4) = pk.u;
#pragma unroll
            for (int e = 0; e < E_; ++e) {
                float4 wvv = *(const float4*)(&lsw[e][it * 256 + L * 4]);
                acc[e] += xv.x * wvv.x + xv.y * wvv.y + xv.z * wvv.z + xv.w * wvv.w;
            }
        }
#pragma unroll
        for (int e = 0; e < E_; ++e) {
            float v = acc[e];
            for (int o = 32; o > 0; o >>= 1) v += __shfl_down(v, o);
            acc[e] = v;
        }
        if (L == 0) {
            float mx = acc[0];
            for (int e = 1; e < E_; ++e) mx = fmaxf(mx, acc[e]);
            float s = 0.f, pr[E_];
            for (int e = 0; e < E_; ++e) { pr[e] = expf(acc[e] - mx); s += pr[e]; }
            float inv = 1.f / s;
            for (int e = 0; e < E_; ++e) pr[e] *= inv;
            for (int k = 0; k < TOPK; ++k) {
                int be = 0; float bv = -1.f;
                for (int e = 0; e < E_; ++e) if (pr[e] > bv) { bv = pr[e]; be = e; }
                gates[n * TOPK + k] = bv;
                idx[n * TOPK + k] = be;
                pr[be] = -1.f;
            }
        }
    } else if (bid < 1280) {
        // ---- castwred ----
        float (*ls)[65] = (float(*)[65])lsbuf;
        int i = bid - 512;
        int e = i >> 6, rem = i & 63, et = rem >> 4, dt = rem & 15;
        int c = tid & 63, rg = tid >> 6;
        const float* src = wred + (size_t)e * (ED_ * D_) + (size_t)(et * 64) * D_ + dt * 64;
#pragma unroll
        for (int q = 0; q < 16; ++q) {
            int r = q * 4 + rg;
            ls[r][c] = src[(size_t)r * D_ + c];
        }
        __syncthreads();
        ushort* dst = wredf + (size_t)e * (D_ * KA_) + (size_t)(dt * 64) * KA_ + et * 64;
#pragma unroll
        for (int q = 0; q < 16; ++q) {
            int r = q * 4 + rg;
            union { _Float16 h; ushort u; } cv; cv.h = (_Float16)ls[c][r];
            dst[(size_t)r * KA_ + c] = cv.u;
        }
    } else if (bid < 5376) {
        // ---- castkv2 ----
        int g = (bid - 1280) * 256 + tid;
        int which = g >> 19, t = g & ((1 << 19) - 1);
        const float* src = which ? value : key;
        ushort* dst = which ? valb : keyb;
        float4 v = *(const float4*)(src + (size_t)t * 4);
        union { __bf16 h[4]; uint2 u; } pk;
        pk.h[0] = (__bf16)v.x; pk.h[1] = (__bf16)v.y;
        pk.h[2] = (__bf16)v.z; pk.h[3] = (__bf16)v.w;
        *(uint2*)(dst + (size_t)t * 4) = pk.u;
    } else if (bid < 6144) {
        // ---- castw (wmap) ----
        float (*ls)[65] = (float(*)[65])lsbuf;
        int i = bid - 5376;
        int e = i >> 6, rem = i & 63, dt = rem >> 2, et = rem & 3;
        int c = tid & 63, rg = tid >> 6;
        const float* src = wmap + (size_t)e * (D_ * ED_) + (size_t)(dt * 64) * ED_ + et * 64;
#pragma unroll
        for (int q = 0; q < 16; ++q) {
            int r = q * 4 + rg;
            ls[r][c] = src[(size_t)r * ED_ + c];
        }
        __syncthreads();
        ushort* dst = wmapT + ((size_t)e << 18) + (size_t)(et * 64) * 1024 + dt * 64;
#pragma unroll
        for (int q = 0; q < 16; ++q) {
            int r = q * 4 + rg;
            union { __bf16 h; ushort u; } cv; cv.h = (__bf16)ls[c][r];
            dst[(size_t)r * 1024 + c] = cv.u;
        }
    } else if (bid < 8192) {
        // ---- zero out ----
        int t = (bid - 6144) * 256 + tid;
        *(float4*)(out + (size_t)t * 4) = make_float4(0.f, 0.f, 0.f, 0.f);
    } else if (bid < 8320) {
        // ---- castwkv ----
        float (*ls)[65] = (float(*)[65])lsbuf;
        int i = bid - 8192;
        int which = i >> 6, rem = i & 63, dt = rem >> 2, et = rem & 3;
        const float* w = which ? wv : wk;
        ushort* wT = which ? wvT : wkT;
        int c = tid & 63, rg = tid >> 6;
        const float* src = w + (size_t)(dt * 64) * ED_ + et * 64;
#pragma unroll
        for (int q = 0; q < 16; ++q) {
            int r = q * 4 + rg;
            ls[r][c] = src[(size_t)r * ED_ + c];
        }
        __syncthreads();
        ushort* dst = wT + (size_t)(et * 64) * 1024 + dt * 64;
#pragma unroll
        for (int q = 0; q < 16; ++q) {
            int r = q * 4 + rg;
            union { __bf16 h; ushort u; } cv; cv.h = (__bf16)ls[c][r];
            dst[(size_t)r * 1024 + c] = cv.u;
        }
    } else {
        // ---- castrpe ----
        int h = bid - 8320;
        int p = tid & 127, dq = tid >> 7;
#pragma unroll
        for (int d0 = 0; d0 < 64; d0 += 2) {
            int d = d0 + dq;
            union { __bf16 b; ushort u; } cv;
            cv.b = (__bf16)rpe[(size_t)(h * 64 + d) * 129 + p];
            rpeT[(size_t)(h * 128 + p) * 64 + d] = cv.u;
        }
    }
}

// ============ hist + scan + scatter fused: ONE block, 1024 threads ===========
// Row order within an expert is arbitrary (rows are independent) -> any valid
// permutation works. Wave w owns 64-row chunks c = w*8 .. w*8+7.
__global__ void __launch_bounds__(1024)
hss_kernel(const int* __restrict__ idx,
           int* __restrict__ rbe3, int* __restrict__ rbs3, int* __restrict__ rbc3,
           int* __restrict__ perm) {
    __shared__ int cnt[128][E_];
    __shared__ int pref[128][E_];
    __shared__ int offl[E_ + 1];
    __shared__ int counts[E_];
    int tid = threadIdx.x, w = tid >> 6, L = tid & 63;
    int mye[8];
#pragma unroll
    for (int g = 0; g < 8; ++g) {
        int c = w * 8 + g;
        int e = idx[c * 64 + L];
        mye[g] = e;
#pragma unroll
        for (int e0 = 0; e0 < E_; ++e0) {
            unsigned long long m = __ballot(e == e0);
            if (L == 0) cnt[c][e0] = (int)__popcll(m);
        }
    }
    __syncthreads();
    if (tid < E_) {
        int s = 0;
        for (int c = 0; c < 128; ++c) { pref[c][tid] = s; s += cnt[c][tid]; }
        counts[tid] = s;
    }
    __syncthreads();
    if (tid == 0) {
        int o = 0;
        for (int e = 0; e < E_; ++e) { offl[e] = o; o += counts[e]; }
        offl[E_] = o;
    }
    __syncthreads();
    if (tid < E_) {
        int pos = 0;
        for (int e = 0; e < tid; ++e) pos += (counts[e] + 127) >> 7;
        int c0 = counts[tid];
        for (int s = 0, k = 0; s < c0; s += 128, ++k) {
            rbe3[pos + k] = tid; rbs3[pos + k] = offl[tid] + s;
            int rem = c0 - s; rbc3[pos + k] = rem < 128 ? rem : 128;
        }
    }
    int tot = 0;
    for (int e = 0; e < E_; ++e) tot += (counts[e] + 127) >> 7;
    for (int i = tot + tid; i < PB3_MAX; i += 1024) {
        rbe3[i] = 0; rbs3[i] = 0; rbc3[i] = 0;
    }
#pragma unroll
    for (int g = 0; g < 8; ++g) {
        int c = w * 8 + g;
        int e = mye[g];
        int rank = 0;
#pragma unroll
        for (int e0 = 0; e0 < E_; ++e0) {
            unsigned long long m = __ballot(e == e0);
            if (e == e0) rank = (int)__popcll(m & ((1ULL << L) - 1ULL));
        }
        perm[offl[e] + pref[c][e] + rank] = c * 64 + L;
    }
}

// ---- shared 128x128 K=1024 bf16 MFMA pipeline body (kv + qproj) -------------
__device__ __forceinline__ void mfma_k16_bf16(
    const ushort* const asrc[4], const ushort* bsrc,
    ushort As[2][128 * 64], ushort Bs[2][128 * 64],
    f32x4 acc[2][8], int w, int L) {
    auto stage = [&](int kt, int bf) {
#pragma unroll
        for (int q = 0; q < 4; ++q)
            async16(asrc[q] + kt * 64, &As[bf][(q * 32 + w * 8) * 64]);
#pragma unroll
        for (int q = 0; q < 4; ++q)
            async16(bsrc + (size_t)(q * 32) * 1024 + kt * 64, &Bs[bf][(q * 32 + w * 8) * 64]);
    };
    auto compute = [&](int bf) {
        const ushort* AB = As[bf] + w * 32 * 64;
        const ushort* BB = Bs[bf];
#pragma unroll
        for (int ks = 0; ks < 2; ++ks) {
            int phys = (((ks * 4 + (L >> 4)) ^ (L & 7))) * 8;
            bf16x8 a0 = *(const bf16x8*)(AB + (L & 15) * 64 + phys);
            bf16x8 a1 = *(const bf16x8*)(AB + (16 + (L & 15)) * 64 + phys);
#pragma unroll
            for (int nt = 0; nt < 8; ++nt) {
                bf16x8 bfr = *(const bf16x8*)(BB + (nt * 16 + (L & 15)) * 64 + phys);
                acc[0][nt] = __builtin_amdgcn_mfma_f32_16x16x32_bf16(a0, bfr, acc[0][nt], 0, 0, 0);
                acc[1][nt] = __builtin_amdgcn_mfma_f32_16x16x32_bf16(a1, bfr, acc[1][nt], 0, 0, 0);
            }
        }
    };
    stage(0, 0);
    for (int t = 0; t < 16; ++t) {
        __syncthreads();
        if (t < 15) stage(t + 1, (t + 1) & 1);
        compute(t & 1);
    }
}

// ============ kv projection + q projection in ONE launch =====================
// blocks [0,64): kv (mc=bid&15 -> b,t0; n0 bit4; which bit5)
// blocks [64, 64+2*PB3_MAX): qproj (blk = (bid-64)>>1, n0 = (bid&1)*128)
__global__ void __launch_bounds__(256)
proj_mfma(const ushort* __restrict__ keyb, const ushort* __restrict__ valb,
          const ushort* __restrict__ wkT, const ushort* __restrict__ wvT,
          const ushort* __restrict__ xb, const ushort* __restrict__ wmapT,
          const int* __restrict__ perm,
          const int* __restrict__ rbe3, const int* __restrict__ rbs3,
          const int* __restrict__ rbc3,
          ushort* __restrict__ kpb, ushort* __restrict__ vpT,
          ushort* __restrict__ qpb) {
    __shared__ __align__(16) ushort As[2][128 * 64];   // 32 KB
    __shared__ __align__(16) ushort Bs[2][128 * 64];   // 32 KB
    __shared__ int rows3[128];
    int tid = threadIdx.x, w = tid >> 6, L = tid & 63;
    int swz = ((L & 7) ^ ((L >> 3) & 7)) * 8;

    f32x4 acc[2][8];
#pragma unroll
    for (int mt = 0; mt < 2; ++mt)
#pragma unroll
        for (int nt = 0; nt < 8; ++nt) acc[mt][nt] = (f32x4){0.f, 0.f, 0.f, 0.f};

    if (blockIdx.x < 64) {
        // ---------------- kv role ----------------
        int which = blockIdx.x >> 5;
        int n0 = ((blockIdx.x >> 4) & 1) * 128;
        int mc = blockIdx.x & 15;
        int b = mc >> 3, t0 = (mc & 7) * 128;
        const ushort* xsrc = which ? valb : keyb;
        const ushort* wT = which ? wvT : wkT;
        const ushort* asrc[4];
#pragma unroll
        for (int q = 0; q < 4; ++q) {
            int rl = q * 32 + w * 8 + (L >> 3);
            int an = (((t0 + rl) << 1) | b);
            asrc[q] = xsrc + (size_t)an * 1024 + swz;
        }
        const ushort* bsrc = wT + (size_t)(n0 + w * 8 + (L >> 3)) * 1024 + swz;

        mfma_k16_bf16(asrc, bsrc, As, Bs, acc, w, L);

#pragma unroll
        for (int mt = 0; mt < 2; ++mt)
#pragma unroll
            for (int nt = 0; nt < 8; ++nt) {
                int ed = n0 + nt * 16 + (L & 15);
                int tb = t0 + w * 32 + mt * 16 + (L >> 4) * 4;
                if (which == 0) {
#pragma unroll
                    for (int r = 0; r < 4; ++r) {
                        union { __bf16 h; ushort u; } cv;
                        cv.h = (__bf16)(acc[mt][nt][r] * sc_());
                        kpb[((size_t)((b << 10) + tb + r)) * ED_ + ed] = cv.u;
                    }
                } else {
                    int h = ed >> 6, d = ed & 63;
                    union { __bf16 h4[4]; uint2 u; } pk;
#pragma unroll
                    for (int r = 0; r < 4; ++r) pk.h4[r] = (__bf16)acc[mt][nt][r];
                    *(uint2*)&vpT[((size_t)((b * 4 + h) * 64 + d)) * 1024 + tb] = pk.u;
                }
            }
    } else {
        // ---------------- qproj role ----------------
        int qid = blockIdx.x - 64;
        int blk = qid >> 1;
        int n0 = (qid & 1) * 128;
        int nr = rbc3[blk];
        if (nr == 0) return;
        int e = rbe3[blk], rs = rbs3[blk];
        if (tid < 128) rows3[tid] = (tid < nr) ? perm[rs + tid] : -1;
        __syncthreads();

        const ushort* asrc[4];
#pragma unroll
        for (int q = 0; q < 4; ++q) {
            int ar = rows3[q * 32 + w * 8 + (L >> 3)];
            asrc[q] = xb + (size_t)((ar < 0 ? 0 : ar) >> 2) * 1024 + swz;
        }
        const ushort* bsrc = wmapT + ((size_t)e << 18)
                           + (size_t)(n0 + w * 8 + (L >> 3)) * 1024 + swz;

        mfma_k16_bf16(asrc, bsrc, As, Bs, acc, w, L);

#pragma unroll
        for (int mt = 0; mt < 2; ++mt)
#pragma unroll
            for (int nt = 0; nt < 8; ++nt) {
                int n = n0 + nt * 16 + (L & 15);
#pragma unroll
                for (int r = 0; r < 4; ++r) {
                    int m = w * 32 + mt * 16 + (L >> 4) * 4 + r;
                    int rowg = rows3[m];
                    if (rowg >= 0) {
                        union { __bf16 h; ushort u; } cv;
                        cv.h = (__bf16)(acc[mt][nt][r] * sc_());
                        qpb[(size_t)rowg * ED_ + n] = cv.u;
                    }
                }
            }
    }
}

// ---------------- rel bias as bf16 MFMA GEMM, f16 output ---------------------
// relh[(qrow*4 + h)*128 + p] = f16( qpb[qrow][h*64..] . rpeT[h][p][..] )
__global__ void __launch_bounds__(256)
rel_mfma(const ushort* __restrict__ qpb, const ushort* __restrict__ rpeT,
         ushort* __restrict__ relh) {
    int m0 = blockIdx.x * 128;
    int h  = blockIdx.y;
    int tid = threadIdx.x, w = tid >> 6, L = tid & 63;
    __shared__ __align__(16) ushort As[128 * 64];   // 16 KB
    __shared__ __align__(16) ushort Bs[128 * 64];   // 16 KB

    int swz = ((L & 7) ^ ((L >> 3) & 7)) * 8;
    const ushort* asrc = qpb + (size_t)(m0 + w * 8 + (L >> 3)) * ED_ + h * HD_ + swz;
    const ushort* bsrc = rpeT + (size_t)(h * 128 + w * 8 + (L >> 3)) * 64 + swz;
#pragma unroll
    for (int q = 0; q < 4; ++q) {
        async16(asrc + (size_t)(q * 32) * ED_, &As[(q * 32 + w * 8) * 64]);
        async16(bsrc + (size_t)(q * 32) * 64,  &Bs[(q * 32 + w * 8) * 64]);
    }
    __syncthreads();

    f32x4 acc[2][8];
#pragma unroll
    for (int mt = 0; mt < 2; ++mt)
#pragma unroll
        for (int nt = 0; nt < 8; ++nt) acc[mt][nt] = (f32x4){0.f, 0.f, 0.f, 0.f};

    const ushort* AB = As + w * 32 * 64;            // wave owns rows w*32..+31
#pragma unroll
    for (int ks = 0; ks < 2; ++ks) {
        int phys = (((ks * 4 + (L >> 4)) ^ (L & 7))) * 8;
        bf16x8 a0 = *(const bf16x8*)(AB + (L & 15) * 64 + phys);
        bf16x8 a1 = *(const bf16x8*)(AB + (16 + (L & 15)) * 64 + phys);
#pragma unroll
        for (int nt = 0; nt < 8; ++nt) {
            bf16x8 b = *(const bf16x8*)(Bs + (nt * 16 + (L & 15)) * 64 + phys);
            acc[0][nt] = __builtin_amdgcn_mfma_f32_16x16x32_bf16(a0, b, acc[0][nt], 0, 0, 0);
            acc[1][nt] = __builtin_amdgcn_mfma_f32_16x16x32_bf16(a1, b, acc[1][nt], 0, 0, 0);
        }
    }

#pragma unroll
    for (int mt = 0; mt < 2; ++mt)
#pragma unroll
        for (int nt = 0; nt < 8; ++nt) {
            int p = nt * 16 + (L & 15);
#pragma unroll
            for (int r = 0; r < 4; ++r) {
                int qrow = m0 + w * 32 + mt * 16 + (L >> 4) * 4 + r;
                union { _Float16 h16; ushort u; } cv;
                cv.h16 = (_Float16)acc[mt][nt][r];
                relh[((size_t)qrow * 4 + h) * 128 + p] = cv.u;
            }
        }
}

// ---------------- MFMA flash attention (bf16, no-max softmax) ----------------
// epilogue writes az[row][256] = f16(attn*gate/l)
__global__ void __launch_bounds__(256)
attn_kernel(const ushort* __restrict__ qpb, const ushort* __restrict__ kpb,
            const ushort* __restrict__ vpT, const ushort* __restrict__ relh,
            const float* __restrict__ gates, ushort* __restrict__ az) {
    __shared__ __align__(16) ushort Ks[2][64 * 64];
    __shared__ __align__(16) ushort Vs[2][64 * 64];
    __shared__ __align__(16) ushort Ps[4][16 * 64];

    const int tid = threadIdx.x;
    const int w = tid >> 6, L = tid & 63;
    const int bkh = blockIdx.x & 31, it = blockIdx.x >> 5;
    const int h = bkh & 3, kk = (bkh >> 2) & 3, bb = bkh >> 4;
    const int i0w = it * 64 + w * 16;
    const int iL = i0w + (L & 15);
    const int row = ((iL * 2 + bb) << 2) | kk;

    const ushort* qrow = qpb + row * ED_ + h * HD_;
    bf16x8 qf0 = *(const bf16x8*)(qrow + (L >> 4) * 8);
    bf16x8 qf1 = *(const bf16x8*)(qrow + 32 + (L >> 4) * 8);

    const ushort* relrow = relh + ((size_t)row * 4 + h) * 128;
    float rel_lo = (float)*(const _Float16*)(relrow + 1);
    float rel_hi = (float)*(const _Float16*)(relrow + 127);
    float gate = gates[row];

    f32x4 O[4];
#pragma unroll
    for (int mf = 0; mf < 4; ++mf) O[mf] = (f32x4){0.f, 0.f, 0.f, 0.f};
    float l_acc = 0.f;

    const ushort* ksrc = kpb + (size_t)(bb << 10) * ED_ + h * HD_;
    const ushort* vsrc = vpT + (size_t)((bb * 4 + h) * 64) * 1024;

    auto stage = [&](int t, int bf) {
        int j0 = t * 64;
#pragma unroll
        for (int q = 0; q < 2; ++q) {
            int r = L >> 3;
            int c = (L & 7) ^ r;
            const ushort* src = ksrc + (size_t)(j0 + w * 16 + q * 8 + r) * ED_ + c * 8;
            async16(src, &Ks[bf][(w * 16 + q * 8) * 64]);
        }
#pragma unroll
        for (int q = 0; q < 2; ++q) {
            int r = L >> 3;
            int d = w * 16 + q * 8 + r;
            int c = (L & 7) ^ (d & 7);
            const ushort* src = vsrc + (size_t)d * 1024 + j0 + c * 8;
            async16(src, &Vs[bf][(w * 16 + q * 8) * 64]);
        }
    };

    auto compute = [&](int bf, int j0) {
        const ushort* KB = Ks[bf];
        const ushort* VB = Vs[bf];
        ushort* PW = Ps[w];
#pragma unroll
        for (int jf = 0; jf < 4; ++jf) {
            int jrow = jf * 16 + (L & 15);
            bf16x8 a0 = *(const bf16x8*)(KB + jrow * 64 + (((L >> 4)) ^ (L & 7)) * 8);
            bf16x8 a1 = *(const bf16x8*)(KB + jrow * 64 + ((4 + (L >> 4)) ^ (L & 7)) * 8);
            f32x4 s = (f32x4){0.f, 0.f, 0.f, 0.f};
            s = __builtin_amdgcn_mfma_f32_16x16x32_bf16(a0, qf0, s, 0, 0, 0);
            s = __builtin_amdgcn_mfma_f32_16x16x32_bf16(a1, qf1, s, 0, 0, 0);
            int jlo = j0 + jf * 16;
            int jbase = jlo + (L >> 4) * 4;
            float pv[4];
            if (jlo >= i0w + 78) {
#pragma unroll
                for (int r = 0; r < 4; ++r) pv[r] = __expf(s[r] + rel_hi);
            } else if (jlo <= i0w - 78) {
#pragma unroll
                for (int r = 0; r < 4; ++r) pv[r] = __expf(s[r] + rel_lo);
            } else {
#pragma unroll
                for (int r = 0; r < 4; ++r) {
                    int dj = jbase + r - iL;
                    dj = dj < -63 ? -63 : (dj > 63 ? 63 : dj);
                    pv[r] = __expf(s[r] + (float)*(const _Float16*)(relrow + dj + 64));
                }
            }
            l_acc += (pv[0] + pv[1]) + (pv[2] + pv[3]);
            union { __bf16 h4[4]; uint2 u; } pk;
#pragma unroll
            for (int r = 0; r < 4; ++r) pk.h4[r] = (__bf16)pv[r];
            int iloc = L & 15;
            int chunk = jf * 2 + ((L >> 4) >> 1);
            int phys = chunk ^ (iloc & 7);
            *(uint2*)(PW + iloc * 64 + phys * 8 + ((L >> 4) & 1) * 4) = pk.u;
        }
#pragma unroll
        for (int ks = 0; ks < 2; ++ks) {
            int c = ks * 4 + (L >> 4);
            int phys = c ^ (L & 7);
            bf16x8 pf = *(const bf16x8*)(PW + (L & 15) * 64 + phys * 8);
#pragma unroll
            for (int mf = 0; mf < 4; ++mf) {
                bf16x8 vf = *(const bf16x8*)(VB + (mf * 16 + (L & 15)) * 64 + phys * 8);
                O[mf] = __builtin_amdgcn_mfma_f32_16x16x32_bf16(vf, pf, O[mf], 0, 0, 0);
            }
        }
    };

    stage(0, 0);
    for (int t = 0; t < 16; ++t) {
        __syncthreads();
        if (t < 15) stage(t + 1, (t + 1) & 1);
        compute(t & 1, t * 64);
    }

    l_acc += __shfl_xor(l_acc, 16);
    l_acc += __shfl_xor(l_acc, 32);
    float inv = gate / l_acc;
    ushort* azrow = az + (size_t)row * KA_ + h * HD_;
#pragma unroll
    for (int mf = 0; mf < 4; ++mf) {
        union { _Float16 h4[4]; uint2 u; } pk;
#pragma unroll
        for (int r = 0; r < 4; ++r) pk.h4[r] = (_Float16)(O[mf][r] * inv);
        int off = mf * 16 + (L >> 4) * 4;
        *(uint2*)(azrow + off) = pk.u;
    }
}

// ---------------- expert reduce as f16 MFMA (single pass, K=256) -------------
// 128-row chunks x 128-col tiles, grid (PB3_MAX, 8). Epilogue: HW f32 atomics
// into out (fused combine): out[row>>2][d] += acc.
__global__ void __launch_bounds__(256)
reduce_mfma(const ushort* __restrict__ az, const ushort* __restrict__ wredf,
            const int* __restrict__ perm,
            const int* __restrict__ rbe3, const int* __restrict__ rbs3,
            const int* __restrict__ rbc3, float* __restrict__ out) {
    int blk = blockIdx.x;
    int nr = rbc3[blk];
    if (nr == 0) return;
    int e = rbe3[blk], rs = rbs3[blk];
    int n0 = blockIdx.y * 128;
    int tid = threadIdx.x, w = tid >> 6, L = tid & 63;
    __shared__ __align__(16) ushort As[2][128 * 64];   // 32 KB
    __shared__ __align__(16) ushort Bs[2][128 * 64];   // 32 KB
    __shared__ int rows3[128];
    if (tid < 128) rows3[tid] = (tid < nr) ? perm[rs + tid] : -1;
    __syncthreads();

    int swz = ((L & 7) ^ ((L >> 3) & 7)) * 8;
    const ushort* asrc[4];
#pragma unroll
    for (int q = 0; q < 4; ++q) {
        int ar = rows3[q * 32 + w * 8 + (L >> 3)];
        asrc[q] = az + (size_t)(ar < 0 ? 0 : ar) * KA_ + swz;
    }
    const ushort* bsrc = wredf + (size_t)e * (D_ * KA_)
                       + (size_t)(n0 + w * 8 + (L >> 3)) * KA_ + swz;

    f32x4 acc[2][8];
#pragma unroll
    for (int mt = 0; mt < 2; ++mt)
#pragma unroll
        for (int nt = 0; nt < 8; ++nt) acc[mt][nt] = (f32x4){0.f, 0.f, 0.f, 0.f};

    auto stage = [&](int kt, int bf) {
#pragma unroll
        for (int q = 0; q < 4; ++q)
            async16(asrc[q] + kt * 64, &As[bf][(q * 32 + w * 8) * 64]);
#pragma unroll
        for (int q = 0; q < 4; ++q)
            async16(bsrc + (size_t)(q * 32) * KA_ + kt * 64, &Bs[bf][(q * 32 + w * 8) * 64]);
    };
    auto compute = [&](int bf) {
        const ushort* AB = As[bf] + w * 32 * 64;     // wave owns rows w*32..+31
        const ushort* BB = Bs[bf];                   // all waves share 128 cols
#pragma unroll
        for (int ks = 0; ks < 2; ++ks) {
            int phys = (((ks * 4 + (L >> 4)) ^ (L & 7))) * 8;
            f16x8 a0 = *(const f16x8*)(AB + (L & 15) * 64 + phys);
            f16x8 a1 = *(const f16x8*)(AB + (16 + (L & 15)) * 64 + phys);
#pragma unroll
            for (int nt = 0; nt < 8; ++nt) {
                f16x8 b = *(const f16x8*)(BB + (nt * 16 + (L & 15)) * 64 + phys);
                acc[0][nt] = __builtin_amdgcn_mfma_f32_16x16x32_f16(a0, b, acc[0][nt], 0, 0, 0);
                acc[1][nt] = __builtin_amdgcn_mfma_f32_16x16x32_f16(a1, b, acc[1][nt], 0, 0, 0);
            }
        }
    };

    stage(0, 0);
    for (int t = 0; t < 4; ++t) {        // K = 256 -> 4 tiles of 64
        __syncthreads();
        if (t < 3) stage(t + 1, (t + 1) & 1);
        compute(t & 1);
    }

#pragma unroll
    for (int mt = 0; mt < 2; ++mt)
#pragma unroll
        for (int nt = 0; nt < 8; ++nt) {
            int n = n0 + nt * 16 + (L & 15);
#pragma unroll
            for (int r = 0; r < 4; ++r) {
                int m = w * 32 + mt * 16 + (L >> 4) * 4 + r;
                int rowg = rows3[m];
                if (rowg >= 0)
                    unsafeAtomicAdd(out + (size_t)(rowg >> 2) * D_ + n, acc[mt][nt][r]);
            }
        }
}

// ---------------- launcher ---------------------------------------------------
extern "C" void kernel_launch(void* const* d_in, const int* in_sizes, int n_in,
                              void* d_out, int out_size, void* d_ws, size_t ws_size,
                              hipStream_t stream) {
    const float* query = (const float*)d_in[0];
    const float* key   = (const float*)d_in[1];
    const float* value = (const float*)d_in[2];
    const float* wg    = (const float*)d_in[3];
    const float* wmap  = (const float*)d_in[4];
    const float* wred  = (const float*)d_in[5];
    const float* wk    = (const float*)d_in[6];
    const float* wv    = (const float*)d_in[7];
    const float* rpe   = (const float*)d_in[8];
    float* out = (float*)d_out;

    char* ws = (char*)d_ws;
    float*  gates = (float*)(ws + 0);                      // 32 KB
    int*    idx   = (int*)(ws + (32 << 10));               // 32 KB
    char*   misc  = ws + (64 << 10);
    int*    rbe3   = (int*)(misc + 12288);                 // 76 ints
    int*    rbs3   = (int*)(misc + 12800);                 // 76 ints
    int*    rbc3   = (int*)(misc + 13312);                 // 76 ints
    int*    perm  = (int*)(ws + (96 << 10));               // 32 KB
    char*   base_ = ws + (128 << 10);
    ushort* rpeT  = (ushort*)(base_);                      // 64 KB [h][p][d] bf16
    ushort* qpb   = (ushort*)(base_ + (8u  << 20));        // 4 MB
    ushort* kpb   = (ushort*)(base_ + (12u << 20));        // 1 MB [b][t][ed]
    ushort* vpT   = (ushort*)(base_ + (13u << 20));        // 1 MB [b][h][d][t]
    ushort* xb    = (ushort*)(base_ + (14u << 20));        // 4 MB
    ushort* wmapT = (ushort*)(base_ + (18u << 20));        // 6 MB
    ushort* keyb  = (ushort*)(base_ + (24u << 20));        // 4 MB
    ushort* valb  = (ushort*)(base_ + (28u << 20));        // 4 MB
    ushort* wkT   = (ushort*)(base_ + (32u << 20));        // 0.5 MB
    ushort* wvT   = (ushort*)(base_ + (32u << 20) + (512u << 10)); // 0.5 MB
    ushort* az    = (ushort*)(base_ + (48u << 20));        // 4.2 MB [row][256] f16
    ushort* wredf = (ushort*)(base_ + (61u << 20));        // 6.3 MB [e][d][256] f16
    ushort* relh  = (ushort*)(base_ + (80u << 20));        // 8 MB [row][h][128] f16

    prep_kernel<<<PREP_GRID, 256, 0, stream>>>(query, key, value, wg, wmap, wred,
        wk, wv, rpe, gates, idx, xb, keyb, valb, wmapT, wredf, wkT, wvT, rpeT, out);
    hss_kernel<<<1, 1024, 0, stream>>>(idx, rbe3, rbs3, rbc3, perm);
    proj_mfma<<<64 + 2 * PB3_MAX, 256, 0, stream>>>(keyb, valb, wkT, wvT, xb, wmapT,
        perm, rbe3, rbs3, rbc3, kpb, vpT, qpb);
    rel_mfma<<<dim3(64, 4), 256, 0, stream>>>(qpb, rpeT, relh);
    attn_kernel<<<512, 256, 0, stream>>>(qpb, kpb, vpT, relh, gates, az);
    reduce_mfma<<<dim3(PB3_MAX, 8), 256, 0, stream>>>(az, wredf, perm, rbe3, rbs3, rbc3, out);
}

// Round 6
// 213.212 us; speedup vs baseline: 1.4965x; 1.0348x over previous
//
#include <hip/hip_runtime.h>

#define T_    1024
#define B_    2
#define D_    1024
#define E_    12
#define TOPK  4
#define ED_   256
#define HD_   64
#define H_    4
#define N_    (T_*B_)      // 2048 tokens
#define NROW  (N_*TOPK)    // 8192 (n,k) rows
#define PB3_MAX 76         // max 128-row expert chunks: 8192/128 + 12
#define KA_   256          // reduce K (f16 single-pass: ED_)

typedef __bf16 bf16x8 __attribute__((ext_vector_type(8)));
typedef _Float16 f16x8 __attribute__((ext_vector_type(8)));
typedef float  f32x4  __attribute__((ext_vector_type(4)));

__device__ __forceinline__ float sc_() { return 0.35355339059327373f; } // 64^-0.25

__device__ __forceinline__ void async16(const void* g, void* l) {
    __builtin_amdgcn_global_load_lds((const __attribute__((address_space(1))) void*)g,
                                     (__attribute__((address_space(3))) void*)l, 16, 0, 0);
}

// ================= prep: ALL independent pre-work in ONE launch ==============
// roles by blockIdx.x:
//   [0,512)      gate + query bf16 cast (wg loaded to LDS, transposed)
//   [512,1280)   castwred  (wredf[e][d][ed] = f16(wred[e][ed][d]))
//   [1280,5376)  castkv2   (key/value -> bf16)
//   [5376,6144)  castw     (wmapT[e][ed][d] = bf16(wmap[e][d][ed]))
//   [6144,8192)  zero out
//   [8192,8320)  castwkv   (wkT/wvT[ed][d] = bf16(w[d][ed]))
//   [8320,8324)  castrpe   (rpeT[h][p][d] = bf16(rpe[h][d][p]))
#define PREP_GRID 8324
__global__ void __launch_bounds__(256)
prep_kernel(const float* __restrict__ query, const float* __restrict__ key,
            const float* __restrict__ value, const float* __restrict__ wg,
            const float* __restrict__ wmap, const float* __restrict__ wred,
            const float* __restrict__ wk, const float* __restrict__ wv,
            const float* __restrict__ rpe,
            float* __restrict__ gates, int* __restrict__ idx, ushort* __restrict__ xb,
            ushort* __restrict__ keyb, ushort* __restrict__ valb,
            ushort* __restrict__ wmapT, ushort* __restrict__ wredf,
            ushort* __restrict__ wkT, ushort* __restrict__ wvT,
            ushort* __restrict__ rpeT, float* __restrict__ out) {
    __shared__ __align__(16) float lsbuf[12288];   // 48 KB, aliased per role
    int bid = blockIdx.x, tid = threadIdx.x;

    if (bid < 512) {
        // ---- gate + query cast ----
        float (*lsw)[1024] = (float(*)[1024])lsbuf;     // [e][d]
        for (int i = tid; i < 12288; i += 256) {
            int d = i / 12, e = i - d * 12;
            lsw[e][d] = wg[i];
        }
        __syncthreads();
        int w = tid >> 6, L = tid & 63;
        int n = bid * 4 + w;
        const float* xr = query + (size_t)n * D_;
        float acc[E_];
#pragma unroll
        for (int e = 0; e < E_; ++e) acc[e] = 0.f;
#pragma unroll
        for (int it = 0; it < 4; ++it) {
            float4 xv = *(const float4*)(xr + it * 256 + L * 4);
            union { __bf16 h[4]; uint2 u; } pk;
            pk.h[0] = (__bf16)xv.x; pk.h[1] = (__bf16)xv.y;
            pk.h[2] = (__bf16)xv.z; pk.h[3] = (__bf16)xv.w;
            *(uint2*)(xb + (size_t)n * D_ + it * 256 + L * 4) = pk.u;
#pragma unroll
            for (int e = 0; e < E_; ++e) {
                float4 wvv = *(const float4*)(&lsw[e][it * 256 + L * 4]);
                acc[e] += xv.x * wvv.x + xv.y * wvv.y + xv.z * wvv.z + xv.w * wvv.w;
            }
        }
#pragma unroll
        for (int e = 0; e < E_; ++e) {
            float v = acc[e];
            for (int o = 32; o > 0; o >>= 1) v += __shfl_down(v, o);
            acc[e] = v;
        }
        if (L == 0) {
            float mx = acc[0];
            for (int e = 1; e < E_; ++e) mx = fmaxf(mx, acc[e]);
            float s = 0.f, pr[E_];
            for (int e = 0; e < E_; ++e) { pr[e] = expf(acc[e] - mx); s += pr[e]; }
            float inv = 1.f / s;
            for (int e = 0; e < E_; ++e) pr[e] *= inv;
            for (int k = 0; k < TOPK; ++k) {
                int be = 0; float bv = -1.f;
                for (int e = 0; e < E_; ++e) if (pr[e] > bv) { bv = pr[e]; be = e; }
                gates[n * TOPK + k] = bv;
                idx[n * TOPK + k] = be;
                pr[be] = -1.f;
            }
        }
    } else if (bid < 1280) {
        // ---- castwred ----
        float (*ls)[65] = (float(*)[65])lsbuf;
        int i = bid - 512;
        int e = i >> 6, rem = i & 63, et = rem >> 4, dt = rem & 15;
        int c = tid & 63, rg = tid >> 6;
        const float* src = wred + (size_t)e * (ED_ * D_) + (size_t)(et * 64) * D_ + dt * 64;
#pragma unroll
        for (int q = 0; q < 16; ++q) {
            int r = q * 4 + rg;
            ls[r][c] = src[(size_t)r * D_ + c];
        }
        __syncthreads();
        ushort* dst = wredf + (size_t)e * (D_ * KA_) + (size_t)(dt * 64) * KA_ + et * 64;
#pragma unroll
        for (int q = 0; q < 16; ++q) {
            int r = q * 4 + rg;
            union { _Float16 h; ushort u; } cv; cv.h = (_Float16)ls[c][r];
            dst[(size_t)r * KA_ + c] = cv.u;
        }
    } else if (bid < 5376) {
        // ---- castkv2 ----
        int g = (bid - 1280) * 256 + tid;
        int which = g >> 19, t = g & ((1 << 19) - 1);
        const float* src = which ? value : key;
        ushort* dst = which ? valb : keyb;
        float4 v = *(const float4*)(src + (size_t)t * 4);
        union { __bf16 h[4]; uint2 u; } pk;
        pk.h[0] = (__bf16)v.x; pk.h[1] = (__bf16)v.y;
        pk.h[2] = (__bf16)v.z; pk.h[3] = (__bf16)v.w;
        *(uint2*)(dst + (size_t)t * 4) = pk.u;
    } else if (bid < 6144) {
        // ---- castw (wmap) ----
        float (*ls)[65] = (float(*)[65])lsbuf;
        int i = bid - 5376;
        int e = i >> 6, rem = i & 63, dt = rem >> 2, et = rem & 3;
        int c = tid & 63, rg = tid >> 6;
        const float* src = wmap + (size_t)e * (D_ * ED_) + (size_t)(dt * 64) * ED_ + et * 64;
#pragma unroll
        for (int q = 0; q < 16; ++q) {
            int r = q * 4 + rg;
            ls[r][c] = src[(size_t)r * ED_ + c];
        }
        __syncthreads();
        ushort* dst = wmapT + ((size_t)e << 18) + (size_t)(et * 64) * 1024 + dt * 64;
#pragma unroll
        for (int q = 0; q < 16; ++q) {
            int r = q * 4 + rg;
            union { __bf16 h; ushort u; } cv; cv.h = (__bf16)ls[c][r];
            dst[(size_t)r * 1024 + c] = cv.u;
        }
    } else if (bid < 8192) {
        // ---- zero out ----
        int t = (bid - 6144) * 256 + tid;
        *(float4*)(out + (size_t)t * 4) = make_float4(0.f, 0.f, 0.f, 0.f);
    } else if (bid < 8320) {
        // ---- castwkv ----
        float (*ls)[65] = (float(*)[65])lsbuf;
        int i = bid - 8192;
        int which = i >> 6, rem = i & 63, dt = rem >> 2, et = rem & 3;
        const float* w = which ? wv : wk;
        ushort* wT = which ? wvT : wkT;
        int c = tid & 63, rg = tid >> 6;
        const float* src = w + (size_t)(dt * 64) * ED_ + et * 64;
#pragma unroll
        for (int q = 0; q < 16; ++q) {
            int r = q * 4 + rg;
            ls[r][c] = src[(size_t)r * ED_ + c];
        }
        __syncthreads();
        ushort* dst = wT + (size_t)(et * 64) * 1024 + dt * 64;
#pragma unroll
        for (int q = 0; q < 16; ++q) {
            int r = q * 4 + rg;
            union { __bf16 h; ushort u; } cv; cv.h = (__bf16)ls[c][r];
            dst[(size_t)r * 1024 + c] = cv.u;
        }
    } else {
        // ---- castrpe ----
        int h = bid - 8320;
        int p = tid & 127, dq = tid >> 7;
#pragma unroll
        for (int d0 = 0; d0 < 64; d0 += 2) {
            int d = d0 + dq;
            union { __bf16 b; ushort u; } cv;
            cv.b = (__bf16)rpe[(size_t)(h * 64 + d) * 129 + p];
            rpeT[(size_t)(h * 128 + p) * 64 + d] = cv.u;
        }
    }
}

// ============ hist + scan + scatter fused: ONE block, 1024 threads ===========
__global__ void __launch_bounds__(1024)
hss_kernel(const int* __restrict__ idx,
           int* __restrict__ rbe3, int* __restrict__ rbs3, int* __restrict__ rbc3,
           int* __restrict__ perm) {
    __shared__ int cnt[128][E_];
    __shared__ int pref[128][E_];
    __shared__ int offl[E_ + 1];
    __shared__ int counts[E_];
    int tid = threadIdx.x, w = tid >> 6, L = tid & 63;
    int mye[8];
#pragma unroll
    for (int g = 0; g < 8; ++g) {
        int c = w * 8 + g;
        int e = idx[c * 64 + L];
        mye[g] = e;
#pragma unroll
        for (int e0 = 0; e0 < E_; ++e0) {
            unsigned long long m = __ballot(e == e0);
            if (L == 0) cnt[c][e0] = (int)__popcll(m);
        }
    }
    __syncthreads();
    if (tid < E_) {
        int s = 0;
        for (int c = 0; c < 128; ++c) { pref[c][tid] = s; s += cnt[c][tid]; }
        counts[tid] = s;
    }
    __syncthreads();
    if (tid == 0) {
        int o = 0;
        for (int e = 0; e < E_; ++e) { offl[e] = o; o += counts[e]; }
        offl[E_] = o;
    }
    __syncthreads();
    if (tid < E_) {
        int pos = 0;
        for (int e = 0; e < tid; ++e) pos += (counts[e] + 127) >> 7;
        int c0 = counts[tid];
        for (int s = 0, k = 0; s < c0; s += 128, ++k) {
            rbe3[pos + k] = tid; rbs3[pos + k] = offl[tid] + s;
            int rem = c0 - s; rbc3[pos + k] = rem < 128 ? rem : 128;
        }
    }
    int tot = 0;
    for (int e = 0; e < E_; ++e) tot += (counts[e] + 127) >> 7;
    for (int i = tot + tid; i < PB3_MAX; i += 1024) {
        rbe3[i] = 0; rbs3[i] = 0; rbc3[i] = 0;
    }
#pragma unroll
    for (int g = 0; g < 8; ++g) {
        int c = w * 8 + g;
        int e = mye[g];
        int rank = 0;
#pragma unroll
        for (int e0 = 0; e0 < E_; ++e0) {
            unsigned long long m = __ballot(e == e0);
            if (e == e0) rank = (int)__popcll(m & ((1ULL << L) - 1ULL));
        }
        perm[offl[e] + pref[c][e] + rank] = c * 64 + L;
    }
}

// ---- shared 128x128 K=1024 bf16 MFMA pipeline body (kv + qproj) -------------
__device__ __forceinline__ void mfma_k16_bf16(
    const ushort* const asrc[4], const ushort* bsrc,
    ushort As[2][128 * 64], ushort Bs[2][128 * 64],
    f32x4 acc[2][8], int w, int L) {
    auto stage = [&](int kt, int bf) {
#pragma unroll
        for (int q = 0; q < 4; ++q)
            async16(asrc[q] + kt * 64, &As[bf][(q * 32 + w * 8) * 64]);
#pragma unroll
        for (int q = 0; q < 4; ++q)
            async16(bsrc + (size_t)(q * 32) * 1024 + kt * 64, &Bs[bf][(q * 32 + w * 8) * 64]);
    };
    auto compute = [&](int bf) {
        const ushort* AB = As[bf] + w * 32 * 64;
        const ushort* BB = Bs[bf];
#pragma unroll
        for (int ks = 0; ks < 2; ++ks) {
            int phys = (((ks * 4 + (L >> 4)) ^ (L & 7))) * 8;
            bf16x8 a0 = *(const bf16x8*)(AB + (L & 15) * 64 + phys);
            bf16x8 a1 = *(const bf16x8*)(AB + (16 + (L & 15)) * 64 + phys);
#pragma unroll
            for (int nt = 0; nt < 8; ++nt) {
                bf16x8 bfr = *(const bf16x8*)(BB + (nt * 16 + (L & 15)) * 64 + phys);
                acc[0][nt] = __builtin_amdgcn_mfma_f32_16x16x32_bf16(a0, bfr, acc[0][nt], 0, 0, 0);
                acc[1][nt] = __builtin_amdgcn_mfma_f32_16x16x32_bf16(a1, bfr, acc[1][nt], 0, 0, 0);
            }
        }
    };
    stage(0, 0);
    for (int t = 0; t < 16; ++t) {
        __syncthreads();
        if (t < 15) stage(t + 1, (t + 1) & 1);
        compute(t & 1);
    }
}

// ============ kv projection + q projection in ONE launch =====================
__global__ void __launch_bounds__(256)
proj_mfma(const ushort* __restrict__ keyb, const ushort* __restrict__ valb,
          const ushort* __restrict__ wkT, const ushort* __restrict__ wvT,
          const ushort* __restrict__ xb, const ushort* __restrict__ wmapT,
          const int* __restrict__ perm,
          const int* __restrict__ rbe3, const int* __restrict__ rbs3,
          const int* __restrict__ rbc3,
          ushort* __restrict__ kpb, ushort* __restrict__ vpT,
          ushort* __restrict__ qpb) {
    __shared__ __align__(16) ushort As[2][128 * 64];   // 32 KB
    __shared__ __align__(16) ushort Bs[2][128 * 64];   // 32 KB
    __shared__ int rows3[128];
    int tid = threadIdx.x, w = tid >> 6, L = tid & 63;
    int swz = ((L & 7) ^ ((L >> 3) & 7)) * 8;

    f32x4 acc[2][8];
#pragma unroll
    for (int mt = 0; mt < 2; ++mt)
#pragma unroll
        for (int nt = 0; nt < 8; ++nt) acc[mt][nt] = (f32x4){0.f, 0.f, 0.f, 0.f};

    if (blockIdx.x < 64) {
        // ---------------- kv role ----------------
        int which = blockIdx.x >> 5;
        int n0 = ((blockIdx.x >> 4) & 1) * 128;
        int mc = blockIdx.x & 15;
        int b = mc >> 3, t0 = (mc & 7) * 128;
        const ushort* xsrc = which ? valb : keyb;
        const ushort* wT = which ? wvT : wkT;
        const ushort* asrc[4];
#pragma unroll
        for (int q = 0; q < 4; ++q) {
            int rl = q * 32 + w * 8 + (L >> 3);
            int an = (((t0 + rl) << 1) | b);
            asrc[q] = xsrc + (size_t)an * 1024 + swz;
        }
        const ushort* bsrc = wT + (size_t)(n0 + w * 8 + (L >> 3)) * 1024 + swz;

        mfma_k16_bf16(asrc, bsrc, As, Bs, acc, w, L);

#pragma unroll
        for (int mt = 0; mt < 2; ++mt)
#pragma unroll
            for (int nt = 0; nt < 8; ++nt) {
                int ed = n0 + nt * 16 + (L & 15);
                int tb = t0 + w * 32 + mt * 16 + (L >> 4) * 4;
                if (which == 0) {
#pragma unroll
                    for (int r = 0; r < 4; ++r) {
                        union { __bf16 h; ushort u; } cv;
                        cv.h = (__bf16)(acc[mt][nt][r] * sc_());
                        kpb[((size_t)((b << 10) + tb + r)) * ED_ + ed] = cv.u;
                    }
                } else {
                    int h = ed >> 6, d = ed & 63;
                    union { __bf16 h4[4]; uint2 u; } pk;
#pragma unroll
                    for (int r = 0; r < 4; ++r) pk.h4[r] = (__bf16)acc[mt][nt][r];
                    *(uint2*)&vpT[((size_t)((b * 4 + h) * 64 + d)) * 1024 + tb] = pk.u;
                }
            }
    } else {
        // ---------------- qproj role ----------------
        int qid = blockIdx.x - 64;
        int blk = qid >> 1;
        int n0 = (qid & 1) * 128;
        int nr = rbc3[blk];
        if (nr == 0) return;
        int e = rbe3[blk], rs = rbs3[blk];
        if (tid < 128) rows3[tid] = (tid < nr) ? perm[rs + tid] : -1;
        __syncthreads();

        const ushort* asrc[4];
#pragma unroll
        for (int q = 0; q < 4; ++q) {
            int ar = rows3[q * 32 + w * 8 + (L >> 3)];
            asrc[q] = xb + (size_t)((ar < 0 ? 0 : ar) >> 2) * 1024 + swz;
        }
        const ushort* bsrc = wmapT + ((size_t)e << 18)
                           + (size_t)(n0 + w * 8 + (L >> 3)) * 1024 + swz;

        mfma_k16_bf16(asrc, bsrc, As, Bs, acc, w, L);

#pragma unroll
        for (int mt = 0; mt < 2; ++mt)
#pragma unroll
            for (int nt = 0; nt < 8; ++nt) {
                int n = n0 + nt * 16 + (L & 15);
#pragma unroll
                for (int r = 0; r < 4; ++r) {
                    int m = w * 32 + mt * 16 + (L >> 4) * 4 + r;
                    int rowg = rows3[m];
                    if (rowg >= 0) {
                        union { __bf16 h; ushort u; } cv;
                        cv.h = (__bf16)(acc[mt][nt][r] * sc_());
                        qpb[(size_t)rowg * ED_ + n] = cv.u;
                    }
                }
            }
    }
}

// ---------------- MFMA flash attention with fused rel prologue ---------------
// rel[i][p] computed in-block via MFMA (A = rpeT[h] p-rows, B = q fragments),
// stored f32 in LDS (stride 132 -> 16B aligned, 2-way bank alias = free).
// epilogue writes az[row][256] = f16(attn*gate/l)
__global__ void __launch_bounds__(256)
attn_kernel(const ushort* __restrict__ qpb, const ushort* __restrict__ kpb,
            const ushort* __restrict__ vpT, const ushort* __restrict__ rpeT,
            const float* __restrict__ gates, ushort* __restrict__ az) {
    __shared__ __align__(16) ushort Ks[2][64 * 64];
    __shared__ __align__(16) ushort Vs[2][64 * 64];
    __shared__ __align__(16) ushort Ps[4][16 * 64];
    __shared__ __align__(16) float ls_rel[64 * 132];   // 33 KB

    const int tid = threadIdx.x;
    const int w = tid >> 6, L = tid & 63;
    const int bkh = blockIdx.x & 31, it = blockIdx.x >> 5;
    const int h = bkh & 3, kk = (bkh >> 2) & 3, bb = bkh >> 4;
    const int i0w = it * 64 + w * 16;
    const int iL = i0w + (L & 15);
    const int row = ((iL * 2 + bb) << 2) | kk;

    const ushort* qrow = qpb + row * ED_ + h * HD_;
    bf16x8 qf0 = *(const bf16x8*)(qrow + (L >> 4) * 8);
    bf16x8 qf1 = *(const bf16x8*)(qrow + 32 + (L >> 4) * 8);

    float gate = gates[row];

    // ---- rel prologue: stage rpeT[h] (128 p-rows x 64 d) into Ks[0],Ks[1] ----
    {
        int r = L >> 3;
        int c = (L & 7) ^ r;
        const ushort* rsrc = rpeT + (size_t)(h * 128) * 64 + c * 8;
#pragma unroll
        for (int q = 0; q < 2; ++q) {
            int p0 = w * 16 + q * 8 + r;
            async16(rsrc + (size_t)p0 * 64, &Ks[0][(w * 16 + q * 8) * 64]);
            async16(rsrc + (size_t)(64 + p0) * 64, &Ks[1][(w * 16 + q * 8) * 64]);
        }
    }
    __syncthreads();
    // rel[p][i] = rpe[h][:,p] . q[i]  via mfma(a=rpe_rows, b=qf) — same
    // fragment scheme as QK^T. Output: p = pt*16 + (L>>4)*4 + r, i = L&15.
#pragma unroll
    for (int pt = 0; pt < 8; ++pt) {
        const ushort* RB = Ks[pt >> 2];
        int prow = (pt & 3) * 16 + (L & 15);
        bf16x8 a0 = *(const bf16x8*)(RB + prow * 64 + (((L >> 4)) ^ (L & 7)) * 8);
        bf16x8 a1 = *(const bf16x8*)(RB + prow * 64 + ((4 + (L >> 4)) ^ (L & 7)) * 8);
        f32x4 s = (f32x4){0.f, 0.f, 0.f, 0.f};
        s = __builtin_amdgcn_mfma_f32_16x16x32_bf16(a0, qf0, s, 0, 0, 0);
        s = __builtin_amdgcn_mfma_f32_16x16x32_bf16(a1, qf1, s, 0, 0, 0);
        *(f32x4*)&ls_rel[(w * 16 + (L & 15)) * 132 + pt * 16 + (L >> 4) * 4] = s;
    }
    __syncthreads();   // rel done; Ks free for K-tiles

    const float* relrow = &ls_rel[(w * 16 + (L & 15)) * 132];
    float rel_lo = relrow[1], rel_hi = relrow[127];

    f32x4 O[4];
#pragma unroll
    for (int mf = 0; mf < 4; ++mf) O[mf] = (f32x4){0.f, 0.f, 0.f, 0.f};
    float l_acc = 0.f;

    const ushort* ksrc = kpb + (size_t)(bb << 10) * ED_ + h * HD_;
    const ushort* vsrc = vpT + (size_t)((bb * 4 + h) * 64) * 1024;

    auto stage = [&](int t, int bf) {
        int j0 = t * 64;
#pragma unroll
        for (int q = 0; q < 2; ++q) {
            int r = L >> 3;
            int c = (L & 7) ^ r;
            const ushort* src = ksrc + (size_t)(j0 + w * 16 + q * 8 + r) * ED_ + c * 8;
            async16(src, &Ks[bf][(w * 16 + q * 8) * 64]);
        }
#pragma unroll
        for (int q = 0; q < 2; ++q) {
            int r = L >> 3;
            int d = w * 16 + q * 8 + r;
            int c = (L & 7) ^ (d & 7);
            const ushort* src = vsrc + (size_t)d * 1024 + j0 + c * 8;
            async16(src, &Vs[bf][(w * 16 + q * 8) * 64]);
        }
    };

    auto compute = [&](int bf, int j0) {
        const ushort* KB = Ks[bf];
        const ushort* VB = Vs[bf];
        ushort* PW = Ps[w];
#pragma unroll
        for (int jf = 0; jf < 4; ++jf) {
            int jrow = jf * 16 + (L & 15);
            bf16x8 a0 = *(const bf16x8*)(KB + jrow * 64 + (((L >> 4)) ^ (L & 7)) * 8);
            bf16x8 a1 = *(const bf16x8*)(KB + jrow * 64 + ((4 + (L >> 4)) ^ (L & 7)) * 8);
            f32x4 s = (f32x4){0.f, 0.f, 0.f, 0.f};
            s = __builtin_amdgcn_mfma_f32_16x16x32_bf16(a0, qf0, s, 0, 0, 0);
            s = __builtin_amdgcn_mfma_f32_16x16x32_bf16(a1, qf1, s, 0, 0, 0);
            int jlo = j0 + jf * 16;
            int jbase = jlo + (L >> 4) * 4;
            float pv[4];
            if (jlo >= i0w + 78) {
#pragma unroll
                for (int r = 0; r < 4; ++r) pv[r] = __expf(s[r] + rel_hi);
            } else if (jlo <= i0w - 78) {
#pragma unroll
                for (int r = 0; r < 4; ++r) pv[r] = __expf(s[r] + rel_lo);
            } else {
#pragma unroll
                for (int r = 0; r < 4; ++r) {
                    int dj = jbase + r - iL;
                    dj = dj < -63 ? -63 : (dj > 63 ? 63 : dj);
                    pv[r] = __expf(s[r] + relrow[dj + 64]);
                }
            }
            l_acc += (pv[0] + pv[1]) + (pv[2] + pv[3]);
            union { __bf16 h4[4]; uint2 u; } pk;
#pragma unroll
            for (int r = 0; r < 4; ++r) pk.h4[r] = (__bf16)pv[r];
            int iloc = L & 15;
            int chunk = jf * 2 + ((L >> 4) >> 1);
            int phys = chunk ^ (iloc & 7);
            *(uint2*)(PW + iloc * 64 + phys * 8 + ((L >> 4) & 1) * 4) = pk.u;
        }
#pragma unroll
        for (int ks = 0; ks < 2; ++ks) {
            int c = ks * 4 + (L >> 4);
            int phys = c ^ (L & 7);
            bf16x8 pf = *(const bf16x8*)(PW + (L & 15) * 64 + phys * 8);
#pragma unroll
            for (int mf = 0; mf < 4; ++mf) {
                bf16x8 vf = *(const bf16x8*)(VB + (mf * 16 + (L & 15)) * 64 + phys * 8);
                O[mf] = __builtin_amdgcn_mfma_f32_16x16x32_bf16(vf, pf, O[mf], 0, 0, 0);
            }
        }
    };

    stage(0, 0);
    for (int t = 0; t < 16; ++t) {
        __syncthreads();
        if (t < 15) stage(t + 1, (t + 1) & 1);
        compute(t & 1, t * 64);
    }

    l_acc += __shfl_xor(l_acc, 16);
    l_acc += __shfl_xor(l_acc, 32);
    float inv = gate / l_acc;
    ushort* azrow = az + (size_t)row * KA_ + h * HD_;
#pragma unroll
    for (int mf = 0; mf < 4; ++mf) {
        union { _Float16 h4[4]; uint2 u; } pk;
#pragma unroll
        for (int r = 0; r < 4; ++r) pk.h4[r] = (_Float16)(O[mf][r] * inv);
        int off = mf * 16 + (L >> 4) * 4;
        *(uint2*)(azrow + off) = pk.u;
    }
}

// ---------------- expert reduce as f16 MFMA (single pass, K=256) -------------
__global__ void __launch_bounds__(256)
reduce_mfma(const ushort* __restrict__ az, const ushort* __restrict__ wredf,
            const int* __restrict__ perm,
            const int* __restrict__ rbe3, const int* __restrict__ rbs3,
            const int* __restrict__ rbc3, float* __restrict__ out) {
    int blk = blockIdx.x;
    int nr = rbc3[blk];
    if (nr == 0) return;
    int e = rbe3[blk], rs = rbs3[blk];
    int n0 = blockIdx.y * 128;
    int tid = threadIdx.x, w = tid >> 6, L = tid & 63;
    __shared__ __align__(16) ushort As[2][128 * 64];   // 32 KB
    __shared__ __align__(16) ushort Bs[2][128 * 64];   // 32 KB
    __shared__ int rows3[128];
    if (tid < 128) rows3[tid] = (tid < nr) ? perm[rs + tid] : -1;
    __syncthreads();

    int swz = ((L & 7) ^ ((L >> 3) & 7)) * 8;
    const ushort* asrc[4];
#pragma unroll
    for (int q = 0; q < 4; ++q) {
        int ar = rows3[q * 32 + w * 8 + (L >> 3)];
        asrc[q] = az + (size_t)(ar < 0 ? 0 : ar) * KA_ + swz;
    }
    const ushort* bsrc = wredf + (size_t)e * (D_ * KA_)
                       + (size_t)(n0 + w * 8 + (L >> 3)) * KA_ + swz;

    f32x4 acc[2][8];
#pragma unroll
    for (int mt = 0; mt < 2; ++mt)
#pragma unroll
        for (int nt = 0; nt < 8; ++nt) acc[mt][nt] = (f32x4){0.f, 0.f, 0.f, 0.f};

    auto stage = [&](int kt, int bf) {
#pragma unroll
        for (int q = 0; q < 4; ++q)
            async16(asrc[q] + kt * 64, &As[bf][(q * 32 + w * 8) * 64]);
#pragma unroll
        for (int q = 0; q < 4; ++q)
            async16(bsrc + (size_t)(q * 32) * KA_ + kt * 64, &Bs[bf][(q * 32 + w * 8) * 64]);
    };
    auto compute = [&](int bf) {
        const ushort* AB = As[bf] + w * 32 * 64;     // wave owns rows w*32..+31
        const ushort* BB = Bs[bf];                   // all waves share 128 cols
#pragma unroll
        for (int ks = 0; ks < 2; ++ks) {
            int phys = (((ks * 4 + (L >> 4)) ^ (L & 7))) * 8;
            f16x8 a0 = *(const f16x8*)(AB + (L & 15) * 64 + phys);
            f16x8 a1 = *(const f16x8*)(AB + (16 + (L & 15)) * 64 + phys);
#pragma unroll
            for (int nt = 0; nt < 8; ++nt) {
                f16x8 b = *(const f16x8*)(BB + (nt * 16 + (L & 15)) * 64 + phys);
                acc[0][nt] = __builtin_amdgcn_mfma_f32_16x16x32_f16(a0, b, acc[0][nt], 0, 0, 0);
                acc[1][nt] = __builtin_amdgcn_mfma_f32_16x16x32_f16(a1, b, acc[1][nt], 0, 0, 0);
            }
        }
    };

    stage(0, 0);
    for (int t = 0; t < 4; ++t) {        // K = 256 -> 4 tiles of 64
        __syncthreads();
        if (t < 3) stage(t + 1, (t + 1) & 1);
        compute(t & 1);
    }

#pragma unroll
    for (int mt = 0; mt < 2; ++mt)
#pragma unroll
        for (int nt = 0; nt < 8; ++nt) {
            int n = n0 + nt * 16 + (L & 15);
#pragma unroll
            for (int r = 0; r < 4; ++r) {
                int m = w * 32 + mt * 16 + (L >> 4) * 4 + r;
                int rowg = rows3[m];
                if (rowg >= 0)
                    unsafeAtomicAdd(out + (size_t)(rowg >> 2) * D_ + n, acc[mt][nt][r]);
            }
        }
}

// ---------------- launcher ---------------------------------------------------
extern "C" void kernel_launch(void* const* d_in, const int* in_sizes, int n_in,
                              void* d_out, int out_size, void* d_ws, size_t ws_size,
                              hipStream_t stream) {
    const float* query = (const float*)d_in[0];
    const float* key   = (const float*)d_in[1];
    const float* value = (const float*)d_in[2];
    const float* wg    = (const float*)d_in[3];
    const float* wmap  = (const float*)d_in[4];
    const float* wred  = (const float*)d_in[5];
    const float* wk    = (const float*)d_in[6];
    const float* wv    = (const float*)d_in[7];
    const float* rpe   = (const float*)d_in[8];
    float* out = (float*)d_out;

    char* ws = (char*)d_ws;
    float*  gates = (float*)(ws + 0);                      // 32 KB
    int*    idx   = (int*)(ws + (32 << 10));               // 32 KB
    char*   misc  = ws + (64 << 10);
    int*    rbe3   = (int*)(misc + 12288);                 // 76 ints
    int*    rbs3   = (int*)(misc + 12800);                 // 76 ints
    int*    rbc3   = (int*)(misc + 13312);                 // 76 ints
    int*    perm  = (int*)(ws + (96 << 10));               // 32 KB
    char*   base_ = ws + (128 << 10);
    ushort* rpeT  = (ushort*)(base_);                      // 64 KB [h][p][d] bf16
    ushort* qpb   = (ushort*)(base_ + (8u  << 20));        // 4 MB
    ushort* kpb   = (ushort*)(base_ + (12u << 20));        // 1 MB [b][t][ed]
    ushort* vpT   = (ushort*)(base_ + (13u << 20));        // 1 MB [b][h][d][t]
    ushort* xb    = (ushort*)(base_ + (14u << 20));        // 4 MB
    ushort* wmapT = (ushort*)(base_ + (18u << 20));        // 6 MB
    ushort* keyb  = (ushort*)(base_ + (24u << 20));        // 4 MB
    ushort* valb  = (ushort*)(base_ + (28u << 20));        // 4 MB
    ushort* wkT   = (ushort*)(base_ + (32u << 20));        // 0.5 MB
    ushort* wvT   = (ushort*)(base_ + (32u << 20) + (512u << 10)); // 0.5 MB
    ushort* az    = (ushort*)(base_ + (48u << 20));        // 4.2 MB [row][256] f16
    ushort* wredf = (ushort*)(base_ + (61u << 20));        // 6.3 MB [e][d][256] f16

    prep_kernel<<<PREP_GRID, 256, 0, stream>>>(query, key, value, wg, wmap, wred,
        wk, wv, rpe, gates, idx, xb, keyb, valb, wmapT, wredf, wkT, wvT, rpeT, out);
    hss_kernel<<<1, 1024, 0, stream>>>(idx, rbe3, rbs3, rbc3, perm);
    proj_mfma<<<64 + 2 * PB3_MAX, 256, 0, stream>>>(keyb, valb, wkT, wvT, xb, wmapT,
        perm, rbe3, rbs3, rbc3, kpb, vpT, qpb);
    attn_kernel<<<512, 256, 0, stream>>>(qpb, kpb, vpT, rpeT, gates, az);
    reduce_mfma<<<dim3(PB3_MAX, 8), 256, 0, stream>>>(az, wredf, perm, rbe3, rbs3, rbc3, out);
}